// Round 2
// baseline (3632.424 us; speedup 1.0000x reference)
//
#include <hip/hip_runtime.h>
#include <hip/hip_bf16.h>
#include <math.h>

#define Bb 8
#define Cc 180
#define HWn 9216
#define PD 16
#define CRr 60
#define HID 360
#define H2 720
#define NF 49
#define SPL 9408   /* spectral plane stride in floats: 96*49*2 */
#define CONV_SCALE 0.01f
#define FFT_RES 0.15f
#define EPSLN 1e-5f
#define TWOPI_96 0.06544984694978735f

typedef __hip_bfloat16 bf16;

__device__ __forceinline__ float geluf(float x){ return 0.5f*x*(1.0f+erff(x*0.7071067811865476f)); }
__device__ __forceinline__ float sigm(float x){ return 1.0f/(1.0f+expf(-x)); }
__device__ __forceinline__ float wredsum(float v){
#pragma unroll
  for(int m=1;m<64;m<<=1) v += __shfl_xor(v,m,64);
  return v;
}

// ---------------- LN1 + transpose to (B,C,H,W) ----------------
__global__ void __launch_bounds__(256) k_ln1(const float* __restrict__ x, const float* __restrict__ g,
                      const float* __restrict__ be, float* __restrict__ ximg){
  __shared__ float sb[32*Cc];
  int b = blockIdx.x / 288;
  int n0 = (blockIdx.x % 288) * 32;
  int t = threadIdx.x;
  const float* src = x + (size_t)(b*HWn + n0)*Cc;
  for(int i=t;i<32*Cc;i+=256) sb[i]=src[i];
  __syncthreads();
  int w = t>>6, lane = t&63;
  for(int pi=0; pi<8; ++pi){
    int p = w*8+pi;
    float s=0.f, sq=0.f;
    for(int e=lane;e<Cc;e+=64){ float v=sb[p*Cc+e]; s+=v; sq+=v*v; }
    s = wredsum(s); sq = wredsum(sq);
    float mean = s*(1.0f/180.0f);
    float var = sq*(1.0f/180.0f) - mean*mean;
    float rstd = rsqrtf(var + EPSLN);
    for(int e=lane;e<Cc;e+=64){ float v=sb[p*Cc+e]; sb[p*Cc+e] = (v-mean)*rstd*g[e]+be[e]; }
  }
  __syncthreads();
  for(int i=t;i<32*Cc;i+=256){
    int c = i/32, p = i%32;
    ximg[(size_t)(b*Cc+c)*HWn + n0 + p] = sb[p*Cc+c];
  }
}

// ---------------- plane mean (9216 -> 1) ----------------
__global__ void __launch_bounds__(256) k_plane_mean(const float* __restrict__ in, float* __restrict__ out){
  __shared__ float red[4];
  int pl = blockIdx.x; int t = threadIdx.x;
  const float* p = in + (size_t)pl*HWn;
  float s=0.f;
  for(int i=t;i<HWn;i+=256) s+=p[i];
  s = wredsum(s);
  if((t&63)==0) red[t>>6]=s;
  __syncthreads();
  if(t==0) out[pl] = (red[0]+red[1]+red[2]+red[3]) * (1.0f/9216.0f);
}

// ---------------- small: gates, hdn->dk, fft bias ----------------
__global__ void k_small(const float* __restrict__ m1, const float* __restrict__ gate_w,
   const float* __restrict__ gate_b, const float* __restrict__ dwc_w1, const float* __restrict__ dwc_b1,
   const float* __restrict__ dwc_w2, const float* __restrict__ dwc_b2, const float* __restrict__ band_b,
   float* __restrict__ gates, float* __restrict__ dkb, float* __restrict__ biasb){
  int b = threadIdx.x;
  if(b>=Bb) return;
  const float* m = m1 + b*Cc;
  float gv[3];
  for(int k=0;k<3;k++){ float a=gate_b[k]; for(int c=0;c<Cc;c++) a+=m[c]*gate_w[k*Cc+c]; gv[k]=sigm(a);}
  float e0=expf(gv[0]), e1=expf(gv[1]), e2=expf(gv[2]); float inv=1.0f/(e0+e1+e2);
  float g0=e0*inv,g1=e1*inv,g2=e2*inv;
  gates[b*3+0]=g0; gates[b*3+1]=g1; gates[b*3+2]=g2;
  float hd[8];
  for(int j=0;j<8;j++){ float a=dwc_b1[j]; for(int c=0;c<PD;c++) a+=m[c]*dwc_w1[j*PD+c]; hd[j]=geluf(a);}
  for(int i=0;i<144;i++){ float a=dwc_b2[i]; for(int j=0;j<8;j++) a+=hd[j]*dwc_w2[i*8+j]; dkb[b*144+i]=a; }
  for(int d=0;d<Cc;d++) biasb[b*Cc+d] = g0*band_b[0*Cc+d]+g1*band_b[1*Cc+d]+g2*band_b[2*Cc+d];
}

// ---------------- forward DFT along x (real -> complex, 49 freqs) ----------------
__global__ void __launch_bounds__(256) k_fwd_x(const float* __restrict__ ximg, float* __restrict__ V){
  __shared__ float img[HWn];
  __shared__ float cs[96], sn[96];
  int bc = blockIdx.x; int t = threadIdx.x;
  const float* src = ximg + (size_t)bc*HWn;
  for(int i=t;i<HWn;i+=256) img[i]=src[i];
  if(t<96){ float th = (float)t * TWOPI_96; cs[t]=cosf(th); sn[t]=sinf(th); }
  __syncthreads();
  float* dst = V + (size_t)bc*SPL;
  for(int o=t;o<96*NF;o+=256){
    int y=o/NF, kx=o%NF;
    float re=0.f, im=0.f; int m=0;
    const float* row = img + y*96;
    for(int xx=0; xx<96; ++xx){
      float v=row[xx];
      re += v*cs[m]; im -= v*sn[m];
      m += kx; if(m>=96) m-=96;
    }
    dst[o*2]=re; dst[o*2+1]=im;
  }
}

// ---------------- forward DFT along y (complex -> complex), ortho 1/96, IN-PLACE ----------------
__global__ void __launch_bounds__(256) k_fwd_y(float* __restrict__ S){
  __shared__ float vb[SPL];
  __shared__ float cs[96], sn[96];
  int bc=blockIdx.x, t=threadIdx.x;
  float* pl = S + (size_t)bc*SPL;
  for(int i=t;i<SPL;i+=256) vb[i]=pl[i];
  if(t<96){ float th = (float)t * TWOPI_96; cs[t]=cosf(th); sn[t]=sinf(th); }
  __syncthreads();
  for(int o=t;o<96*NF;o+=256){
    int ky=o/NF, kx=o%NF;
    float re=0.f, im=0.f; int m=0;
    for(int y=0;y<96;++y){
      float vr=vb[(y*NF+kx)*2], vi=vb[(y*NF+kx)*2+1];
      float c=cs[m], s=sn[m];
      re += vr*c + vi*s;
      im += vi*c - vr*s;
      m += ky; if(m>=96) m-=96;
    }
    pl[o*2]=re*(1.0f/96.0f); pl[o*2+1]=im*(1.0f/96.0f);
  }
}

// ---------------- per-frequency band channel mix: Y = g_bk * W_k @ X, IN-PLACE ----------------
__global__ void __launch_bounds__(256) k_bandmix(float* __restrict__ S, const float* __restrict__ band_w,
                          const float* __restrict__ gates){
  __shared__ float xs[Cc*50];
  int b = blockIdx.x; int ky = blockIdx.y; int half = blockIdx.z;
  int kx0 = half*25; int nkx = half? 24:25;
  int t=threadIdx.x;
  for(int i=t;i<Cc*nkx*2;i+=256){
    int c = i/(nkx*2); int r = i%(nkx*2);
    xs[c*50+r] = S[ (size_t)(b*Cc+c)*SPL + ky*(NF*2) + kx0*2 + r ];
  }
  __syncthreads();
  float yy = -1.0f + 2.0f*(float)ky/95.0f;
  for(int o=t;o<Cc*nkx;o+=256){
    int d = o/nkx, kxl = o%nkx; int kx = kx0+kxl;
    float xxf = (float)kx/48.0f;
    float rr = sqrtf(yy*yy+xxf*xxf);
    int k = (rr<=0.25f)?0:((rr<=0.6f)?1:2);
    float g = gates[b*3+k];
    const float* wr = band_w + ((size_t)k*Cc + d)*Cc;
    float re=0.f, im=0.f;
    for(int c=0;c<Cc;++c){
      float w=wr[c];
      re += w*xs[c*50 + kxl*2];
      im += w*xs[c*50 + kxl*2 + 1];
    }
    size_t off = (size_t)(b*Cc+d)*SPL + ky*(NF*2) + kx*2;
    S[off]=g*re; S[off+1]=g*im;
  }
}

// ---------------- inverse DFT along ky (complex -> complex, e^{+i}), IN-PLACE ----------------
__global__ void __launch_bounds__(256) k_inv_y(float* __restrict__ S){
  __shared__ float vb[SPL];
  __shared__ float cs[96], sn[96];
  int bd=blockIdx.x, t=threadIdx.x;
  float* pl = S + (size_t)bd*SPL;
  for(int i=t;i<SPL;i+=256) vb[i]=pl[i];
  if(t<96){ float th = (float)t * TWOPI_96; cs[t]=cosf(th); sn[t]=sinf(th); }
  __syncthreads();
  for(int o=t;o<96*NF;o+=256){
    int y=o/NF, kx=o%NF;
    float re=0.f, im=0.f; int m=0;
    for(int ky=0;ky<96;++ky){
      float vr=vb[(ky*NF+kx)*2], vi=vb[(ky*NF+kx)*2+1];
      float c=cs[m], s=sn[m];
      re += vr*c - vi*s;
      im += vr*s + vi*c;
      m += y; if(m>=96) m-=96;
    }
    pl[o*2]=re; pl[o*2+1]=im;
  }
}

// -------- inverse rDFT along kx + combine, IN-PLACE into spec plane (first 9216 floats) --------
__global__ void __launch_bounds__(256) k_inv_x(float* __restrict__ S, const float* __restrict__ ximg,
                        const float* __restrict__ biasb){
  __shared__ float tb[SPL];
  __shared__ float cs[96], sn[96];
  int bd = blockIdx.x; int t=threadIdx.x;
  int b = bd / Cc; int d = bd % Cc;
  float* pl = S + (size_t)bd*SPL;
  for(int i=t;i<SPL;i+=256) tb[i]=pl[i];
  if(t<96){ float th = (float)t * TWOPI_96; cs[t]=cosf(th); sn[t]=sinf(th); }
  __syncthreads();
  float bias = biasb[b*Cc+d];
  const float* xs = ximg + (size_t)bd*HWn;
  for(int o=t;o<HWn;o+=256){
    int y=o/96, xx=o%96;
    float acc=0.f; int m=0;
    const float* row = tb + y*(NF*2);
    for(int kx=0;kx<NF;++kx){
      float wgt = (kx==0||kx==48)?1.0f:2.0f;
      acc += wgt*(row[kx*2]*cs[m] - row[kx*2+1]*sn[m]);
      m += xx; if(m>=96) m-=96;
    }
    pl[o] = xs[o] + FFT_RES*(acc*(1.0f/96.0f) + bias);
  }
}

// ---------------- 3x3 conv, LDS tile, 2x2 px/thread, 4 co/block ----------------
template<int CIN, bool ACT>
__global__ void __launch_bounds__(256) k_conv3(const float* __restrict__ xin, const float* __restrict__ wgt,
    const float* __restrict__ bias, float* __restrict__ out, int COUT, int istride){
  __shared__ float tile[34*34];
  __shared__ float wl[36];
  int tile_id = blockIdx.x;
  int co0 = blockIdx.y*4;
  int b = blockIdx.z;
  int ty0 = (tile_id/3)*32, tx0 = (tile_id%3)*32;
  int t=threadIdx.x;
  int px0 = (t%16)*2, py0 = (t/16)*2;
  float acc[4][4]={};
  for(int ci=0; ci<CIN; ++ci){
    __syncthreads();
    for(int i=t;i<34*34;i+=256){
      int ly=i/34, lx=i%34;
      int gy=ty0+ly-1, gx=tx0+lx-1;
      float v=0.f;
      if((unsigned)gy<96u && (unsigned)gx<96u) v = xin[(size_t)(b*CIN+ci)*istride + gy*96+gx];
      tile[i]=v;
    }
    if(t<36) wl[t] = wgt[ ((size_t)(co0 + t/9)*CIN + ci)*9 + (t%9) ];
    __syncthreads();
    float r[4][4];
#pragma unroll
    for(int dy=0;dy<4;dy++)
#pragma unroll
      for(int dx=0;dx<4;dx++) r[dy][dx]=tile[(py0+dy)*34+px0+dx];
#pragma unroll
    for(int co=0;co<4;co++){
#pragma unroll
      for(int ky=0;ky<3;ky++)
#pragma unroll
        for(int kx=0;kx<3;kx++){
          float w=wl[co*9+ky*3+kx];
          acc[co][0]+=w*r[ky][kx];   acc[co][1]+=w*r[ky][kx+1];
          acc[co][2]+=w*r[ky+1][kx]; acc[co][3]+=w*r[ky+1][kx+1];
        }
    }
  }
#pragma unroll
  for(int co=0;co<4;co++){
    float bb = bias[co0+co];
#pragma unroll
    for(int q=0;q<4;q++){
      int gy=ty0+py0+(q>>1), gx=tx0+px0+(q&1);
      float v = acc[co][q]+bb;
      out[((size_t)(b*COUT+co0+co)*96+gy)*96+gx] = ACT ? geluf(v) : v;
    }
  }
}

// ---------------- ECA ----------------
__global__ void k_eca(const float* __restrict__ gap, const float* __restrict__ ew, float* __restrict__ s){
  int i = blockIdx.x*blockDim.x + threadIdx.x;
  if(i>=Bb*Cc) return;
  int b=i/Cc, c=i%Cc;
  float z=0.f;
  for(int j=0;j<5;j++){ int cc=c-2+j; if(cc>=0&&cc<Cc) z+=gap[b*Cc+cc]*ew[j]; }
  s[i]=sigm(z);
}

// ---------------- plk 13x13 conv (16->16) + fused dynamic depthwise 3x3 ----------------
__global__ void __launch_bounds__(256) k_plk(const float* __restrict__ ximg, const float* __restrict__ plk,
    const float* __restrict__ dkb, float* __restrict__ attn){
  __shared__ float tile[44*44];
  __shared__ float wl[169];
  __shared__ float dk9[9];
  int tile_id=blockIdx.x; int co=blockIdx.y; int b=blockIdx.z;
  int ty0=(tile_id/3)*32, tx0=(tile_id%3)*32;
  int t=threadIdx.x;
  int px0=(t%16)*2, py0=(t/16)*2;
  if(t<9) dk9[t]=dkb[b*144+co*9+t];
  float a00=0,a01=0,a10=0,a11=0;
  for(int ci=0;ci<PD;++ci){
    __syncthreads();
    for(int i=t;i<44*44;i+=256){
      int ly=i/44, lx=i%44;
      int gy=ty0+ly-6, gx=tx0+lx-6;
      float v=0.f;
      if((unsigned)gy<96u&&(unsigned)gx<96u) v=ximg[((size_t)(b*Cc+ci)*96+gy)*96+gx];
      tile[i]=v;
    }
    for(int i=t;i<169;i+=256) wl[i]=plk[((size_t)(co*PD+ci)*169)+i];
    __syncthreads();
    for(int rr2=0; rr2<14; ++rr2){
      float rowv[14];
      const float* trow = tile + (py0+rr2)*44 + px0;
#pragma unroll
      for(int i=0;i<14;i++) rowv[i]=trow[i];
      if(rr2<13){
        const float* wr = wl + rr2*13;
#pragma unroll
        for(int kx=0;kx<13;kx++){ float w=wr[kx]; a00+=w*rowv[kx]; a01+=w*rowv[kx+1]; }
      }
      if(rr2>=1){
        const float* wr = wl + (rr2-1)*13;
#pragma unroll
        for(int kx=0;kx<13;kx++){ float w=wr[kx]; a10+=w*rowv[kx]; a11+=w*rowv[kx+1]; }
      }
    }
    if(ci==co){
#pragma unroll
      for(int ky=0;ky<3;ky++)
#pragma unroll
        for(int kx=0;kx<3;kx++){
          float w=dk9[ky*3+kx];
          a00+=w*tile[(py0+5+ky)*44+px0+5+kx];
          a01+=w*tile[(py0+5+ky)*44+px0+6+kx];
          a10+=w*tile[(py0+6+ky)*44+px0+5+kx];
          a11+=w*tile[(py0+6+ky)*44+px0+6+kx];
        }
    }
  }
  int gy=ty0+py0, gx=tx0+px0;
  float* dst = attn + (size_t)(b*PD+co)*HWn;
  dst[gy*96+gx]=a00; dst[gy*96+gx+1]=a01; dst[(gy+1)*96+gx]=a10; dst[(gy+1)*96+gx+1]=a11;
}

// ---------------- aggr (180x180) + residual + conv_x scale -> xm (B,N,C) ----------------
__global__ void __launch_bounds__(256) k_aggr(const float* __restrict__ x, const float* __restrict__ attn,
   const float* __restrict__ ximg, const float* __restrict__ ycab, const float* __restrict__ aggw,
   const float* __restrict__ aggb, const float* __restrict__ s, float* __restrict__ xm){
  __shared__ float u[Cc*24];
  __shared__ float yc[Cc*24];
  __shared__ float ob[24*Cc];
  int b=blockIdx.x/384; int n0=(blockIdx.x%384)*24;
  int t=threadIdx.x;
  for(int i=t;i<Cc*24;i+=256){
    int c=i/24, p=i%24;
    u[i] = (c<PD)? attn[(size_t)(b*PD+c)*HWn + n0+p] : ximg[(size_t)(b*Cc+c)*HWn + n0+p];
    yc[i] = ycab[(size_t)(b*Cc+c)*HWn + n0+p];
  }
  __syncthreads();
  for(int o=t;o<24*Cc;o+=256){
    int d=o/24, p=o%24;
    const float* wr = aggw + (size_t)d*Cc;
    float a=0.f;
    for(int c=0;c<Cc;c++) a += wr[c]*u[c*24+p];
    a += aggb[d] + CONV_SCALE * s[b*Cc+d] * yc[d*24+p];
    ob[p*Cc+d]=a;
  }
  __syncthreads();
  size_t base = (size_t)(b*HWn+n0)*Cc;
  for(int i=t;i<24*Cc;i+=256) xm[base+i] = x[base+i] + ob[i];
}

// ---------------- LN2 row stats ----------------
__global__ void __launch_bounds__(256) k_ln2stats(const float* __restrict__ xm, float* __restrict__ mean, float* __restrict__ rstd){
  int w = (blockIdx.x*256 + threadIdx.x)>>6;
  int lane = threadIdx.x&63;
  const float* row = xm + (size_t)w*Cc;
  float s=0,sq=0;
  for(int e=lane;e<Cc;e+=64){ float v=row[e]; s+=v; sq+=v*v; }
  s=wredsum(s); sq=wredsum(sq);
  if(lane==0){
    float m=s*(1.0f/180.0f); float v=sq*(1.0f/180.0f)-m*m;
    mean[w]=m; rstd[w]=rsqrtf(v+EPSLN);
  }
}

// ---------------- fc1: t1[b,j,n] = (LN2(xm) @ fc1_w^T + b) -> bf16, 64x64 tile GEMM ----------------
__global__ void __launch_bounds__(256) k_fc1(const float* __restrict__ xm, const float* __restrict__ mean,
    const float* __restrict__ rstd, const float* __restrict__ g2, const float* __restrict__ b2,
    const float* __restrict__ fw, const float* __restrict__ fb, bf16* __restrict__ t1){
  __shared__ float Al[64*61];
  __shared__ float Wl[60*65];
  int rt = blockIdx.x;
  int ct = blockIdx.y;
  int t=threadIdx.x;
  int tr=t%16, tc=t/16;
  int r0=tr*4, j0=tc*4;
  float acc[4][4]={};
  int grow0 = rt*64;
  for(int k0=0;k0<180;k0+=60){
    __syncthreads();
    for(int i=t;i<64*60;i+=256){
      int r=i/60, kk=i%60;
      int gr=grow0+r;
      float v=xm[(size_t)gr*Cc+k0+kk];
      Al[r*61+kk]=(v-mean[gr])*rstd[gr]*g2[k0+kk]+b2[k0+kk];
    }
    for(int i=t;i<64*60;i+=256){
      int j=i/60, kk=i%60;
      int jc=ct*64+j;
      Wl[kk*65+j] = (jc<H2)? fw[(size_t)jc*Cc+k0+kk] : 0.f;
    }
    __syncthreads();
    for(int kk=0;kk<60;kk++){
      float av[4], wv[4];
#pragma unroll
      for(int i=0;i<4;i++) av[i]=Al[(r0+i)*61+kk];
#pragma unroll
      for(int j=0;j<4;j++) wv[j]=Wl[kk*65+j0+j];
#pragma unroll
      for(int i=0;i<4;i++)
#pragma unroll
        for(int j=0;j<4;j++) acc[i][j] += av[i]*wv[j];
    }
  }
#pragma unroll
  for(int i=0;i<4;i++){
    int gr=grow0+r0+i; int bb=gr/HWn; int n=gr%HWn;
#pragma unroll
    for(int j=0;j<4;j++){
      int jc=ct*64+j0+j;
      if(jc<H2) t1[((size_t)(bb*H2+jc))*HWn + n] = __float2bfloat16(acc[i][j]+fb[jc]);
    }
  }
}

// ---------------- depthwise 3x3 on t1 + GLU -> pg (B,360,HW) bf16 ----------------
__global__ void __launch_bounds__(256) k_dwglu(const bf16* __restrict__ t1, const float* __restrict__ dww,
    const float* __restrict__ dwb, bf16* __restrict__ pg){
  __shared__ float ta[34*34];
  __shared__ float tg[34*34];
  int tile_id=blockIdx.x; int c=blockIdx.y; int b=blockIdx.z;
  int ty0=(tile_id/3)*32, tx0=(tile_id%3)*32;
  int t=threadIdx.x;
  int px0=(t%16)*2, py0=(t/16)*2;
  for(int i=t;i<34*34;i+=256){
    int ly=i/34, lx=i%34; int gy=ty0+ly-1, gx=tx0+lx-1;
    bool ok=((unsigned)gy<96u&&(unsigned)gx<96u);
    ta[i]= ok? __bfloat162float(t1[((size_t)(b*H2+c)*96+gy)*96+gx]) :0.f;
    tg[i]= ok? __bfloat162float(t1[((size_t)(b*H2+c+HID)*96+gy)*96+gx]) :0.f;
  }
  __syncthreads();
  float wp[9],wg[9];
#pragma unroll
  for(int i=0;i<9;i++){ wp[i]=dww[c*9+i]; wg[i]=dww[(c+HID)*9+i]; }
  float bp=dwb[c], bg=dwb[c+HID];
#pragma unroll
  for(int oy=0;oy<2;oy++)
#pragma unroll
    for(int ox=0;ox<2;ox++){
      float p=bp,g=bg;
#pragma unroll
      for(int ky=0;ky<3;ky++)
#pragma unroll
        for(int kx=0;kx<3;kx++){
          p+=wp[ky*3+kx]*ta[(py0+oy+ky)*34+px0+ox+kx];
          g+=wg[ky*3+kx]*tg[(py0+oy+ky)*34+px0+ox+kx];
        }
      float val = p * g * sigm(g);
      pg[((size_t)(b*HID+c)*96 + ty0+py0+oy)*96 + tx0+px0+ox] = __float2bfloat16(val);
    }
}

// ---------------- fc2 + residual -> out (B,N,C) ----------------
__global__ void __launch_bounds__(256) k_fc2(const bf16* __restrict__ pg, const float* __restrict__ xm,
    const float* __restrict__ fw, const float* __restrict__ fb, float* __restrict__ out){
  __shared__ float Al[64*61];
  __shared__ float Wl[60*65];
  int rt=blockIdx.x; int ct=blockIdx.y;
  int t=threadIdx.x; int tr=t%16, tc=t/16;
  int r0=tr*4, j0=tc*4;
  float acc[4][4]={};
  int grow0=rt*64; int b=grow0/HWn; int n0=grow0%HWn;
  for(int k0=0;k0<360;k0+=60){
    __syncthreads();
    for(int i=t;i<60*64;i+=256){
      int kk=i/64, r=i%64;
      Al[r*61+kk]=__bfloat162float(pg[((size_t)(b*HID+k0+kk))*HWn + n0 + r]);
    }
    for(int i=t;i<64*60;i+=256){
      int j=i/60, kk=i%60;
      int jc=ct*64+j;
      Wl[kk*65+j]= (jc<Cc)? fw[(size_t)jc*HID + k0+kk] : 0.f;
    }
    __syncthreads();
    for(int kk=0;kk<60;kk++){
      float av[4], wv[4];
#pragma unroll
      for(int i=0;i<4;i++) av[i]=Al[(r0+i)*61+kk];
#pragma unroll
      for(int j=0;j<4;j++) wv[j]=Wl[kk*65+j0+j];
#pragma unroll
      for(int i=0;i<4;i++)
#pragma unroll
        for(int j=0;j<4;j++) acc[i][j] += av[i]*wv[j];
    }
  }
#pragma unroll
  for(int i=0;i<4;i++){
    int gr=grow0+r0+i;
#pragma unroll
    for(int j=0;j<4;j++){
      int jc=ct*64+j0+j;
      if(jc<Cc){ size_t o=(size_t)gr*Cc+jc; out[o]=xm[o]+acc[i][j]+fb[jc]; }
    }
  }
}

extern "C" void kernel_launch(void* const* d_in, const int* in_sizes, int n_in,
                              void* d_out, int out_size, void* d_ws, size_t ws_size,
                              hipStream_t stream){
  (void)in_sizes; (void)n_in; (void)out_size; (void)ws_size;
  const float* x     = (const float*)d_in[0];
  const float* ln1_g = (const float*)d_in[3];
  const float* ln1_b = (const float*)d_in[4];
  const float* band_w= (const float*)d_in[5];
  const float* band_b= (const float*)d_in[6];
  const float* gate_w= (const float*)d_in[7];
  const float* gate_b= (const float*)d_in[8];
  const float* cab_w1= (const float*)d_in[9];
  const float* cab_b1= (const float*)d_in[10];
  const float* cab_w2= (const float*)d_in[11];
  const float* cab_b2= (const float*)d_in[12];
  const float* eca_w = (const float*)d_in[13];
  const float* plkw  = (const float*)d_in[14];
  const float* dwc_w1= (const float*)d_in[15];
  const float* dwc_b1= (const float*)d_in[16];
  const float* dwc_w2= (const float*)d_in[17];
  const float* dwc_b2= (const float*)d_in[18];
  const float* aggr_w= (const float*)d_in[19];
  const float* aggr_b= (const float*)d_in[20];
  const float* ln2_g = (const float*)d_in[21];
  const float* ln2_b = (const float*)d_in[22];
  const float* fc1_w = (const float*)d_in[23];
  const float* fc1_b = (const float*)d_in[24];
  const float* dw_w  = (const float*)d_in[25];
  const float* dw_b  = (const float*)d_in[26];
  const float* fc2_w = (const float*)d_in[27];
  const float* fc2_b = (const float*)d_in[28];

  float* ws = (float*)d_ws;
  // persistent region
  float* xm   = ws;                     // 13,271,040
  float* meanb= ws + 13271040;          // 73,728
  float* rstdb= meanb + 73728;          // 73,728
  float* m1   = ws + 13418496;          // 1,440
  float* gates= m1 + 1440;              // 24 (+pad 8)
  float* dkb  = gates + 32;             // 1,152
  float* biasb= dkb + 1152;             // 1,440
  float* gapb = biasb + 1440;           // 1,440
  float* svec = gapb + 1440;            // 1,440
  float* big  = ws + 13425664;
  // phase 1 (FFT + convs) inside big:
  float* ximg = big;                    // 13,271,040
  float* spec = big + 13271040;         // 13,547,520 (1440 planes x 9408; xfft lives in first 9216 of each plane)
  float* mid  = big + 26818560;         // 4,423,680
  float* attn = big + 31242240;         // 1,179,648  -> phase-1 top = big + 32,421,888
  float* ycab = spec;                   // reuse (stride 9216), spec dead after conv1
  // phase 2 aliases big (phase-1 all dead):
  bf16* t1 = (bf16*)big;                        // 53,084,160 bf16 = 26,542,080 float slots
  bf16* pgb= (bf16*)(big + 26542080);           // 26,542,080 bf16 = 13,271,040 float slots
  // total ws usage: 13,425,664 + 39,813,120 floats = 53,238,784 floats = 213 MB

  k_ln1<<<2304,256,0,stream>>>(x, ln1_g, ln1_b, ximg);
  k_plane_mean<<<1440,256,0,stream>>>(ximg, m1);
  k_small<<<1,64,0,stream>>>(m1, gate_w, gate_b, dwc_w1, dwc_b1, dwc_w2, dwc_b2, band_b, gates, dkb, biasb);
  k_fwd_x<<<1440,256,0,stream>>>(ximg, spec);
  k_fwd_y<<<1440,256,0,stream>>>(spec);
  k_bandmix<<<dim3(Bb,96,2),256,0,stream>>>(spec, band_w, gates);
  k_inv_y<<<1440,256,0,stream>>>(spec);
  k_inv_x<<<1440,256,0,stream>>>(spec, ximg, biasb);
  k_conv3<Cc,true ><<<dim3(9,15,8),256,0,stream>>>(spec, cab_w1, cab_b1, mid, CRr, SPL);
  k_conv3<CRr,false><<<dim3(9,45,8),256,0,stream>>>(mid, cab_w2, cab_b2, ycab, Cc, HWn);
  k_plane_mean<<<1440,256,0,stream>>>(ycab, gapb);
  k_eca<<<6,256,0,stream>>>(gapb, eca_w, svec);
  k_plk<<<dim3(9,PD,Bb),256,0,stream>>>(ximg, plkw, dkb, attn);
  k_aggr<<<3072,256,0,stream>>>(x, attn, ximg, ycab, aggr_w, aggr_b, svec, xm);
  k_ln2stats<<<18432,256,0,stream>>>(xm, meanb, rstdb);
  k_fc1<<<dim3(1152,12),256,0,stream>>>(xm, meanb, rstdb, ln2_g, ln2_b, fc1_w, fc1_b, t1);
  k_dwglu<<<dim3(9,HID,Bb),256,0,stream>>>(t1, dw_w, dw_b, pgb);
  k_fc2<<<dim3(1152,3),256,0,stream>>>(pgb, xm, fc2_w, fc2_b, (float*)d_out);
}

// Round 3
// 3344.143 us; speedup vs baseline: 1.0862x; 1.0862x over previous
//
#include <hip/hip_runtime.h>
#include <hip/hip_bf16.h>
#include <math.h>

#define Bb 8
#define Cc 180
#define HWn 9216
#define PD 16
#define CRr 60
#define HID 360
#define H2 720
#define NF 49
#define SPL 9408   /* spectral plane stride in floats: 96*49*2 */
#define CONV_SCALE 0.01f
#define FFT_RES 0.15f
#define EPSLN 1e-5f
#define TWOPI_96 0.06544984694978735f

typedef __hip_bfloat16 bf16;
typedef unsigned short ushort;
typedef __attribute__((ext_vector_type(8))) short s8v;   // 8 bf16 (4 VGPRs) MFMA A/B frag
typedef __attribute__((ext_vector_type(4))) float f4v;   // MFMA C/D frag

__device__ __forceinline__ float geluf(float x){ return 0.5f*x*(1.0f+erff(x*0.7071067811865476f)); }
__device__ __forceinline__ float sigm(float x){ return 1.0f/(1.0f+expf(-x)); }
__device__ __forceinline__ short f2bf(float f){
  unsigned u = __float_as_uint(f);
  u += 0x7fff + ((u>>16)&1);
  return (short)(u>>16);
}
__device__ __forceinline__ float wredsum(float v){
#pragma unroll
  for(int m=1;m<64;m<<=1) v += __shfl_xor(v,m,64);
  return v;
}

// ---------------- LN1 + transpose to (B,C,H,W) ----------------
__global__ void __launch_bounds__(256) k_ln1(const float* __restrict__ x, const float* __restrict__ g,
                      const float* __restrict__ be, float* __restrict__ ximg){
  __shared__ float sb[32*Cc];
  int b = blockIdx.x / 288;
  int n0 = (blockIdx.x % 288) * 32;
  int t = threadIdx.x;
  const float* src = x + (size_t)(b*HWn + n0)*Cc;
  for(int i=t;i<32*Cc;i+=256) sb[i]=src[i];
  __syncthreads();
  int w = t>>6, lane = t&63;
  for(int pi=0; pi<8; ++pi){
    int p = w*8+pi;
    float s=0.f, sq=0.f;
    for(int e=lane;e<Cc;e+=64){ float v=sb[p*Cc+e]; s+=v; sq+=v*v; }
    s = wredsum(s); sq = wredsum(sq);
    float mean = s*(1.0f/180.0f);
    float var = sq*(1.0f/180.0f) - mean*mean;
    float rstd = rsqrtf(var + EPSLN);
    for(int e=lane;e<Cc;e+=64){ float v=sb[p*Cc+e]; sb[p*Cc+e] = (v-mean)*rstd*g[e]+be[e]; }
  }
  __syncthreads();
  for(int i=t;i<32*Cc;i+=256){
    int c = i/32, p = i%32;
    ximg[(size_t)(b*Cc+c)*HWn + n0 + p] = sb[p*Cc+c];
  }
}

// ---------------- plane mean (9216 -> 1) ----------------
__global__ void __launch_bounds__(256) k_plane_mean(const float* __restrict__ in, float* __restrict__ out){
  __shared__ float red[4];
  int pl = blockIdx.x; int t = threadIdx.x;
  const float* p = in + (size_t)pl*HWn;
  float s=0.f;
  for(int i=t;i<HWn;i+=256) s+=p[i];
  s = wredsum(s);
  if((t&63)==0) red[t>>6]=s;
  __syncthreads();
  if(t==0) out[pl] = (red[0]+red[1]+red[2]+red[3]) * (1.0f/9216.0f);
}

// ---------------- small: gates, hdn->dk, fft bias ----------------
__global__ void k_small(const float* __restrict__ m1, const float* __restrict__ gate_w,
   const float* __restrict__ gate_b, const float* __restrict__ dwc_w1, const float* __restrict__ dwc_b1,
   const float* __restrict__ dwc_w2, const float* __restrict__ dwc_b2, const float* __restrict__ band_b,
   float* __restrict__ gates, float* __restrict__ dkb, float* __restrict__ biasb){
  int b = threadIdx.x;
  if(b>=Bb) return;
  const float* m = m1 + b*Cc;
  float gv[3];
  for(int k=0;k<3;k++){ float a=gate_b[k]; for(int c=0;c<Cc;c++) a+=m[c]*gate_w[k*Cc+c]; gv[k]=sigm(a);}
  float e0=expf(gv[0]), e1=expf(gv[1]), e2=expf(gv[2]); float inv=1.0f/(e0+e1+e2);
  float g0=e0*inv,g1=e1*inv,g2=e2*inv;
  gates[b*3+0]=g0; gates[b*3+1]=g1; gates[b*3+2]=g2;
  float hd[8];
  for(int j=0;j<8;j++){ float a=dwc_b1[j]; for(int c=0;c<PD;c++) a+=m[c]*dwc_w1[j*PD+c]; hd[j]=geluf(a);}
  for(int i=0;i<144;i++){ float a=dwc_b2[i]; for(int j=0;j<8;j++) a+=hd[j]*dwc_w2[i*8+j]; dkb[b*144+i]=a; }
  for(int d=0;d<Cc;d++) biasb[b*Cc+d] = g0*band_b[0*Cc+d]+g1*band_b[1*Cc+d]+g2*band_b[2*Cc+d];
}

// ---------------- forward DFT along x (real -> complex, 49 freqs) ----------------
__global__ void __launch_bounds__(256) k_fwd_x(const float* __restrict__ ximg, float* __restrict__ V){
  __shared__ float img[HWn];
  __shared__ float cs[96], sn[96];
  int bc = blockIdx.x; int t = threadIdx.x;
  const float* src = ximg + (size_t)bc*HWn;
  for(int i=t;i<HWn;i+=256) img[i]=src[i];
  if(t<96){ float th = (float)t * TWOPI_96; cs[t]=cosf(th); sn[t]=sinf(th); }
  __syncthreads();
  float* dst = V + (size_t)bc*SPL;
  for(int o=t;o<96*NF;o+=256){
    int y=o/NF, kx=o%NF;
    float re=0.f, im=0.f; int m=0;
    const float* row = img + y*96;
    for(int xx=0; xx<96; ++xx){
      float v=row[xx];
      re += v*cs[m]; im -= v*sn[m];
      m += kx; if(m>=96) m-=96;
    }
    dst[o*2]=re; dst[o*2+1]=im;
  }
}

// ---------------- forward DFT along y (complex -> complex), ortho 1/96, IN-PLACE ----------------
__global__ void __launch_bounds__(256) k_fwd_y(float* __restrict__ S){
  __shared__ float vb[SPL];
  __shared__ float cs[96], sn[96];
  int bc=blockIdx.x, t=threadIdx.x;
  float* pl = S + (size_t)bc*SPL;
  for(int i=t;i<SPL;i+=256) vb[i]=pl[i];
  if(t<96){ float th = (float)t * TWOPI_96; cs[t]=cosf(th); sn[t]=sinf(th); }
  __syncthreads();
  for(int o=t;o<96*NF;o+=256){
    int ky=o/NF, kx=o%NF;
    float re=0.f, im=0.f; int m=0;
    for(int y=0;y<96;++y){
      float vr=vb[(y*NF+kx)*2], vi=vb[(y*NF+kx)*2+1];
      float c=cs[m], s=sn[m];
      re += vr*c + vi*s;
      im += vi*c - vr*s;
      m += ky; if(m>=96) m-=96;
    }
    pl[o*2]=re*(1.0f/96.0f); pl[o*2+1]=im*(1.0f/96.0f);
  }
}

// ---------------- per-frequency band channel mix: Y = g_bk * W_k @ X, IN-PLACE ----------------
__global__ void __launch_bounds__(256) k_bandmix(float* __restrict__ S, const float* __restrict__ band_w,
                          const float* __restrict__ gates){
  __shared__ float xs[Cc*50];
  int b = blockIdx.x; int ky = blockIdx.y; int half = blockIdx.z;
  int kx0 = half*25; int nkx = half? 24:25;
  int t=threadIdx.x;
  for(int i=t;i<Cc*nkx*2;i+=256){
    int c = i/(nkx*2); int r = i%(nkx*2);
    xs[c*50+r] = S[ (size_t)(b*Cc+c)*SPL + ky*(NF*2) + kx0*2 + r ];
  }
  __syncthreads();
  float yy = -1.0f + 2.0f*(float)ky/95.0f;
  for(int o=t;o<Cc*nkx;o+=256){
    int d = o/nkx, kxl = o%nkx; int kx = kx0+kxl;
    float xxf = (float)kx/48.0f;
    float rr = sqrtf(yy*yy+xxf*xxf);
    int k = (rr<=0.25f)?0:((rr<=0.6f)?1:2);
    float g = gates[b*3+k];
    const float* wr = band_w + ((size_t)k*Cc + d)*Cc;
    float re=0.f, im=0.f;
    for(int c=0;c<Cc;++c){
      float w=wr[c];
      re += w*xs[c*50 + kxl*2];
      im += w*xs[c*50 + kxl*2 + 1];
    }
    size_t off = (size_t)(b*Cc+d)*SPL + ky*(NF*2) + kx*2;
    S[off]=g*re; S[off+1]=g*im;
  }
}

// ---------------- inverse DFT along ky (complex -> complex, e^{+i}), IN-PLACE ----------------
__global__ void __launch_bounds__(256) k_inv_y(float* __restrict__ S){
  __shared__ float vb[SPL];
  __shared__ float cs[96], sn[96];
  int bd=blockIdx.x, t=threadIdx.x;
  float* pl = S + (size_t)bd*SPL;
  for(int i=t;i<SPL;i+=256) vb[i]=pl[i];
  if(t<96){ float th = (float)t * TWOPI_96; cs[t]=cosf(th); sn[t]=sinf(th); }
  __syncthreads();
  for(int o=t;o<96*NF;o+=256){
    int y=o/NF, kx=o%NF;
    float re=0.f, im=0.f; int m=0;
    for(int ky=0;ky<96;++ky){
      float vr=vb[(ky*NF+kx)*2], vi=vb[(ky*NF+kx)*2+1];
      float c=cs[m], s=sn[m];
      re += vr*c - vi*s;
      im += vr*s + vi*c;
      m += y; if(m>=96) m-=96;
    }
    pl[o*2]=re; pl[o*2+1]=im;
  }
}

// -------- inverse rDFT along kx + combine, IN-PLACE into spec plane (first 9216 floats) --------
__global__ void __launch_bounds__(256) k_inv_x(float* __restrict__ S, const float* __restrict__ ximg,
                        const float* __restrict__ biasb){
  __shared__ float tb[SPL];
  __shared__ float cs[96], sn[96];
  int bd = blockIdx.x; int t=threadIdx.x;
  int b = bd / Cc; int d = bd % Cc;
  float* pl = S + (size_t)bd*SPL;
  for(int i=t;i<SPL;i+=256) tb[i]=pl[i];
  if(t<96){ float th = (float)t * TWOPI_96; cs[t]=cosf(th); sn[t]=sinf(th); }
  __syncthreads();
  float bias = biasb[b*Cc+d];
  const float* xs = ximg + (size_t)bd*HWn;
  for(int o=t;o<HWn;o+=256){
    int y=o/96, xx=o%96;
    float acc=0.f; int m=0;
    const float* row = tb + y*(NF*2);
    for(int kx=0;kx<NF;++kx){
      float wgt = (kx==0||kx==48)?1.0f:2.0f;
      acc += wgt*(row[kx*2]*cs[m] - row[kx*2+1]*sn[m]);
      m += xx; if(m>=96) m-=96;
    }
    pl[o] = xs[o] + FFT_RES*(acc*(1.0f/96.0f) + bias);
  }
}

// ---------------- 3x3 conv, LDS tile, 2x2 px/thread, 4 co/block ----------------
template<int CIN, bool ACT>
__global__ void __launch_bounds__(256) k_conv3(const float* __restrict__ xin, const float* __restrict__ wgt,
    const float* __restrict__ bias, float* __restrict__ out, int COUT, int istride){
  __shared__ float tile[34*34];
  __shared__ float wl[36];
  int tile_id = blockIdx.x;
  int co0 = blockIdx.y*4;
  int b = blockIdx.z;
  int ty0 = (tile_id/3)*32, tx0 = (tile_id%3)*32;
  int t=threadIdx.x;
  int px0 = (t%16)*2, py0 = (t/16)*2;
  float acc[4][4]={};
  for(int ci=0; ci<CIN; ++ci){
    __syncthreads();
    for(int i=t;i<34*34;i+=256){
      int ly=i/34, lx=i%34;
      int gy=ty0+ly-1, gx=tx0+lx-1;
      float v=0.f;
      if((unsigned)gy<96u && (unsigned)gx<96u) v = xin[(size_t)(b*CIN+ci)*istride + gy*96+gx];
      tile[i]=v;
    }
    if(t<36) wl[t] = wgt[ ((size_t)(co0 + t/9)*CIN + ci)*9 + (t%9) ];
    __syncthreads();
    float r[4][4];
#pragma unroll
    for(int dy=0;dy<4;dy++)
#pragma unroll
      for(int dx=0;dx<4;dx++) r[dy][dx]=tile[(py0+dy)*34+px0+dx];
#pragma unroll
    for(int co=0;co<4;co++){
#pragma unroll
      for(int ky=0;ky<3;ky++)
#pragma unroll
        for(int kx=0;kx<3;kx++){
          float w=wl[co*9+ky*3+kx];
          acc[co][0]+=w*r[ky][kx];   acc[co][1]+=w*r[ky][kx+1];
          acc[co][2]+=w*r[ky+1][kx]; acc[co][3]+=w*r[ky+1][kx+1];
        }
    }
  }
#pragma unroll
  for(int co=0;co<4;co++){
    float bb = bias[co0+co];
#pragma unroll
    for(int q=0;q<4;q++){
      int gy=ty0+py0+(q>>1), gx=tx0+px0+(q&1);
      float v = acc[co][q]+bb;
      out[((size_t)(b*COUT+co0+co)*96+gy)*96+gx] = ACT ? geluf(v) : v;
    }
  }
}

// ---------------- ECA ----------------
__global__ void k_eca(const float* __restrict__ gap, const float* __restrict__ ew, float* __restrict__ s){
  int i = blockIdx.x*blockDim.x + threadIdx.x;
  if(i>=Bb*Cc) return;
  int b=i/Cc, c=i%Cc;
  float z=0.f;
  for(int j=0;j<5;j++){ int cc=c-2+j; if(cc>=0&&cc<Cc) z+=gap[b*Cc+cc]*ew[j]; }
  s[i]=sigm(z);
}

// ---------------- plk 13x13 conv (16->16) + fused dynamic depthwise 3x3 ----------------
__global__ void __launch_bounds__(256) k_plk(const float* __restrict__ ximg, const float* __restrict__ plk,
    const float* __restrict__ dkb, float* __restrict__ attn){
  __shared__ float tile[44*44];
  __shared__ float wl[169];
  __shared__ float dk9[9];
  int tile_id=blockIdx.x; int co=blockIdx.y; int b=blockIdx.z;
  int ty0=(tile_id/3)*32, tx0=(tile_id%3)*32;
  int t=threadIdx.x;
  int px0=(t%16)*2, py0=(t/16)*2;
  if(t<9) dk9[t]=dkb[b*144+co*9+t];
  float a00=0,a01=0,a10=0,a11=0;
  for(int ci=0;ci<PD;++ci){
    __syncthreads();
    for(int i=t;i<44*44;i+=256){
      int ly=i/44, lx=i%44;
      int gy=ty0+ly-6, gx=tx0+lx-6;
      float v=0.f;
      if((unsigned)gy<96u&&(unsigned)gx<96u) v=ximg[((size_t)(b*Cc+ci)*96+gy)*96+gx];
      tile[i]=v;
    }
    for(int i=t;i<169;i+=256) wl[i]=plk[((size_t)(co*PD+ci)*169)+i];
    __syncthreads();
    for(int rr2=0; rr2<14; ++rr2){
      float rowv[14];
      const float* trow = tile + (py0+rr2)*44 + px0;
#pragma unroll
      for(int i=0;i<14;i++) rowv[i]=trow[i];
      if(rr2<13){
        const float* wr = wl + rr2*13;
#pragma unroll
        for(int kx=0;kx<13;kx++){ float w=wr[kx]; a00+=w*rowv[kx]; a01+=w*rowv[kx+1]; }
      }
      if(rr2>=1){
        const float* wr = wl + (rr2-1)*13;
#pragma unroll
        for(int kx=0;kx<13;kx++){ float w=wr[kx]; a10+=w*rowv[kx]; a11+=w*rowv[kx+1]; }
      }
    }
    if(ci==co){
#pragma unroll
      for(int ky=0;ky<3;ky++)
#pragma unroll
        for(int kx=0;kx<3;kx++){
          float w=dk9[ky*3+kx];
          a00+=w*tile[(py0+5+ky)*44+px0+5+kx];
          a01+=w*tile[(py0+5+ky)*44+px0+6+kx];
          a10+=w*tile[(py0+6+ky)*44+px0+5+kx];
          a11+=w*tile[(py0+6+ky)*44+px0+6+kx];
        }
    }
  }
  int gy=ty0+py0, gx=tx0+px0;
  float* dst = attn + (size_t)(b*PD+co)*HWn;
  dst[gy*96+gx]=a00; dst[gy*96+gx+1]=a01; dst[(gy+1)*96+gx]=a10; dst[(gy+1)*96+gx+1]=a11;
}

// ---------------- aggr (180x180) + residual + conv_x scale -> xm (B,N,C) ----------------
__global__ void __launch_bounds__(256) k_aggr(const float* __restrict__ x, const float* __restrict__ attn,
   const float* __restrict__ ximg, const float* __restrict__ ycab, const float* __restrict__ aggw,
   const float* __restrict__ aggb, const float* __restrict__ s, float* __restrict__ xm){
  __shared__ float u[Cc*24];
  __shared__ float yc[Cc*24];
  __shared__ float ob[24*Cc];
  int b=blockIdx.x/384; int n0=(blockIdx.x%384)*24;
  int t=threadIdx.x;
  for(int i=t;i<Cc*24;i+=256){
    int c=i/24, p=i%24;
    u[i] = (c<PD)? attn[(size_t)(b*PD+c)*HWn + n0+p] : ximg[(size_t)(b*Cc+c)*HWn + n0+p];
    yc[i] = ycab[(size_t)(b*Cc+c)*HWn + n0+p];
  }
  __syncthreads();
  for(int o=t;o<24*Cc;o+=256){
    int d=o/24, p=o%24;
    const float* wr = aggw + (size_t)d*Cc;
    float a=0.f;
    for(int c=0;c<Cc;c++) a += wr[c]*u[c*24+p];
    a += aggb[d] + CONV_SCALE * s[b*Cc+d] * yc[d*24+p];
    ob[p*Cc+d]=a;
  }
  __syncthreads();
  size_t base = (size_t)(b*HWn+n0)*Cc;
  for(int i=t;i<24*Cc;i+=256) xm[base+i] = x[base+i] + ob[i];
}

// ---------------- LN2 fused: stats + normalize + bf16 cast, K padded 180->192 ----------------
__global__ void __launch_bounds__(256) k_ln2(const float* __restrict__ xm, const float* __restrict__ g2,
    const float* __restrict__ b2, ushort* __restrict__ xn2){
  int w = (blockIdx.x*256 + threadIdx.x)>>6;
  int lane = threadIdx.x&63;
  const float* row = xm + (size_t)w*Cc;
  float s=0,sq=0;
  for(int e=lane;e<Cc;e+=64){ float v=row[e]; s+=v; sq+=v*v; }
  s=wredsum(s); sq=wredsum(sq);
  float m=s*(1.0f/180.0f); float v=sq*(1.0f/180.0f)-m*m;
  float rstd=rsqrtf(v+EPSLN);
  ushort* orow = xn2 + (size_t)w*192;
  for(int e=lane;e<192;e+=64){
    float val = (e<Cc)? (row[e]-m)*rstd*g2[e]+b2[e] : 0.f;
    orow[e] = (ushort)f2bf(val);
  }
}

// ---------------- fc1 MFMA: t1[j][n] = xn2 @ fc1_w^T + fb  (bf16 out) ----------------
__global__ void __launch_bounds__(256) k_fc1(const ushort* __restrict__ xn2,
    const float* __restrict__ fw, const float* __restrict__ fb, ushort* __restrict__ t1){
  __shared__ short As[64*200];
  __shared__ short Ws[64*200];
  int rt = blockIdx.x, ct = blockIdx.y;
  int t = threadIdx.x;
  int w = t>>6, lane = t&63, kq = lane>>4, lr = lane&15;
  int grow0 = rt*64;
  // stage A: 64 rows x 192 K (bf16, pre-padded), vector loads
  for(int i=t;i<64*24;i+=256){
    int r=i/24, seg=i%24;
    *(s8v*)&As[r*200+seg*8] = *(const s8v*)&xn2[(size_t)(grow0+r)*192 + seg*8];
  }
  // stage W: 64 j x 180 K fp32 -> bf16 (pad to 192)
  for(int i=t;i<64*192;i+=256){
    int j=i/192, kk=i%192;
    int jc=ct*64+j;
    float v = (jc<H2 && kk<Cc)? fw[(size_t)jc*Cc+kk] : 0.f;
    Ws[j*200+kk]=f2bf(v);
  }
  __syncthreads();
  f4v acc[4]={};
  int arow=(w*16+lr)*200 + kq*8;
#pragma unroll
  for(int k0=0;k0<192;k0+=32){
    s8v af = *(const s8v*)&As[arow+k0];
#pragma unroll
    for(int ts=0;ts<4;ts++){
      s8v wf = *(const s8v*)&Ws[(ts*16+lr)*200 + kq*8 + k0];
      acc[ts]=__builtin_amdgcn_mfma_f32_16x16x32_bf16(af,wf,acc[ts],0,0,0);
    }
  }
  __syncthreads();
  // transpose C through LDS (reuse Ws): cT[j][m], stride 72
  short* cT = Ws;
#pragma unroll
  for(int ts=0;ts<4;ts++){
    int j = ts*16+lr;
    float bb = fb[ct*64+j < H2 ? ct*64+j : 0];
#pragma unroll
    for(int reg=0;reg<4;reg++){
      int m = w*16 + kq*4 + reg;
      cT[j*72+m] = f2bf(acc[ts][reg]+bb);
    }
  }
  __syncthreads();
  int bb_ = grow0/HWn, n0 = grow0%HWn;
  for(int i=t;i<4096;i+=256){
    int j=i>>6, m=i&63;
    int jc=ct*64+j;
    if(jc<H2) t1[((size_t)(bb_*H2+jc))*HWn + n0 + m] = (ushort)cT[j*72+m];
  }
}

// ---------------- depthwise 3x3 on t1 + GLU -> pg (B,360,HW) bf16 ----------------
__global__ void __launch_bounds__(256) k_dwglu(const bf16* __restrict__ t1, const float* __restrict__ dww,
    const float* __restrict__ dwb, bf16* __restrict__ pg){
  __shared__ float ta[34*34];
  __shared__ float tg[34*34];
  int tile_id=blockIdx.x; int c=blockIdx.y; int b=blockIdx.z;
  int ty0=(tile_id/3)*32, tx0=(tile_id%3)*32;
  int t=threadIdx.x;
  int px0=(t%16)*2, py0=(t/16)*2;
  for(int i=t;i<34*34;i+=256){
    int ly=i/34, lx=i%34; int gy=ty0+ly-1, gx=tx0+lx-1;
    bool ok=((unsigned)gy<96u&&(unsigned)gx<96u);
    ta[i]= ok? __bfloat162float(t1[((size_t)(b*H2+c)*96+gy)*96+gx]) :0.f;
    tg[i]= ok? __bfloat162float(t1[((size_t)(b*H2+c+HID)*96+gy)*96+gx]) :0.f;
  }
  __syncthreads();
  float wp[9],wg[9];
#pragma unroll
  for(int i=0;i<9;i++){ wp[i]=dww[c*9+i]; wg[i]=dww[(c+HID)*9+i]; }
  float bp=dwb[c], bg=dwb[c+HID];
#pragma unroll
  for(int oy=0;oy<2;oy++)
#pragma unroll
    for(int ox=0;ox<2;ox++){
      float p=bp,g=bg;
#pragma unroll
      for(int ky=0;ky<3;ky++)
#pragma unroll
        for(int kx=0;kx<3;kx++){
          p+=wp[ky*3+kx]*ta[(py0+oy+ky)*34+px0+ox+kx];
          g+=wg[ky*3+kx]*tg[(py0+oy+ky)*34+px0+ox+kx];
        }
      float val = p * g * sigm(g);
      pg[((size_t)(b*HID+c)*96 + ty0+py0+oy)*96 + tx0+px0+ox] = __float2bfloat16(val);
    }
}

// ---------------- fc2 MFMA + residual -> out (B,N,C) ----------------
__global__ void __launch_bounds__(256) k_fc2(const ushort* __restrict__ pg, const float* __restrict__ xm,
    const float* __restrict__ fw, const float* __restrict__ fb, float* __restrict__ out){
  __shared__ short As[64*200];
  __shared__ short Ws[64*200];
  int rt = blockIdx.x, ct = blockIdx.y;
  int t = threadIdx.x;
  int w = t>>6, lane = t&63, kq = lane>>4, lr = lane&15;
  int grow0 = rt*64; int b = grow0/HWn; int n0 = grow0%HWn;
  f4v acc[4]={};
  for(int kc0=0;kc0<384;kc0+=192){
    __syncthreads();
    // stage A (transpose): As[r][kk] = pg[h=kc0+kk][n0+r]
    for(int i=t;i<192*64;i+=256){
      int kk=i/64, r=i%64;
      int kc=kc0+kk;
      As[r*200+kk] = (kc<HID)? (short)pg[((size_t)(b*HID+kc))*HWn + n0 + r] : (short)0;
    }
    // stage W
    for(int i=t;i<64*192;i+=256){
      int j=i/192, kk=i%192;
      int jc=ct*64+j; int kc=kc0+kk;
      float v = (jc<Cc && kc<HID)? fw[(size_t)jc*HID+kc] : 0.f;
      Ws[j*200+kk]=f2bf(v);
    }
    __syncthreads();
    int arow=(w*16+lr)*200 + kq*8;
#pragma unroll
    for(int k0=0;k0<192;k0+=32){
      s8v af = *(const s8v*)&As[arow+k0];
#pragma unroll
      for(int ts=0;ts<4;ts++){
        s8v wf = *(const s8v*)&Ws[(ts*16+lr)*200 + kq*8 + k0];
        acc[ts]=__builtin_amdgcn_mfma_f32_16x16x32_bf16(af,wf,acc[ts],0,0,0);
      }
    }
  }
#pragma unroll
  for(int ts=0;ts<4;ts++){
    int jc = ct*64 + ts*16 + lr;
    if(jc>=Cc) continue;
    float bb = fb[jc];
#pragma unroll
    for(int reg=0;reg<4;reg++){
      int m = w*16 + kq*4 + reg;
      size_t o = (size_t)(grow0+m)*Cc + jc;
      out[o] = xm[o] + acc[ts][reg] + bb;
    }
  }
}

extern "C" void kernel_launch(void* const* d_in, const int* in_sizes, int n_in,
                              void* d_out, int out_size, void* d_ws, size_t ws_size,
                              hipStream_t stream){
  (void)in_sizes; (void)n_in; (void)out_size; (void)ws_size;
  const float* x     = (const float*)d_in[0];
  const float* ln1_g = (const float*)d_in[3];
  const float* ln1_b = (const float*)d_in[4];
  const float* band_w= (const float*)d_in[5];
  const float* band_b= (const float*)d_in[6];
  const float* gate_w= (const float*)d_in[7];
  const float* gate_b= (const float*)d_in[8];
  const float* cab_w1= (const float*)d_in[9];
  const float* cab_b1= (const float*)d_in[10];
  const float* cab_w2= (const float*)d_in[11];
  const float* cab_b2= (const float*)d_in[12];
  const float* eca_w = (const float*)d_in[13];
  const float* plkw  = (const float*)d_in[14];
  const float* dwc_w1= (const float*)d_in[15];
  const float* dwc_b1= (const float*)d_in[16];
  const float* dwc_w2= (const float*)d_in[17];
  const float* dwc_b2= (const float*)d_in[18];
  const float* aggr_w= (const float*)d_in[19];
  const float* aggr_b= (const float*)d_in[20];
  const float* ln2_g = (const float*)d_in[21];
  const float* ln2_b = (const float*)d_in[22];
  const float* fc1_w = (const float*)d_in[23];
  const float* fc1_b = (const float*)d_in[24];
  const float* dw_w  = (const float*)d_in[25];
  const float* dw_b  = (const float*)d_in[26];
  const float* fc2_w = (const float*)d_in[27];
  const float* fc2_b = (const float*)d_in[28];

  float* ws = (float*)d_ws;
  // persistent region
  float* xm   = ws;                     // 13,271,040
  float* m1   = ws + 13271040;          // 1,440
  float* gates= m1 + 1440;              // 32
  float* dkb  = gates + 32;             // 1,152
  float* biasb= dkb + 1152;             // 1,440
  float* gapb = biasb + 1440;           // 1,440
  float* svec = gapb + 1440;            // 1,440
  float* big  = ws + 13279232;
  // phase 1 (FFT + convs) inside big:
  float* ximg = big;                    // 13,271,040
  float* spec = big + 13271040;         // 13,547,520 (xfft lives in first 9216 of each 9408 plane)
  float* mid  = big + 26818560;         // 4,423,680
  float* attn = big + 31242240;         // 1,179,648  -> phase-1 top = 32,421,888
  float* ycab = spec;                   // reuse (stride 9216), spec dead after conv1
  // phase 2 aliases big:
  ushort* t1  = (ushort*)big;                      // 53,084,160 bf16 = 26,542,080 float slots
  float*  reg2= big + 26542080;
  ushort* xn2 = (ushort*)reg2;                     // 14,155,776 bf16 (lives ln2->fc1)
  ushort* pgb = (ushort*)reg2;                     // 26,542,080 bf16 (lives dwglu->fc2; xn2 dead)
  // phase-2 top = 26,542,080 + 14,155,776/2 = 33,619,968 float slots; big = max = 40,697,856? no:
  // xn2 = 7,077,888 float slots; pg = 13,271,040 float slots -> region2 = 13,271,040
  // total = 13,279,232 + 39,813,120 = 53,092,352 floats (~212 MB)

  k_ln1<<<2304,256,0,stream>>>(x, ln1_g, ln1_b, ximg);
  k_plane_mean<<<1440,256,0,stream>>>(ximg, m1);
  k_small<<<1,64,0,stream>>>(m1, gate_w, gate_b, dwc_w1, dwc_b1, dwc_w2, dwc_b2, band_b, gates, dkb, biasb);
  k_fwd_x<<<1440,256,0,stream>>>(ximg, spec);
  k_fwd_y<<<1440,256,0,stream>>>(spec);
  k_bandmix<<<dim3(Bb,96,2),256,0,stream>>>(spec, band_w, gates);
  k_inv_y<<<1440,256,0,stream>>>(spec);
  k_inv_x<<<1440,256,0,stream>>>(spec, ximg, biasb);
  k_conv3<Cc,true ><<<dim3(9,15,8),256,0,stream>>>(spec, cab_w1, cab_b1, mid, CRr, SPL);
  k_conv3<CRr,false><<<dim3(9,45,8),256,0,stream>>>(mid, cab_w2, cab_b2, ycab, Cc, HWn);
  k_plane_mean<<<1440,256,0,stream>>>(ycab, gapb);
  k_eca<<<6,256,0,stream>>>(gapb, eca_w, svec);
  k_plk<<<dim3(9,PD,Bb),256,0,stream>>>(ximg, plkw, dkb, attn);
  k_aggr<<<3072,256,0,stream>>>(x, attn, ximg, ycab, aggr_w, aggr_b, svec, xm);
  k_ln2<<<18432,256,0,stream>>>(xm, ln2_g, ln2_b, xn2);
  k_fc1<<<dim3(1152,12),256,0,stream>>>(xn2, fc1_w, fc1_b, t1);
  k_dwglu<<<dim3(9,HID,Bb),256,0,stream>>>((const bf16*)t1, dw_w, dw_b, (bf16*)pgb);
  k_fc2<<<dim3(1152,3),256,0,stream>>>(pgb, xm, fc2_w, fc2_b, (float*)d_out);
}

// Round 4
// 2789.385 us; speedup vs baseline: 1.3022x; 1.1989x over previous
//
#include <hip/hip_runtime.h>
#include <hip/hip_bf16.h>
#include <math.h>
#include <type_traits>

#define Bb 8
#define Cc 180
#define HWn 9216
#define PD 16
#define CRr 60
#define HID 360
#define H2 720
#define NF 49
#define SPL 9408   /* spectral plane stride in floats: 96*49*2 */
#define CONV_SCALE 0.01f
#define FFT_RES 0.15f
#define EPSLN 1e-5f
#define TWOPI_96 0.06544984694978735f

typedef __hip_bfloat16 bf16;
typedef unsigned short ushort;
typedef __attribute__((ext_vector_type(8))) short s8v;   // 8 bf16 (4 VGPRs) MFMA A/B frag
typedef __attribute__((ext_vector_type(4))) float f4v;   // MFMA C/D frag

__device__ __forceinline__ float geluf(float x){ return 0.5f*x*(1.0f+erff(x*0.7071067811865476f)); }
__device__ __forceinline__ float sigm(float x){ return 1.0f/(1.0f+expf(-x)); }
__device__ __forceinline__ short f2bf(float f){
  unsigned u = __float_as_uint(f);
  u += 0x7fff + ((u>>16)&1);
  return (short)(u>>16);
}
__device__ __forceinline__ float wredsum(float v){
#pragma unroll
  for(int m=1;m<64;m<<=1) v += __shfl_xor(v,m,64);
  return v;
}

// ---------------- LN1 + transpose to (B,C,H,W) ----------------
__global__ void __launch_bounds__(256) k_ln1(const float* __restrict__ x, const float* __restrict__ g,
                      const float* __restrict__ be, float* __restrict__ ximg){
  __shared__ float sb[32*Cc];
  int b = blockIdx.x / 288;
  int n0 = (blockIdx.x % 288) * 32;
  int t = threadIdx.x;
  const float* src = x + (size_t)(b*HWn + n0)*Cc;
  for(int i=t;i<32*Cc;i+=256) sb[i]=src[i];
  __syncthreads();
  int w = t>>6, lane = t&63;
  for(int pi=0; pi<8; ++pi){
    int p = w*8+pi;
    float s=0.f, sq=0.f;
    for(int e=lane;e<Cc;e+=64){ float v=sb[p*Cc+e]; s+=v; sq+=v*v; }
    s = wredsum(s); sq = wredsum(sq);
    float mean = s*(1.0f/180.0f);
    float var = sq*(1.0f/180.0f) - mean*mean;
    float rstd = rsqrtf(var + EPSLN);
    for(int e=lane;e<Cc;e+=64){ float v=sb[p*Cc+e]; sb[p*Cc+e] = (v-mean)*rstd*g[e]+be[e]; }
  }
  __syncthreads();
  for(int i=t;i<32*Cc;i+=256){
    int c = i/32, p = i%32;
    ximg[(size_t)(b*Cc+c)*HWn + n0 + p] = sb[p*Cc+c];
  }
}

// ---------------- plane mean (9216 -> 1) ----------------
__global__ void __launch_bounds__(256) k_plane_mean(const float* __restrict__ in, float* __restrict__ out){
  __shared__ float red[4];
  int pl = blockIdx.x; int t = threadIdx.x;
  const float* p = in + (size_t)pl*HWn;
  float s=0.f;
  for(int i=t;i<HWn;i+=256) s+=p[i];
  s = wredsum(s);
  if((t&63)==0) red[t>>6]=s;
  __syncthreads();
  if(t==0) out[pl] = (red[0]+red[1]+red[2]+red[3]) * (1.0f/9216.0f);
}

// ---------------- small: gates, hdn->dk, fft bias ----------------
__global__ void k_small(const float* __restrict__ m1, const float* __restrict__ gate_w,
   const float* __restrict__ gate_b, const float* __restrict__ dwc_w1, const float* __restrict__ dwc_b1,
   const float* __restrict__ dwc_w2, const float* __restrict__ dwc_b2, const float* __restrict__ band_b,
   float* __restrict__ gates, float* __restrict__ dkb, float* __restrict__ biasb){
  int b = threadIdx.x;
  if(b>=Bb) return;
  const float* m = m1 + b*Cc;
  float gv[3];
  for(int k=0;k<3;k++){ float a=gate_b[k]; for(int c=0;c<Cc;c++) a+=m[c]*gate_w[k*Cc+c]; gv[k]=sigm(a);}
  float e0=expf(gv[0]), e1=expf(gv[1]), e2=expf(gv[2]); float inv=1.0f/(e0+e1+e2);
  float g0=e0*inv,g1=e1*inv,g2=e2*inv;
  gates[b*3+0]=g0; gates[b*3+1]=g1; gates[b*3+2]=g2;
  float hd[8];
  for(int j=0;j<8;j++){ float a=dwc_b1[j]; for(int c=0;c<PD;c++) a+=m[c]*dwc_w1[j*PD+c]; hd[j]=geluf(a);}
  for(int i=0;i<144;i++){ float a=dwc_b2[i]; for(int j=0;j<8;j++) a+=hd[j]*dwc_w2[i*8+j]; dkb[b*144+i]=a; }
  for(int d=0;d<Cc;d++) biasb[b*Cc+d] = g0*band_b[0*Cc+d]+g1*band_b[1*Cc+d]+g2*band_b[2*Cc+d];
}

// ---------------- pack CAB conv weights to bf16 [co][tap][ci_pad] ----------------
__global__ void __launch_bounds__(256) k_packw(const float* __restrict__ w1, const float* __restrict__ w2,
    ushort* __restrict__ Wg1, ushort* __restrict__ Wg2){
  int t = blockIdx.x*256 + threadIdx.x;
  if(t < 64*9*192){
    int co = t/(9*192); int rem = t%(9*192); int tap = rem/192; int ci = rem%192;
    float v = (co<CRr && ci<Cc) ? w1[((size_t)(co*Cc+ci))*9 + tap] : 0.f;
    Wg1[t] = (ushort)f2bf(v);
  }
  if(t < 192*9*64){
    int co = t/(9*64); int rem = t%(9*64); int tap = rem/64; int ci = rem%64;
    float v = (co<Cc && ci<CRr) ? w2[((size_t)(co*CRr+ci))*9 + tap] : 0.f;
    Wg2[t] = (ushort)f2bf(v);
  }
}

// ---------------- forward DFT along x (real -> complex, 49 freqs) ----------------
__global__ void __launch_bounds__(256) k_fwd_x(const float* __restrict__ ximg, float* __restrict__ V){
  __shared__ float img[HWn];
  __shared__ float cs[96], sn[96];
  int bc = blockIdx.x; int t = threadIdx.x;
  const float* src = ximg + (size_t)bc*HWn;
  for(int i=t;i<HWn;i+=256) img[i]=src[i];
  if(t<96){ float th = (float)t * TWOPI_96; cs[t]=cosf(th); sn[t]=sinf(th); }
  __syncthreads();
  float* dst = V + (size_t)bc*SPL;
  for(int o=t;o<96*NF;o+=256){
    int y=o/NF, kx=o%NF;
    float re=0.f, im=0.f; int m=0;
    const float* row = img + y*96;
    for(int xx=0; xx<96; ++xx){
      float v=row[xx];
      re += v*cs[m]; im -= v*sn[m];
      m += kx; if(m>=96) m-=96;
    }
    dst[o*2]=re; dst[o*2+1]=im;
  }
}

// ---------------- forward DFT along y (complex -> complex), ortho 1/96, IN-PLACE ----------------
__global__ void __launch_bounds__(256) k_fwd_y(float* __restrict__ S){
  __shared__ float vb[SPL];
  __shared__ float cs[96], sn[96];
  int bc=blockIdx.x, t=threadIdx.x;
  float* pl = S + (size_t)bc*SPL;
  for(int i=t;i<SPL;i+=256) vb[i]=pl[i];
  if(t<96){ float th = (float)t * TWOPI_96; cs[t]=cosf(th); sn[t]=sinf(th); }
  __syncthreads();
  for(int o=t;o<96*NF;o+=256){
    int ky=o/NF, kx=o%NF;
    float re=0.f, im=0.f; int m=0;
    for(int y=0;y<96;++y){
      float vr=vb[(y*NF+kx)*2], vi=vb[(y*NF+kx)*2+1];
      float c=cs[m], s=sn[m];
      re += vr*c + vi*s;
      im += vi*c - vr*s;
      m += ky; if(m>=96) m-=96;
    }
    pl[o*2]=re*(1.0f/96.0f); pl[o*2+1]=im*(1.0f/96.0f);
  }
}

// ---------------- per-frequency band channel mix: Y = g_bk * W_k @ X, IN-PLACE ----------------
__global__ void __launch_bounds__(256) k_bandmix(float* __restrict__ S, const float* __restrict__ band_w,
                          const float* __restrict__ gates){
  __shared__ float xs[Cc*50];
  int b = blockIdx.x; int ky = blockIdx.y; int half = blockIdx.z;
  int kx0 = half*25; int nkx = half? 24:25;
  int t=threadIdx.x;
  for(int i=t;i<Cc*nkx*2;i+=256){
    int c = i/(nkx*2); int r = i%(nkx*2);
    xs[c*50+r] = S[ (size_t)(b*Cc+c)*SPL + ky*(NF*2) + kx0*2 + r ];
  }
  __syncthreads();
  float yy = -1.0f + 2.0f*(float)ky/95.0f;
  for(int o=t;o<Cc*nkx;o+=256){
    int d = o/nkx, kxl = o%nkx; int kx = kx0+kxl;
    float xxf = (float)kx/48.0f;
    float rr = sqrtf(yy*yy+xxf*xxf);
    int k = (rr<=0.25f)?0:((rr<=0.6f)?1:2);
    float g = gates[b*3+k];
    const float* wr = band_w + ((size_t)k*Cc + d)*Cc;
    float re=0.f, im=0.f;
    for(int c=0;c<Cc;++c){
      float w=wr[c];
      re += w*xs[c*50 + kxl*2];
      im += w*xs[c*50 + kxl*2 + 1];
    }
    size_t off = (size_t)(b*Cc+d)*SPL + ky*(NF*2) + kx*2;
    S[off]=g*re; S[off+1]=g*im;
  }
}

// ---------------- inverse DFT along ky (complex -> complex, e^{+i}), IN-PLACE ----------------
__global__ void __launch_bounds__(256) k_inv_y(float* __restrict__ S){
  __shared__ float vb[SPL];
  __shared__ float cs[96], sn[96];
  int bd=blockIdx.x, t=threadIdx.x;
  float* pl = S + (size_t)bd*SPL;
  for(int i=t;i<SPL;i+=256) vb[i]=pl[i];
  if(t<96){ float th = (float)t * TWOPI_96; cs[t]=cosf(th); sn[t]=sinf(th); }
  __syncthreads();
  for(int o=t;o<96*NF;o+=256){
    int y=o/NF, kx=o%NF;
    float re=0.f, im=0.f; int m=0;
    for(int ky=0;ky<96;++ky){
      float vr=vb[(ky*NF+kx)*2], vi=vb[(ky*NF+kx)*2+1];
      float c=cs[m], s=sn[m];
      re += vr*c - vi*s;
      im += vr*s + vi*c;
      m += y; if(m>=96) m-=96;
    }
    pl[o*2]=re; pl[o*2+1]=im;
  }
}

// -------- inverse rDFT along kx + combine, IN-PLACE into spec plane (first 9216 floats) --------
__global__ void __launch_bounds__(256) k_inv_x(float* __restrict__ S, const float* __restrict__ ximg,
                        const float* __restrict__ biasb){
  __shared__ float tb[SPL];
  __shared__ float cs[96], sn[96];
  int bd = blockIdx.x; int t=threadIdx.x;
  int b = bd / Cc; int d = bd % Cc;
  float* pl = S + (size_t)bd*SPL;
  for(int i=t;i<SPL;i+=256) tb[i]=pl[i];
  if(t<96){ float th = (float)t * TWOPI_96; cs[t]=cosf(th); sn[t]=sinf(th); }
  __syncthreads();
  float bias = biasb[b*Cc+d];
  const float* xs = ximg + (size_t)bd*HWn;
  for(int o=t;o<HWn;o+=256){
    int y=o/96, xx=o%96;
    float acc=0.f; int m=0;
    const float* row = tb + y*(NF*2);
    for(int kx=0;kx<NF;++kx){
      float wgt = (kx==0||kx==48)?1.0f:2.0f;
      acc += wgt*(row[kx*2]*cs[m] - row[kx*2+1]*sn[m]);
      m += xx; if(m>=96) m-=96;
    }
    pl[o] = xs[o] + FFT_RES*(acc*(1.0f/96.0f) + bias);
  }
}

// ---------------- CAB 3x3 conv as implicit-GEMM MFMA ----------------
// Block: 2 output rows (M=192 px) x 64 co. A staged transposed in LDS; B pre-packed bf16 in global.
template<typename TIN, int CIN, int KPAD, int NCHUNK, bool ACT, bool OUTBF>
__global__ void __launch_bounds__(256) k_cab(const TIN* __restrict__ xin, const ushort* __restrict__ Wg,
    const float* __restrict__ bias, void* __restrict__ outv, int COUT, int istride){
  __shared__ short As[4*98*36];   // 28224 B; also reused for epilogue transpose
  int y0 = blockIdx.x*2;
  int ct = blockIdx.y;
  int b  = blockIdx.z;
  int t = threadIdx.x;
  int w = t>>6, lane = t&63, kq = lane>>4, lr = lane&15;
  f4v acc[3][4] = {};
  for(int ch=0; ch<NCHUNK; ++ch){
    int ci0 = ch*32;
    __syncthreads();
    for(int i=t;i<4*98*32;i+=256){
      int ci = i/392; int rem = i%392; int row = rem/98; int pxh = rem%98;
      int gy = y0 - 1 + row; int px = pxh - 1;
      int cig = ci0 + ci;
      short sv = 0;
      if((unsigned)gy<96u && (unsigned)px<96u && cig<CIN){
        if constexpr (std::is_same<TIN,float>::value)
          sv = f2bf(xin[(size_t)(b*CIN+cig)*istride + gy*96 + px]);
        else
          sv = (short)xin[(size_t)(b*CIN+cig)*istride + gy*96 + px];
      }
      As[(row*98+pxh)*36 + ci] = sv;
    }
    __syncthreads();
#pragma unroll
    for(int tap=0; tap<9; ++tap){
      int ky = tap/3, kx = tap%3;
      s8v bfr[4];
#pragma unroll
      for(int ts=0;ts<4;ts++)
        bfr[ts] = *(const s8v*)&Wg[((size_t)(ct*64 + ts*16 + lr)*9 + tap)*KPAD + ci0 + kq*8];
#pragma unroll
      for(int s=0;s<3;s++){
        int mt = w + 4*s;
        int orow = mt/6, px = (mt%6)*16 + lr;
        s8v af = *(const s8v*)&As[((orow+ky)*98 + px + kx)*36 + kq*8];
#pragma unroll
        for(int ts=0;ts<4;ts++)
          acc[s][ts] = __builtin_amdgcn_mfma_f32_16x16x32_bf16(af, bfr[ts], acc[s][ts], 0,0,0);
      }
    }
  }
  // epilogue
  if(OUTBF){
    __syncthreads();
    short* cT = As;   // [64 co][200] bf16
#pragma unroll
    for(int ts=0;ts<4;ts++){
      int cog = ct*64 + ts*16 + lr;
      float bb = (cog<COUT)? bias[cog] : 0.f;
#pragma unroll
      for(int s=0;s<3;s++){
#pragma unroll
        for(int reg=0;reg<4;reg++){
          int px = (w+4*s)*16 + kq*4 + reg;
          float v = acc[s][ts][reg] + bb;
          if(ACT) v = geluf(v);
          cT[(ts*16+lr)*200 + px] = f2bf(v);
        }
      }
    }
    __syncthreads();
    ushort* out = (ushort*)outv;
    for(int i=t;i<64*192;i+=256){
      int co=i/192, px=i%192;
      int cog = ct*64+co;
      if(cog<COUT) out[(size_t)(b*COUT+cog)*HWn + y0*96 + px] = (ushort)cT[co*200+px];
    }
  } else {
    float* cF = (float*)As;  // [32 co][200] fp32 per half
    float* out = (float*)outv;
    for(int h=0;h<2;h++){
      __syncthreads();
#pragma unroll
      for(int tt=0;tt<2;tt++){
        int ts = 2*h+tt;
        int cog = ct*64 + ts*16 + lr;
        float bb = (cog<COUT)? bias[cog] : 0.f;
#pragma unroll
        for(int s=0;s<3;s++){
#pragma unroll
          for(int reg=0;reg<4;reg++){
            int px = (w+4*s)*16 + kq*4 + reg;
            cF[(tt*16+lr)*200 + px] = acc[s][ts][reg] + bb;
          }
        }
      }
      __syncthreads();
      for(int i=t;i<32*192;i+=256){
        int co=i/192, px=i%192;
        int cog = ct*64 + h*32 + co;
        if(cog<COUT) out[(size_t)(b*COUT+cog)*HWn + y0*96 + px] = cF[co*200+px];
      }
    }
  }
}

// ---------------- ECA ----------------
__global__ void k_eca(const float* __restrict__ gap, const float* __restrict__ ew, float* __restrict__ s){
  int i = blockIdx.x*blockDim.x + threadIdx.x;
  if(i>=Bb*Cc) return;
  int b=i/Cc, c=i%Cc;
  float z=0.f;
  for(int j=0;j<5;j++){ int cc=c-2+j; if(cc>=0&&cc<Cc) z+=gap[b*Cc+cc]*ew[j]; }
  s[i]=sigm(z);
}

// ---------------- plk 13x13 conv (16->16) + fused dynamic depthwise 3x3 ----------------
__global__ void __launch_bounds__(256) k_plk(const float* __restrict__ ximg, const float* __restrict__ plk,
    const float* __restrict__ dkb, float* __restrict__ attn){
  __shared__ float tile[44*44];
  __shared__ float wl[169];
  __shared__ float dk9[9];
  int tile_id=blockIdx.x; int co=blockIdx.y; int b=blockIdx.z;
  int ty0=(tile_id/3)*32, tx0=(tile_id%3)*32;
  int t=threadIdx.x;
  int px0=(t%16)*2, py0=(t/16)*2;
  if(t<9) dk9[t]=dkb[b*144+co*9+t];
  float a00=0,a01=0,a10=0,a11=0;
  for(int ci=0;ci<PD;++ci){
    __syncthreads();
    for(int i=t;i<44*44;i+=256){
      int ly=i/44, lx=i%44;
      int gy=ty0+ly-6, gx=tx0+lx-6;
      float v=0.f;
      if((unsigned)gy<96u&&(unsigned)gx<96u) v=ximg[((size_t)(b*Cc+ci)*96+gy)*96+gx];
      tile[i]=v;
    }
    for(int i=t;i<169;i+=256) wl[i]=plk[((size_t)(co*PD+ci)*169)+i];
    __syncthreads();
    for(int rr2=0; rr2<14; ++rr2){
      float rowv[14];
      const float* trow = tile + (py0+rr2)*44 + px0;
#pragma unroll
      for(int i=0;i<14;i++) rowv[i]=trow[i];
      if(rr2<13){
        const float* wr = wl + rr2*13;
#pragma unroll
        for(int kx=0;kx<13;kx++){ float w=wr[kx]; a00+=w*rowv[kx]; a01+=w*rowv[kx+1]; }
      }
      if(rr2>=1){
        const float* wr = wl + (rr2-1)*13;
#pragma unroll
        for(int kx=0;kx<13;kx++){ float w=wr[kx]; a10+=w*rowv[kx]; a11+=w*rowv[kx+1]; }
      }
    }
    if(ci==co){
#pragma unroll
      for(int ky=0;ky<3;ky++)
#pragma unroll
        for(int kx=0;kx<3;kx++){
          float w=dk9[ky*3+kx];
          a00+=w*tile[(py0+5+ky)*44+px0+5+kx];
          a01+=w*tile[(py0+5+ky)*44+px0+6+kx];
          a10+=w*tile[(py0+6+ky)*44+px0+5+kx];
          a11+=w*tile[(py0+6+ky)*44+px0+6+kx];
        }
    }
  }
  int gy=ty0+py0, gx=tx0+px0;
  float* dst = attn + (size_t)(b*PD+co)*HWn;
  dst[gy*96+gx]=a00; dst[gy*96+gx+1]=a01; dst[(gy+1)*96+gx]=a10; dst[(gy+1)*96+gx+1]=a11;
}

// ---------------- aggr (180x180) + residual + conv_x scale -> xm (B,N,C) ----------------
__global__ void __launch_bounds__(256) k_aggr(const float* __restrict__ x, const float* __restrict__ attn,
   const float* __restrict__ ximg, const float* __restrict__ ycab, const float* __restrict__ aggw,
   const float* __restrict__ aggb, const float* __restrict__ s, float* __restrict__ xm){
  __shared__ float u[Cc*24];
  __shared__ float yc[Cc*24];
  __shared__ float ob[24*Cc];
  int b=blockIdx.x/384; int n0=(blockIdx.x%384)*24;
  int t=threadIdx.x;
  for(int i=t;i<Cc*24;i+=256){
    int c=i/24, p=i%24;
    u[i] = (c<PD)? attn[(size_t)(b*PD+c)*HWn + n0+p] : ximg[(size_t)(b*Cc+c)*HWn + n0+p];
    yc[i] = ycab[(size_t)(b*Cc+c)*HWn + n0+p];
  }
  __syncthreads();
  for(int o=t;o<24*Cc;o+=256){
    int d=o/24, p=o%24;
    const float* wr = aggw + (size_t)d*Cc;
    float a=0.f;
    for(int c=0;c<Cc;c++) a += wr[c]*u[c*24+p];
    a += aggb[d] + CONV_SCALE * s[b*Cc+d] * yc[d*24+p];
    ob[p*Cc+d]=a;
  }
  __syncthreads();
  size_t base = (size_t)(b*HWn+n0)*Cc;
  for(int i=t;i<24*Cc;i+=256) xm[base+i] = x[base+i] + ob[i];
}

// ---------------- LN2 fused: stats + normalize + bf16 cast, K padded 180->192 ----------------
__global__ void __launch_bounds__(256) k_ln2(const float* __restrict__ xm, const float* __restrict__ g2,
    const float* __restrict__ b2, ushort* __restrict__ xn2){
  int w = (blockIdx.x*256 + threadIdx.x)>>6;
  int lane = threadIdx.x&63;
  const float* row = xm + (size_t)w*Cc;
  float s=0,sq=0;
  for(int e=lane;e<Cc;e+=64){ float v=row[e]; s+=v; sq+=v*v; }
  s=wredsum(s); sq=wredsum(sq);
  float m=s*(1.0f/180.0f); float v=sq*(1.0f/180.0f)-m*m;
  float rstd=rsqrtf(v+EPSLN);
  ushort* orow = xn2 + (size_t)w*192;
  for(int e=lane;e<192;e+=64){
    float val = (e<Cc)? (row[e]-m)*rstd*g2[e]+b2[e] : 0.f;
    orow[e] = (ushort)f2bf(val);
  }
}

// ---------------- fc1 MFMA: t1[j][n] = xn2 @ fc1_w^T + fb  (bf16 out) ----------------
__global__ void __launch_bounds__(256) k_fc1(const ushort* __restrict__ xn2,
    const float* __restrict__ fw, const float* __restrict__ fb, ushort* __restrict__ t1){
  __shared__ short As[64*200];
  __shared__ short Ws[64*200];
  int rt = blockIdx.x, ct = blockIdx.y;
  int t = threadIdx.x;
  int w = t>>6, lane = t&63, kq = lane>>4, lr = lane&15;
  int grow0 = rt*64;
  for(int i=t;i<64*24;i+=256){
    int r=i/24, seg=i%24;
    *(s8v*)&As[r*200+seg*8] = *(const s8v*)&xn2[(size_t)(grow0+r)*192 + seg*8];
  }
  for(int i=t;i<64*192;i+=256){
    int j=i/192, kk=i%192;
    int jc=ct*64+j;
    float v = (jc<H2 && kk<Cc)? fw[(size_t)jc*Cc+kk] : 0.f;
    Ws[j*200+kk]=f2bf(v);
  }
  __syncthreads();
  f4v acc[4]={};
  int arow=(w*16+lr)*200 + kq*8;
#pragma unroll
  for(int k0=0;k0<192;k0+=32){
    s8v af = *(const s8v*)&As[arow+k0];
#pragma unroll
    for(int ts=0;ts<4;ts++){
      s8v wf = *(const s8v*)&Ws[(ts*16+lr)*200 + kq*8 + k0];
      acc[ts]=__builtin_amdgcn_mfma_f32_16x16x32_bf16(af,wf,acc[ts],0,0,0);
    }
  }
  __syncthreads();
  short* cT = Ws;
#pragma unroll
  for(int ts=0;ts<4;ts++){
    int j = ts*16+lr;
    float bb = fb[ct*64+j < H2 ? ct*64+j : 0];
#pragma unroll
    for(int reg=0;reg<4;reg++){
      int m = w*16 + kq*4 + reg;
      cT[j*72+m] = f2bf(acc[ts][reg]+bb);
    }
  }
  __syncthreads();
  int bb_ = grow0/HWn, n0 = grow0%HWn;
  for(int i=t;i<4096;i+=256){
    int j=i>>6, m=i&63;
    int jc=ct*64+j;
    if(jc<H2) t1[((size_t)(bb_*H2+jc))*HWn + n0 + m] = (ushort)cT[j*72+m];
  }
}

// ---------------- depthwise 3x3 on t1 + GLU -> pg (B,360,HW) bf16 ----------------
__global__ void __launch_bounds__(256) k_dwglu(const bf16* __restrict__ t1, const float* __restrict__ dww,
    const float* __restrict__ dwb, bf16* __restrict__ pg){
  __shared__ float ta[34*34];
  __shared__ float tg[34*34];
  int tile_id=blockIdx.x; int c=blockIdx.y; int b=blockIdx.z;
  int ty0=(tile_id/3)*32, tx0=(tile_id%3)*32;
  int t=threadIdx.x;
  int px0=(t%16)*2, py0=(t/16)*2;
  for(int i=t;i<34*34;i+=256){
    int ly=i/34, lx=i%34; int gy=ty0+ly-1, gx=tx0+lx-1;
    bool ok=((unsigned)gy<96u&&(unsigned)gx<96u);
    ta[i]= ok? __bfloat162float(t1[((size_t)(b*H2+c)*96+gy)*96+gx]) :0.f;
    tg[i]= ok? __bfloat162float(t1[((size_t)(b*H2+c+HID)*96+gy)*96+gx]) :0.f;
  }
  __syncthreads();
  float wp[9],wg[9];
#pragma unroll
  for(int i=0;i<9;i++){ wp[i]=dww[c*9+i]; wg[i]=dww[(c+HID)*9+i]; }
  float bp=dwb[c], bg=dwb[c+HID];
#pragma unroll
  for(int oy=0;oy<2;oy++)
#pragma unroll
    for(int ox=0;ox<2;ox++){
      float p=bp,g=bg;
#pragma unroll
      for(int ky=0;ky<3;ky++)
#pragma unroll
        for(int kx=0;kx<3;kx++){
          p+=wp[ky*3+kx]*ta[(py0+oy+ky)*34+px0+ox+kx];
          g+=wg[ky*3+kx]*tg[(py0+oy+ky)*34+px0+ox+kx];
        }
      float val = p * g * sigm(g);
      pg[((size_t)(b*HID+c)*96 + ty0+py0+oy)*96 + tx0+px0+ox] = __float2bfloat16(val);
    }
}

// ---------------- fc2 MFMA + residual -> out (B,N,C) ----------------
__global__ void __launch_bounds__(256) k_fc2(const ushort* __restrict__ pg, const float* __restrict__ xm,
    const float* __restrict__ fw, const float* __restrict__ fb, float* __restrict__ out){
  __shared__ short As[64*200];
  __shared__ short Ws[64*200];
  int rt = blockIdx.x, ct = blockIdx.y;
  int t = threadIdx.x;
  int w = t>>6, lane = t&63, kq = lane>>4, lr = lane&15;
  int grow0 = rt*64; int b = grow0/HWn; int n0 = grow0%HWn;
  f4v acc[4]={};
  for(int kc0=0;kc0<384;kc0+=192){
    __syncthreads();
    for(int i=t;i<192*64;i+=256){
      int kk=i/64, r=i%64;
      int kc=kc0+kk;
      As[r*200+kk] = (kc<HID)? (short)pg[((size_t)(b*HID+kc))*HWn + n0 + r] : (short)0;
    }
    for(int i=t;i<64*192;i+=256){
      int j=i/192, kk=i%192;
      int jc=ct*64+j; int kc=kc0+kk;
      float v = (jc<Cc && kc<HID)? fw[(size_t)jc*HID+kc] : 0.f;
      Ws[j*200+kk]=f2bf(v);
    }
    __syncthreads();
    int arow=(w*16+lr)*200 + kq*8;
#pragma unroll
    for(int k0=0;k0<192;k0+=32){
      s8v af = *(const s8v*)&As[arow+k0];
#pragma unroll
      for(int ts=0;ts<4;ts++){
        s8v wf = *(const s8v*)&Ws[(ts*16+lr)*200 + kq*8 + k0];
        acc[ts]=__builtin_amdgcn_mfma_f32_16x16x32_bf16(af,wf,acc[ts],0,0,0);
      }
    }
  }
#pragma unroll
  for(int ts=0;ts<4;ts++){
    int jc = ct*64 + ts*16 + lr;
    if(jc>=Cc) continue;
    float bb = fb[jc];
#pragma unroll
    for(int reg=0;reg<4;reg++){
      int m = w*16 + kq*4 + reg;
      size_t o = (size_t)(grow0+m)*Cc + jc;
      out[o] = xm[o] + acc[ts][reg] + bb;
    }
  }
}

extern "C" void kernel_launch(void* const* d_in, const int* in_sizes, int n_in,
                              void* d_out, int out_size, void* d_ws, size_t ws_size,
                              hipStream_t stream){
  (void)in_sizes; (void)n_in; (void)out_size; (void)ws_size;
  const float* x     = (const float*)d_in[0];
  const float* ln1_g = (const float*)d_in[3];
  const float* ln1_b = (const float*)d_in[4];
  const float* band_w= (const float*)d_in[5];
  const float* band_b= (const float*)d_in[6];
  const float* gate_w= (const float*)d_in[7];
  const float* gate_b= (const float*)d_in[8];
  const float* cab_w1= (const float*)d_in[9];
  const float* cab_b1= (const float*)d_in[10];
  const float* cab_w2= (const float*)d_in[11];
  const float* cab_b2= (const float*)d_in[12];
  const float* eca_w = (const float*)d_in[13];
  const float* plkw  = (const float*)d_in[14];
  const float* dwc_w1= (const float*)d_in[15];
  const float* dwc_b1= (const float*)d_in[16];
  const float* dwc_w2= (const float*)d_in[17];
  const float* dwc_b2= (const float*)d_in[18];
  const float* aggr_w= (const float*)d_in[19];
  const float* aggr_b= (const float*)d_in[20];
  const float* ln2_g = (const float*)d_in[21];
  const float* ln2_b = (const float*)d_in[22];
  const float* fc1_w = (const float*)d_in[23];
  const float* fc1_b = (const float*)d_in[24];
  const float* dw_w  = (const float*)d_in[25];
  const float* dw_b  = (const float*)d_in[26];
  const float* fc2_w = (const float*)d_in[27];
  const float* fc2_b = (const float*)d_in[28];

  float* ws = (float*)d_ws;
  // persistent region
  float* xm   = ws;                      // 13,271,040
  float* m1   = ws + 13271040;           // 1,440
  float* gates= ws + 13272480;           // 32
  float* dkb  = ws + 13272512;           // 1,152
  float* biasb= ws + 13273664;           // 1,440
  float* gapb = ws + 13275104;           // 1,440
  float* svec = ws + 13276544;           // 1,440 -> 13,277,984
  ushort* Wg1 = (ushort*)(ws + 13278000);// 110,592 shorts = 55,296 floats
  ushort* Wg2 = (ushort*)(ws + 13333296);// 110,592 shorts = 55,296 floats -> 13,388,592
  float* big  = ws + 13388800;
  // phase 1 inside big:
  float* ximg = big;                     // 13,271,040
  float* spec = big + 13271040;          // 13,547,520 (xfft in first 9216 of each 9408 plane)
  ushort* mid = (ushort*)(big + 26818560); // 4,423,680 bf16 = 2,211,840 float slots
  float* attn = big + 29030400;          // 1,179,648 -> phase-1 top = 30,210,048
  float* ycab = spec;                    // reuse (stride 9216), spec dead after conv1
  // phase 2 aliases big:
  ushort* t1  = (ushort*)big;                    // 26,542,080 float slots
  float*  reg2= big + 26542080;
  ushort* xn2 = (ushort*)reg2;                   // 7,077,888 float slots (ln2->fc1)
  ushort* pgb = (ushort*)reg2;                   // 13,271,040 float slots (dwglu->fc2)
  // total = 13,388,800 + 39,813,120 = 53,201,920 floats (~213 MB)

  k_packw<<<432,256,0,stream>>>(cab_w1, cab_w2, Wg1, Wg2);
  k_ln1<<<2304,256,0,stream>>>(x, ln1_g, ln1_b, ximg);
  k_plane_mean<<<1440,256,0,stream>>>(ximg, m1);
  k_small<<<1,64,0,stream>>>(m1, gate_w, gate_b, dwc_w1, dwc_b1, dwc_w2, dwc_b2, band_b, gates, dkb, biasb);
  k_fwd_x<<<1440,256,0,stream>>>(ximg, spec);
  k_fwd_y<<<1440,256,0,stream>>>(spec);
  k_bandmix<<<dim3(Bb,96,2),256,0,stream>>>(spec, band_w, gates);
  k_inv_y<<<1440,256,0,stream>>>(spec);
  k_inv_x<<<1440,256,0,stream>>>(spec, ximg, biasb);
  k_cab<float, Cc, 192, 6, true,  true ><<<dim3(48,1,Bb),256,0,stream>>>(spec, Wg1, cab_b1, (void*)mid, CRr, SPL);
  k_cab<ushort, CRr, 64, 2, false, false><<<dim3(48,3,Bb),256,0,stream>>>(mid, Wg2, cab_b2, (void*)ycab, Cc, HWn);
  k_plane_mean<<<1440,256,0,stream>>>(ycab, gapb);
  k_eca<<<6,256,0,stream>>>(gapb, eca_w, svec);
  k_plk<<<dim3(9,PD,Bb),256,0,stream>>>(ximg, plkw, dkb, attn);
  k_aggr<<<3072,256,0,stream>>>(x, attn, ximg, ycab, aggr_w, aggr_b, svec, xm);
  k_ln2<<<18432,256,0,stream>>>(xm, ln2_g, ln2_b, xn2);
  k_fc1<<<dim3(1152,12),256,0,stream>>>(xn2, fc1_w, fc1_b, t1);
  k_dwglu<<<dim3(9,HID,Bb),256,0,stream>>>((const bf16*)t1, dw_w, dw_b, (bf16*)pgb);
  k_fc2<<<dim3(1152,3),256,0,stream>>>(pgb, xm, fc2_w, fc2_b, (float*)d_out);
}

// Round 5
// 2674.735 us; speedup vs baseline: 1.3581x; 1.0429x over previous
//
#include <hip/hip_runtime.h>
#include <hip/hip_bf16.h>
#include <math.h>
#include <type_traits>

#define Bb 8
#define Cc 180
#define HWn 9216
#define PD 16
#define CRr 60
#define HID 360
#define H2 720
#define NF 49
#define SPL 9408   /* spectral plane stride in floats: 96*49*2 */
#define CONV_SCALE 0.01f
#define FFT_RES 0.15f
#define EPSLN 1e-5f
#define TWOPI_96 0.06544984694978735f

typedef __hip_bfloat16 bf16;
typedef unsigned short ushort;
typedef __attribute__((ext_vector_type(8))) short s8v;   // 8 bf16 (4 VGPRs) MFMA A/B frag
typedef __attribute__((ext_vector_type(4))) float f4v;   // MFMA C/D frag

__device__ __forceinline__ float geluf(float x){ return 0.5f*x*(1.0f+erff(x*0.7071067811865476f)); }
__device__ __forceinline__ float sigm(float x){ return 1.0f/(1.0f+expf(-x)); }
__device__ __forceinline__ short f2bf(float f){
  unsigned u = __float_as_uint(f);
  u += 0x7fff + ((u>>16)&1);
  return (short)(u>>16);
}
__device__ __forceinline__ float wredsum(float v){
#pragma unroll
  for(int m=1;m<64;m<<=1) v += __shfl_xor(v,m,64);
  return v;
}

// ---------------- LN1 + transpose to (B,C,H,W) ----------------
__global__ void __launch_bounds__(256) k_ln1(const float* __restrict__ x, const float* __restrict__ g,
                      const float* __restrict__ be, float* __restrict__ ximg){
  __shared__ float sb[32*Cc];
  int b = blockIdx.x / 288;
  int n0 = (blockIdx.x % 288) * 32;
  int t = threadIdx.x;
  const float* src = x + (size_t)(b*HWn + n0)*Cc;
  for(int i=t;i<32*Cc;i+=256) sb[i]=src[i];
  __syncthreads();
  int w = t>>6, lane = t&63;
  for(int pi=0; pi<8; ++pi){
    int p = w*8+pi;
    float s=0.f, sq=0.f;
    for(int e=lane;e<Cc;e+=64){ float v=sb[p*Cc+e]; s+=v; sq+=v*v; }
    s = wredsum(s); sq = wredsum(sq);
    float mean = s*(1.0f/180.0f);
    float var = sq*(1.0f/180.0f) - mean*mean;
    float rstd = rsqrtf(var + EPSLN);
    for(int e=lane;e<Cc;e+=64){ float v=sb[p*Cc+e]; sb[p*Cc+e] = (v-mean)*rstd*g[e]+be[e]; }
  }
  __syncthreads();
  for(int i=t;i<32*Cc;i+=256){
    int c = i/32, p = i%32;
    ximg[(size_t)(b*Cc+c)*HWn + n0 + p] = sb[p*Cc+c];
  }
}

// ---------------- plane mean (9216 -> 1) ----------------
__global__ void __launch_bounds__(256) k_plane_mean(const float* __restrict__ in, float* __restrict__ out){
  __shared__ float red[4];
  int pl = blockIdx.x; int t = threadIdx.x;
  const float* p = in + (size_t)pl*HWn;
  float s=0.f;
  for(int i=t;i<HWn;i+=256) s+=p[i];
  s = wredsum(s);
  if((t&63)==0) red[t>>6]=s;
  __syncthreads();
  if(t==0) out[pl] = (red[0]+red[1]+red[2]+red[3]) * (1.0f/9216.0f);
}

// ---------------- small: gates, hdn->dk, fft bias ----------------
__global__ void k_small(const float* __restrict__ m1, const float* __restrict__ gate_w,
   const float* __restrict__ gate_b, const float* __restrict__ dwc_w1, const float* __restrict__ dwc_b1,
   const float* __restrict__ dwc_w2, const float* __restrict__ dwc_b2, const float* __restrict__ band_b,
   float* __restrict__ gates, float* __restrict__ dkb, float* __restrict__ biasb){
  int b = threadIdx.x;
  if(b>=Bb) return;
  const float* m = m1 + b*Cc;
  float gv[3];
  for(int k=0;k<3;k++){ float a=gate_b[k]; for(int c=0;c<Cc;c++) a+=m[c]*gate_w[k*Cc+c]; gv[k]=sigm(a);}
  float e0=expf(gv[0]), e1=expf(gv[1]), e2=expf(gv[2]); float inv=1.0f/(e0+e1+e2);
  float g0=e0*inv,g1=e1*inv,g2=e2*inv;
  gates[b*3+0]=g0; gates[b*3+1]=g1; gates[b*3+2]=g2;
  float hd[8];
  for(int j=0;j<8;j++){ float a=dwc_b1[j]; for(int c=0;c<PD;c++) a+=m[c]*dwc_w1[j*PD+c]; hd[j]=geluf(a);}
  for(int i=0;i<144;i++){ float a=dwc_b2[i]; for(int j=0;j<8;j++) a+=hd[j]*dwc_w2[i*8+j]; dkb[b*144+i]=a; }
  for(int d=0;d<Cc;d++) biasb[b*Cc+d] = g0*band_b[0*Cc+d]+g1*band_b[1*Cc+d]+g2*band_b[2*Cc+d];
}

// ---------------- pack CAB conv weights to bf16 [co][tap][ci_pad] ----------------
__global__ void __launch_bounds__(256) k_packw(const float* __restrict__ w1, const float* __restrict__ w2,
    ushort* __restrict__ Wg1, ushort* __restrict__ Wg2){
  int t = blockIdx.x*256 + threadIdx.x;
  if(t < 64*9*192){
    int co = t/(9*192); int rem = t%(9*192); int tap = rem/192; int ci = rem%192;
    float v = (co<CRr && ci<Cc) ? w1[((size_t)(co*Cc+ci))*9 + tap] : 0.f;
    Wg1[t] = (ushort)f2bf(v);
  }
  if(t < 192*9*64){
    int co = t/(9*64); int rem = t%(9*64); int tap = rem/64; int ci = rem%64;
    float v = (co<Cc && ci<CRr) ? w2[((size_t)(co*CRr+ci))*9 + tap] : 0.f;
    Wg2[t] = (ushort)f2bf(v);
  }
}

// ---------------- forward DFT along x (real -> complex, 49 freqs) ----------------
__global__ void __launch_bounds__(256) k_fwd_x(const float* __restrict__ ximg, float* __restrict__ V){
  __shared__ float img[HWn];
  __shared__ float cs[96], sn[96];
  int bc = blockIdx.x; int t = threadIdx.x;
  const float* src = ximg + (size_t)bc*HWn;
  for(int i=t;i<HWn;i+=256) img[i]=src[i];
  if(t<96){ float th = (float)t * TWOPI_96; cs[t]=cosf(th); sn[t]=sinf(th); }
  __syncthreads();
  float* dst = V + (size_t)bc*SPL;
  for(int o=t;o<96*NF;o+=256){
    int y=o/NF, kx=o%NF;
    float re=0.f, im=0.f; int m=0;
    const float* row = img + y*96;
    for(int xx=0; xx<96; ++xx){
      float v=row[xx];
      re += v*cs[m]; im -= v*sn[m];
      m += kx; if(m>=96) m-=96;
    }
    dst[o*2]=re; dst[o*2+1]=im;
  }
}

// ---------------- forward DFT along y (complex -> complex), ortho 1/96, IN-PLACE ----------------
__global__ void __launch_bounds__(256) k_fwd_y(float* __restrict__ S){
  __shared__ float vb[SPL];
  __shared__ float cs[96], sn[96];
  int bc=blockIdx.x, t=threadIdx.x;
  float* pl = S + (size_t)bc*SPL;
  for(int i=t;i<SPL;i+=256) vb[i]=pl[i];
  if(t<96){ float th = (float)t * TWOPI_96; cs[t]=cosf(th); sn[t]=sinf(th); }
  __syncthreads();
  for(int o=t;o<96*NF;o+=256){
    int ky=o/NF, kx=o%NF;
    float re=0.f, im=0.f; int m=0;
    for(int y=0;y<96;++y){
      float vr=vb[(y*NF+kx)*2], vi=vb[(y*NF+kx)*2+1];
      float c=cs[m], s=sn[m];
      re += vr*c + vi*s;
      im += vi*c - vr*s;
      m += ky; if(m>=96) m-=96;
    }
    pl[o*2]=re*(1.0f/96.0f); pl[o*2+1]=im*(1.0f/96.0f);
  }
}

// ---------------- per-frequency band channel mix: Y = g_bk * W_k @ X, IN-PLACE ----------------
__global__ void __launch_bounds__(256) k_bandmix(float* __restrict__ S, const float* __restrict__ band_w,
                          const float* __restrict__ gates){
  __shared__ float xs[Cc*50];
  int b = blockIdx.x; int ky = blockIdx.y; int half = blockIdx.z;
  int kx0 = half*25; int nkx = half? 24:25;
  int t=threadIdx.x;
  for(int i=t;i<Cc*nkx*2;i+=256){
    int c = i/(nkx*2); int r = i%(nkx*2);
    xs[c*50+r] = S[ (size_t)(b*Cc+c)*SPL + ky*(NF*2) + kx0*2 + r ];
  }
  __syncthreads();
  float yy = -1.0f + 2.0f*(float)ky/95.0f;
  for(int o=t;o<Cc*nkx;o+=256){
    int d = o/nkx, kxl = o%nkx; int kx = kx0+kxl;
    float xxf = (float)kx/48.0f;
    float rr = sqrtf(yy*yy+xxf*xxf);
    int k = (rr<=0.25f)?0:((rr<=0.6f)?1:2);
    float g = gates[b*3+k];
    const float* wr = band_w + ((size_t)k*Cc + d)*Cc;
    float re=0.f, im=0.f;
    for(int c=0;c<Cc;++c){
      float w=wr[c];
      re += w*xs[c*50 + kxl*2];
      im += w*xs[c*50 + kxl*2 + 1];
    }
    size_t off = (size_t)(b*Cc+d)*SPL + ky*(NF*2) + kx*2;
    S[off]=g*re; S[off+1]=g*im;
  }
}

// ---------------- inverse DFT along ky (complex -> complex, e^{+i}), IN-PLACE ----------------
__global__ void __launch_bounds__(256) k_inv_y(float* __restrict__ S){
  __shared__ float vb[SPL];
  __shared__ float cs[96], sn[96];
  int bd=blockIdx.x, t=threadIdx.x;
  float* pl = S + (size_t)bd*SPL;
  for(int i=t;i<SPL;i+=256) vb[i]=pl[i];
  if(t<96){ float th = (float)t * TWOPI_96; cs[t]=cosf(th); sn[t]=sinf(th); }
  __syncthreads();
  for(int o=t;o<96*NF;o+=256){
    int y=o/NF, kx=o%NF;
    float re=0.f, im=0.f; int m=0;
    for(int ky=0;ky<96;++ky){
      float vr=vb[(ky*NF+kx)*2], vi=vb[(ky*NF+kx)*2+1];
      float c=cs[m], s=sn[m];
      re += vr*c - vi*s;
      im += vr*s + vi*c;
      m += y; if(m>=96) m-=96;
    }
    pl[o*2]=re; pl[o*2+1]=im;
  }
}

// -------- inverse rDFT along kx + combine, IN-PLACE into spec plane (first 9216 floats) --------
__global__ void __launch_bounds__(256) k_inv_x(float* __restrict__ S, const float* __restrict__ ximg,
                        const float* __restrict__ biasb){
  __shared__ float tb[SPL];
  __shared__ float cs[96], sn[96];
  int bd = blockIdx.x; int t=threadIdx.x;
  int b = bd / Cc; int d = bd % Cc;
  float* pl = S + (size_t)bd*SPL;
  for(int i=t;i<SPL;i+=256) tb[i]=pl[i];
  if(t<96){ float th = (float)t * TWOPI_96; cs[t]=cosf(th); sn[t]=sinf(th); }
  __syncthreads();
  float bias = biasb[b*Cc+d];
  const float* xs = ximg + (size_t)bd*HWn;
  for(int o=t;o<HWn;o+=256){
    int y=o/96, xx=o%96;
    float acc=0.f; int m=0;
    const float* row = tb + y*(NF*2);
    for(int kx=0;kx<NF;++kx){
      float wgt = (kx==0||kx==48)?1.0f:2.0f;
      acc += wgt*(row[kx*2]*cs[m] - row[kx*2+1]*sn[m]);
      m += xx; if(m>=96) m-=96;
    }
    pl[o] = xs[o] + FFT_RES*(acc*(1.0f/96.0f) + bias);
  }
}

// ---------------- CAB 3x3 conv as implicit-GEMM MFMA ----------------
template<typename TIN, int CIN, int KPAD, int NCHUNK, bool ACT, bool OUTBF>
__global__ void __launch_bounds__(256) k_cab(const TIN* __restrict__ xin, const ushort* __restrict__ Wg,
    const float* __restrict__ bias, void* __restrict__ outv, int COUT, int istride){
  __shared__ short As[4*98*36];   // 28224 B; also reused for epilogue transpose
  int y0 = blockIdx.x*2;
  int ct = blockIdx.y;
  int b  = blockIdx.z;
  int t = threadIdx.x;
  int w = t>>6, lane = t&63, kq = lane>>4, lr = lane&15;
  f4v acc[3][4] = {};
  for(int ch=0; ch<NCHUNK; ++ch){
    int ci0 = ch*32;
    __syncthreads();
    for(int i=t;i<4*98*32;i+=256){
      int ci = i/392; int rem = i%392; int row = rem/98; int pxh = rem%98;
      int gy = y0 - 1 + row; int px = pxh - 1;
      int cig = ci0 + ci;
      short sv = 0;
      if((unsigned)gy<96u && (unsigned)px<96u && cig<CIN){
        if constexpr (std::is_same<TIN,float>::value)
          sv = f2bf(xin[(size_t)(b*CIN+cig)*istride + gy*96 + px]);
        else
          sv = (short)xin[(size_t)(b*CIN+cig)*istride + gy*96 + px];
      }
      As[(row*98+pxh)*36 + ci] = sv;
    }
    __syncthreads();
#pragma unroll
    for(int tap=0; tap<9; ++tap){
      int ky = tap/3, kx = tap%3;
      s8v bfr[4];
#pragma unroll
      for(int ts=0;ts<4;ts++)
        bfr[ts] = *(const s8v*)&Wg[((size_t)(ct*64 + ts*16 + lr)*9 + tap)*KPAD + ci0 + kq*8];
#pragma unroll
      for(int s=0;s<3;s++){
        int mt = w + 4*s;
        int orow = mt/6, px = (mt%6)*16 + lr;
        s8v af = *(const s8v*)&As[((orow+ky)*98 + px + kx)*36 + kq*8];
#pragma unroll
        for(int ts=0;ts<4;ts++)
          acc[s][ts] = __builtin_amdgcn_mfma_f32_16x16x32_bf16(af, bfr[ts], acc[s][ts], 0,0,0);
      }
    }
  }
  // epilogue
  if(OUTBF){
    __syncthreads();
    short* cT = As;   // [64 co][200] bf16
#pragma unroll
    for(int ts=0;ts<4;ts++){
      int cog = ct*64 + ts*16 + lr;
      float bb = (cog<COUT)? bias[cog] : 0.f;
#pragma unroll
      for(int s=0;s<3;s++){
#pragma unroll
        for(int reg=0;reg<4;reg++){
          int px = (w+4*s)*16 + kq*4 + reg;
          float v = acc[s][ts][reg] + bb;
          if(ACT) v = geluf(v);
          cT[(ts*16+lr)*200 + px] = f2bf(v);
        }
      }
    }
    __syncthreads();
    ushort* out = (ushort*)outv;
    for(int i=t;i<64*192;i+=256){
      int co=i/192, px=i%192;
      int cog = ct*64+co;
      if(cog<COUT) out[(size_t)(b*COUT+cog)*HWn + y0*96 + px] = (ushort)cT[co*200+px];
    }
  } else {
    float* cF = (float*)As;  // [32 co][200] fp32 per half
    float* out = (float*)outv;
    for(int h=0;h<2;h++){
      __syncthreads();
#pragma unroll
      for(int tt=0;tt<2;tt++){
        int ts = 2*h+tt;
        int cog = ct*64 + ts*16 + lr;
        float bb = (cog<COUT)? bias[cog] : 0.f;
#pragma unroll
        for(int s=0;s<3;s++){
#pragma unroll
          for(int reg=0;reg<4;reg++){
            int px = (w+4*s)*16 + kq*4 + reg;
            cF[(tt*16+lr)*200 + px] = acc[s][ts][reg] + bb;
          }
        }
      }
      __syncthreads();
      for(int i=t;i<32*192;i+=256){
        int co=i/192, px=i%192;
        int cog = ct*64 + h*32 + co;
        if(cog<COUT) out[(size_t)(b*COUT+cog)*HWn + y0*96 + px] = cF[co*200+px];
      }
    }
  }
}

// ---------------- ECA ----------------
__global__ void k_eca(const float* __restrict__ gap, const float* __restrict__ ew, float* __restrict__ s){
  int i = blockIdx.x*blockDim.x + threadIdx.x;
  if(i>=Bb*Cc) return;
  int b=i/Cc, c=i%Cc;
  float z=0.f;
  for(int j=0;j<5;j++){ int cc=c-2+j; if(cc>=0&&cc<Cc) z+=gap[b*Cc+cc]*ew[j]; }
  s[i]=sigm(z);
}

// ---------------- plk 13x13 conv (16->16) + fused dynamic depthwise 3x3 ----------------
__global__ void __launch_bounds__(256) k_plk(const float* __restrict__ ximg, const float* __restrict__ plk,
    const float* __restrict__ dkb, float* __restrict__ attn){
  __shared__ float tile[44*44];
  __shared__ float wl[169];
  __shared__ float dk9[9];
  int tile_id=blockIdx.x; int co=blockIdx.y; int b=blockIdx.z;
  int ty0=(tile_id/3)*32, tx0=(tile_id%3)*32;
  int t=threadIdx.x;
  int px0=(t%16)*2, py0=(t/16)*2;
  if(t<9) dk9[t]=dkb[b*144+co*9+t];
  float a00=0,a01=0,a10=0,a11=0;
  for(int ci=0;ci<PD;++ci){
    __syncthreads();
    for(int i=t;i<44*44;i+=256){
      int ly=i/44, lx=i%44;
      int gy=ty0+ly-6, gx=tx0+lx-6;
      float v=0.f;
      if((unsigned)gy<96u&&(unsigned)gx<96u) v=ximg[((size_t)(b*Cc+ci)*96+gy)*96+gx];
      tile[i]=v;
    }
    for(int i=t;i<169;i+=256) wl[i]=plk[((size_t)(co*PD+ci)*169)+i];
    __syncthreads();
    for(int rr2=0; rr2<14; ++rr2){
      float rowv[14];
      const float* trow = tile + (py0+rr2)*44 + px0;
#pragma unroll
      for(int i=0;i<14;i++) rowv[i]=trow[i];
      if(rr2<13){
        const float* wr = wl + rr2*13;
#pragma unroll
        for(int kx=0;kx<13;kx++){ float w=wr[kx]; a00+=w*rowv[kx]; a01+=w*rowv[kx+1]; }
      }
      if(rr2>=1){
        const float* wr = wl + (rr2-1)*13;
#pragma unroll
        for(int kx=0;kx<13;kx++){ float w=wr[kx]; a10+=w*rowv[kx]; a11+=w*rowv[kx+1]; }
      }
    }
    if(ci==co){
#pragma unroll
      for(int ky=0;ky<3;ky++)
#pragma unroll
        for(int kx=0;kx<3;kx++){
          float w=dk9[ky*3+kx];
          a00+=w*tile[(py0+5+ky)*44+px0+5+kx];
          a01+=w*tile[(py0+5+ky)*44+px0+6+kx];
          a10+=w*tile[(py0+6+ky)*44+px0+5+kx];
          a11+=w*tile[(py0+6+ky)*44+px0+6+kx];
        }
    }
  }
  int gy=ty0+py0, gx=tx0+px0;
  float* dst = attn + (size_t)(b*PD+co)*HWn;
  dst[gy*96+gx]=a00; dst[gy*96+gx+1]=a01; dst[(gy+1)*96+gx]=a10; dst[(gy+1)*96+gx+1]=a11;
}

// ---------------- aggr as MFMA GEMM + residual + conv_x scale -> xm (B,N,C) ----------------
__global__ void __launch_bounds__(256) k_aggrm(const float* __restrict__ x, const float* __restrict__ attn,
   const float* __restrict__ ximg, const float* __restrict__ ycab, const float* __restrict__ aggw,
   const float* __restrict__ aggb, const float* __restrict__ svec, float* __restrict__ xm){
  __shared__ short smem[2*64*200];   // As | Ws ; reused as cF (fp32 64x68) in epilogue
  short* As = smem;
  short* Ws = smem + 64*200;
  int rt = blockIdx.x, ct = blockIdx.y;
  int t = threadIdx.x;
  int w = t>>6, lane = t&63, kq = lane>>4, lr = lane&15;
  int grow0 = rt*64; int b = grow0/HWn; int n0 = grow0%HWn;
  // stage A: As[r][kk] = u[kk][n0+r]; u = concat(attn[0:16], ximg[16:180])
  for(int i=t;i<192*64;i+=256){
    int kk=i/64, r=i%64;
    float v=0.f;
    if(kk<PD)      v = attn[(size_t)(b*PD+kk)*HWn + n0 + r];
    else if(kk<Cc) v = ximg[(size_t)(b*Cc+kk)*HWn + n0 + r];
    As[r*200+kk] = f2bf(v);
  }
  // stage W: Ws[j][kk] = aggw[jc][kk] (L2-cached across rt blocks)
  for(int i=t;i<64*192;i+=256){
    int j=i/192, kk=i%192;
    int jc=ct*64+j;
    float v = (jc<Cc && kk<Cc)? aggw[(size_t)jc*Cc+kk] : 0.f;
    Ws[j*200+kk]=f2bf(v);
  }
  __syncthreads();
  f4v acc[4]={};
  int arow=(w*16+lr)*200 + kq*8;
#pragma unroll
  for(int k0=0;k0<192;k0+=32){
    s8v af = *(const s8v*)&As[arow+k0];
#pragma unroll
    for(int ts=0;ts<4;ts++){
      s8v wf = *(const s8v*)&Ws[(ts*16+lr)*200 + kq*8 + k0];
      acc[ts]=__builtin_amdgcn_mfma_f32_16x16x32_bf16(af,wf,acc[ts],0,0,0);
    }
  }
  __syncthreads();
  // epilogue: cF[m][j] = acc + aggb + CONV_SCALE*svec*ycab  (stride 68, conflict-free)
  float* cF = (float*)smem;
#pragma unroll
  for(int ts=0;ts<4;ts++){
    int j = ts*16+lr;
    int jc = ct*64 + j;
    float bb=0.f, sv=0.f;
    if(jc<Cc){ bb=aggb[jc]; sv=CONV_SCALE*svec[b*Cc+jc]; }
    const float* yrow = ycab + ((jc<Cc)? (size_t)(b*Cc+jc)*HWn + n0 : 0);
#pragma unroll
    for(int reg=0;reg<4;reg++){
      int m = w*16 + kq*4 + reg;
      float v = 0.f;
      if(jc<Cc) v = acc[ts][reg] + bb + sv*yrow[m];
      cF[m*68+j] = v;
    }
  }
  __syncthreads();
  // coalesced write of xm = x + cF
  for(int i=t;i<64*64;i+=256){
    int m=i>>6, j=i&63;
    int jc=ct*64+j;
    if(jc<Cc){
      size_t o = (size_t)(grow0+m)*Cc + jc;
      xm[o] = x[o] + cF[m*68+j];
    }
  }
}

// ---------------- LN2 fused: stats + normalize + bf16 cast, K padded 180->192 ----------------
__global__ void __launch_bounds__(256) k_ln2(const float* __restrict__ xm, const float* __restrict__ g2,
    const float* __restrict__ b2, ushort* __restrict__ xn2){
  int w = (blockIdx.x*256 + threadIdx.x)>>6;
  int lane = threadIdx.x&63;
  const float* row = xm + (size_t)w*Cc;
  float s=0,sq=0;
  for(int e=lane;e<Cc;e+=64){ float v=row[e]; s+=v; sq+=v*v; }
  s=wredsum(s); sq=wredsum(sq);
  float m=s*(1.0f/180.0f); float v=sq*(1.0f/180.0f)-m*m;
  float rstd=rsqrtf(v+EPSLN);
  ushort* orow = xn2 + (size_t)w*192;
  for(int e=lane;e<192;e+=64){
    float val = (e<Cc)? (row[e]-m)*rstd*g2[e]+b2[e] : 0.f;
    orow[e] = (ushort)f2bf(val);
  }
}

// ---------------- fc1 MFMA: t1[j][n] = xn2 @ fc1_w^T + fb  (bf16 out) ----------------
__global__ void __launch_bounds__(256) k_fc1(const ushort* __restrict__ xn2,
    const float* __restrict__ fw, const float* __restrict__ fb, ushort* __restrict__ t1){
  __shared__ short As[64*200];
  __shared__ short Ws[64*200];
  int rt = blockIdx.x, ct = blockIdx.y;
  int t = threadIdx.x;
  int w = t>>6, lane = t&63, kq = lane>>4, lr = lane&15;
  int grow0 = rt*64;
  for(int i=t;i<64*24;i+=256){
    int r=i/24, seg=i%24;
    *(s8v*)&As[r*200+seg*8] = *(const s8v*)&xn2[(size_t)(grow0+r)*192 + seg*8];
  }
  for(int i=t;i<64*192;i+=256){
    int j=i/192, kk=i%192;
    int jc=ct*64+j;
    float v = (jc<H2 && kk<Cc)? fw[(size_t)jc*Cc+kk] : 0.f;
    Ws[j*200+kk]=f2bf(v);
  }
  __syncthreads();
  f4v acc[4]={};
  int arow=(w*16+lr)*200 + kq*8;
#pragma unroll
  for(int k0=0;k0<192;k0+=32){
    s8v af = *(const s8v*)&As[arow+k0];
#pragma unroll
    for(int ts=0;ts<4;ts++){
      s8v wf = *(const s8v*)&Ws[(ts*16+lr)*200 + kq*8 + k0];
      acc[ts]=__builtin_amdgcn_mfma_f32_16x16x32_bf16(af,wf,acc[ts],0,0,0);
    }
  }
  __syncthreads();
  short* cT = Ws;
#pragma unroll
  for(int ts=0;ts<4;ts++){
    int j = ts*16+lr;
    float bb = fb[ct*64+j < H2 ? ct*64+j : 0];
#pragma unroll
    for(int reg=0;reg<4;reg++){
      int m = w*16 + kq*4 + reg;
      cT[j*72+m] = f2bf(acc[ts][reg]+bb);
    }
  }
  __syncthreads();
  int bb_ = grow0/HWn, n0 = grow0%HWn;
  for(int i=t;i<4096;i+=256){
    int j=i>>6, m=i&63;
    int jc=ct*64+j;
    if(jc<H2) t1[((size_t)(bb_*H2+jc))*HWn + n0 + m] = (ushort)cT[j*72+m];
  }
}

// ---------------- depthwise 3x3 on t1 + GLU -> pg (B,360,HW) bf16 ----------------
__global__ void __launch_bounds__(256) k_dwglu(const bf16* __restrict__ t1, const float* __restrict__ dww,
    const float* __restrict__ dwb, bf16* __restrict__ pg){
  __shared__ float ta[34*34];
  __shared__ float tg[34*34];
  int tile_id=blockIdx.x; int c=blockIdx.y; int b=blockIdx.z;
  int ty0=(tile_id/3)*32, tx0=(tile_id%3)*32;
  int t=threadIdx.x;
  int px0=(t%16)*2, py0=(t/16)*2;
  for(int i=t;i<34*34;i+=256){
    int ly=i/34, lx=i%34; int gy=ty0+ly-1, gx=tx0+lx-1;
    bool ok=((unsigned)gy<96u&&(unsigned)gx<96u);
    ta[i]= ok? __bfloat162float(t1[((size_t)(b*H2+c)*96+gy)*96+gx]) :0.f;
    tg[i]= ok? __bfloat162float(t1[((size_t)(b*H2+c+HID)*96+gy)*96+gx]) :0.f;
  }
  __syncthreads();
  float wp[9],wg[9];
#pragma unroll
  for(int i=0;i<9;i++){ wp[i]=dww[c*9+i]; wg[i]=dww[(c+HID)*9+i]; }
  float bp=dwb[c], bg=dwb[c+HID];
#pragma unroll
  for(int oy=0;oy<2;oy++)
#pragma unroll
    for(int ox=0;ox<2;ox++){
      float p=bp,g=bg;
#pragma unroll
      for(int ky=0;ky<3;ky++)
#pragma unroll
        for(int kx=0;kx<3;kx++){
          p+=wp[ky*3+kx]*ta[(py0+oy+ky)*34+px0+ox+kx];
          g+=wg[ky*3+kx]*tg[(py0+oy+ky)*34+px0+ox+kx];
        }
      float val = p * g * sigm(g);
      pg[((size_t)(b*HID+c)*96 + ty0+py0+oy)*96 + tx0+px0+ox] = __float2bfloat16(val);
    }
}

// ---------------- fc2 MFMA + residual -> out (B,N,C) ----------------
__global__ void __launch_bounds__(256) k_fc2(const ushort* __restrict__ pg, const float* __restrict__ xm,
    const float* __restrict__ fw, const float* __restrict__ fb, float* __restrict__ out){
  __shared__ short As[64*200];
  __shared__ short Ws[64*200];
  int rt = blockIdx.x, ct = blockIdx.y;
  int t = threadIdx.x;
  int w = t>>6, lane = t&63, kq = lane>>4, lr = lane&15;
  int grow0 = rt*64; int b = grow0/HWn; int n0 = grow0%HWn;
  f4v acc[4]={};
  for(int kc0=0;kc0<384;kc0+=192){
    __syncthreads();
    for(int i=t;i<192*64;i+=256){
      int kk=i/64, r=i%64;
      int kc=kc0+kk;
      As[r*200+kk] = (kc<HID)? (short)pg[((size_t)(b*HID+kc))*HWn + n0 + r] : (short)0;
    }
    for(int i=t;i<64*192;i+=256){
      int j=i/192, kk=i%192;
      int jc=ct*64+j; int kc=kc0+kk;
      float v = (jc<Cc && kc<HID)? fw[(size_t)jc*HID+kc] : 0.f;
      Ws[j*200+kk]=f2bf(v);
    }
    __syncthreads();
    int arow=(w*16+lr)*200 + kq*8;
#pragma unroll
    for(int k0=0;k0<192;k0+=32){
      s8v af = *(const s8v*)&As[arow+k0];
#pragma unroll
      for(int ts=0;ts<4;ts++){
        s8v wf = *(const s8v*)&Ws[(ts*16+lr)*200 + kq*8 + k0];
        acc[ts]=__builtin_amdgcn_mfma_f32_16x16x32_bf16(af,wf,acc[ts],0,0,0);
      }
    }
  }
#pragma unroll
  for(int ts=0;ts<4;ts++){
    int jc = ct*64 + ts*16 + lr;
    if(jc>=Cc) continue;
    float bb = fb[jc];
#pragma unroll
    for(int reg=0;reg<4;reg++){
      int m = w*16 + kq*4 + reg;
      size_t o = (size_t)(grow0+m)*Cc + jc;
      out[o] = xm[o] + acc[ts][reg] + bb;
    }
  }
}

extern "C" void kernel_launch(void* const* d_in, const int* in_sizes, int n_in,
                              void* d_out, int out_size, void* d_ws, size_t ws_size,
                              hipStream_t stream){
  (void)in_sizes; (void)n_in; (void)out_size; (void)ws_size;
  const float* x     = (const float*)d_in[0];
  const float* ln1_g = (const float*)d_in[3];
  const float* ln1_b = (const float*)d_in[4];
  const float* band_w= (const float*)d_in[5];
  const float* band_b= (const float*)d_in[6];
  const float* gate_w= (const float*)d_in[7];
  const float* gate_b= (const float*)d_in[8];
  const float* cab_w1= (const float*)d_in[9];
  const float* cab_b1= (const float*)d_in[10];
  const float* cab_w2= (const float*)d_in[11];
  const float* cab_b2= (const float*)d_in[12];
  const float* eca_w = (const float*)d_in[13];
  const float* plkw  = (const float*)d_in[14];
  const float* dwc_w1= (const float*)d_in[15];
  const float* dwc_b1= (const float*)d_in[16];
  const float* dwc_w2= (const float*)d_in[17];
  const float* dwc_b2= (const float*)d_in[18];
  const float* aggr_w= (const float*)d_in[19];
  const float* aggr_b= (const float*)d_in[20];
  const float* ln2_g = (const float*)d_in[21];
  const float* ln2_b = (const float*)d_in[22];
  const float* fc1_w = (const float*)d_in[23];
  const float* fc1_b = (const float*)d_in[24];
  const float* dw_w  = (const float*)d_in[25];
  const float* dw_b  = (const float*)d_in[26];
  const float* fc2_w = (const float*)d_in[27];
  const float* fc2_b = (const float*)d_in[28];

  float* ws = (float*)d_ws;
  // persistent region
  float* xm   = ws;                      // 13,271,040
  float* m1   = ws + 13271040;           // 1,440
  float* gates= ws + 13272480;           // 32
  float* dkb  = ws + 13272512;           // 1,152
  float* biasb= ws + 13273664;           // 1,440
  float* gapb = ws + 13275104;           // 1,440
  float* svec = ws + 13276544;           // 1,440 -> 13,277,984
  ushort* Wg1 = (ushort*)(ws + 13278000);// 110,592 shorts = 55,296 floats
  ushort* Wg2 = (ushort*)(ws + 13333296);// 110,592 shorts = 55,296 floats -> 13,388,592
  float* big  = ws + 13388800;
  // phase 1 inside big:
  float* ximg = big;                     // 13,271,040
  float* spec = big + 13271040;          // 13,547,520 (xfft in first 9216 of each 9408 plane)
  ushort* mid = (ushort*)(big + 26818560); // 4,423,680 bf16 = 2,211,840 float slots
  float* attn = big + 29030400;          // 1,179,648 -> phase-1 top = 30,210,048
  float* ycab = spec;                    // reuse (stride 9216), spec dead after conv1
  // phase 2 aliases big:
  ushort* t1  = (ushort*)big;                    // 26,542,080 float slots
  float*  reg2= big + 26542080;
  ushort* xn2 = (ushort*)reg2;                   // 7,077,888 float slots (ln2->fc1)
  ushort* pgb = (ushort*)reg2;                   // 13,271,040 float slots (dwglu->fc2)
  // total = 13,388,800 + 39,813,120 = 53,201,920 floats (~213 MB)

  k_packw<<<432,256,0,stream>>>(cab_w1, cab_w2, Wg1, Wg2);
  k_ln1<<<2304,256,0,stream>>>(x, ln1_g, ln1_b, ximg);
  k_plane_mean<<<1440,256,0,stream>>>(ximg, m1);
  k_small<<<1,64,0,stream>>>(m1, gate_w, gate_b, dwc_w1, dwc_b1, dwc_w2, dwc_b2, band_b, gates, dkb, biasb);
  k_fwd_x<<<1440,256,0,stream>>>(ximg, spec);
  k_fwd_y<<<1440,256,0,stream>>>(spec);
  k_bandmix<<<dim3(Bb,96,2),256,0,stream>>>(spec, band_w, gates);
  k_inv_y<<<1440,256,0,stream>>>(spec);
  k_inv_x<<<1440,256,0,stream>>>(spec, ximg, biasb);
  k_cab<float, Cc, 192, 6, true,  true ><<<dim3(48,1,Bb),256,0,stream>>>(spec, Wg1, cab_b1, (void*)mid, CRr, SPL);
  k_cab<ushort, CRr, 64, 2, false, false><<<dim3(48,3,Bb),256,0,stream>>>(mid, Wg2, cab_b2, (void*)ycab, Cc, HWn);
  k_plane_mean<<<1440,256,0,stream>>>(ycab, gapb);
  k_eca<<<6,256,0,stream>>>(gapb, eca_w, svec);
  k_plk<<<dim3(9,PD,Bb),256,0,stream>>>(ximg, plkw, dkb, attn);
  k_aggrm<<<dim3(1152,3),256,0,stream>>>(x, attn, ximg, ycab, aggr_w, aggr_b, svec, xm);
  k_ln2<<<18432,256,0,stream>>>(xm, ln2_g, ln2_b, xn2);
  k_fc1<<<dim3(1152,12),256,0,stream>>>(xn2, fc1_w, fc1_b, t1);
  k_dwglu<<<dim3(9,HID,Bb),256,0,stream>>>((const bf16*)t1, dw_w, dw_b, (bf16*)pgb);
  k_fc2<<<dim3(1152,3),256,0,stream>>>(pgb, xm, fc2_w, fc2_b, (float*)d_out);
}

// Round 6
// 2223.319 us; speedup vs baseline: 1.6338x; 1.2030x over previous
//
#include <hip/hip_runtime.h>
#include <hip/hip_bf16.h>
#include <math.h>
#include <type_traits>

#define Bb 8
#define Cc 180
#define HWn 9216
#define PD 16
#define CRr 60
#define HID 360
#define H2 720
#define NF 49
#define SPL 9408   /* spectral plane stride in floats: 96*49*2 */
#define CONV_SCALE 0.01f
#define FFT_RES 0.15f
#define EPSLN 1e-5f
#define TWOPI_96 0.06544984694978735f

typedef __hip_bfloat16 bf16;
typedef unsigned short ushort;
typedef __attribute__((ext_vector_type(8))) short s8v;   // 8 bf16 (4 VGPRs) MFMA A/B frag
typedef __attribute__((ext_vector_type(4))) float f4v;   // MFMA C/D frag

__device__ __forceinline__ float geluf(float x){ return 0.5f*x*(1.0f+erff(x*0.7071067811865476f)); }
__device__ __forceinline__ float sigm(float x){ return 1.0f/(1.0f+expf(-x)); }
__device__ __forceinline__ short f2bf(float f){
  unsigned u = __float_as_uint(f);
  u += 0x7fff + ((u>>16)&1);
  return (short)(u>>16);
}
__device__ __forceinline__ float wredsum(float v){
#pragma unroll
  for(int m=1;m<64;m<<=1) v += __shfl_xor(v,m,64);
  return v;
}

// ---------------- LN1 + transpose to (B,C,H,W) ----------------
__global__ void __launch_bounds__(256) k_ln1(const float* __restrict__ x, const float* __restrict__ g,
                      const float* __restrict__ be, float* __restrict__ ximg){
  __shared__ float sb[32*Cc];
  int b = blockIdx.x / 288;
  int n0 = (blockIdx.x % 288) * 32;
  int t = threadIdx.x;
  const float* src = x + (size_t)(b*HWn + n0)*Cc;
  for(int i=t;i<32*Cc;i+=256) sb[i]=src[i];
  __syncthreads();
  int w = t>>6, lane = t&63;
  for(int pi=0; pi<8; ++pi){
    int p = w*8+pi;
    float s=0.f, sq=0.f;
    for(int e=lane;e<Cc;e+=64){ float v=sb[p*Cc+e]; s+=v; sq+=v*v; }
    s = wredsum(s); sq = wredsum(sq);
    float mean = s*(1.0f/180.0f);
    float var = sq*(1.0f/180.0f) - mean*mean;
    float rstd = rsqrtf(var + EPSLN);
    for(int e=lane;e<Cc;e+=64){ float v=sb[p*Cc+e]; sb[p*Cc+e] = (v-mean)*rstd*g[e]+be[e]; }
  }
  __syncthreads();
  for(int i=t;i<32*Cc;i+=256){
    int c = i/32, p = i%32;
    ximg[(size_t)(b*Cc+c)*HWn + n0 + p] = sb[p*Cc+c];
  }
}

// ---------------- plane mean (9216 -> 1) ----------------
__global__ void __launch_bounds__(256) k_plane_mean(const float* __restrict__ in, float* __restrict__ out){
  __shared__ float red[4];
  int pl = blockIdx.x; int t = threadIdx.x;
  const float* p = in + (size_t)pl*HWn;
  float s=0.f;
  for(int i=t;i<HWn;i+=256) s+=p[i];
  s = wredsum(s);
  if((t&63)==0) red[t>>6]=s;
  __syncthreads();
  if(t==0) out[pl] = (red[0]+red[1]+red[2]+red[3]) * (1.0f/9216.0f);
}

// ---------------- small: gates, hdn->dk, fft bias ----------------
__global__ void k_small(const float* __restrict__ m1, const float* __restrict__ gate_w,
   const float* __restrict__ gate_b, const float* __restrict__ dwc_w1, const float* __restrict__ dwc_b1,
   const float* __restrict__ dwc_w2, const float* __restrict__ dwc_b2, const float* __restrict__ band_b,
   float* __restrict__ gates, float* __restrict__ dkb, float* __restrict__ biasb){
  int b = threadIdx.x;
  if(b>=Bb) return;
  const float* m = m1 + b*Cc;
  float gv[3];
  for(int k=0;k<3;k++){ float a=gate_b[k]; for(int c=0;c<Cc;c++) a+=m[c]*gate_w[k*Cc+c]; gv[k]=sigm(a);}
  float e0=expf(gv[0]), e1=expf(gv[1]), e2=expf(gv[2]); float inv=1.0f/(e0+e1+e2);
  float g0=e0*inv,g1=e1*inv,g2=e2*inv;
  gates[b*3+0]=g0; gates[b*3+1]=g1; gates[b*3+2]=g2;
  float hd[8];
  for(int j=0;j<8;j++){ float a=dwc_b1[j]; for(int c=0;c<PD;c++) a+=m[c]*dwc_w1[j*PD+c]; hd[j]=geluf(a);}
  for(int i=0;i<144;i++){ float a=dwc_b2[i]; for(int j=0;j<8;j++) a+=hd[j]*dwc_w2[i*8+j]; dkb[b*144+i]=a; }
  for(int d=0;d<Cc;d++) biasb[b*Cc+d] = g0*band_b[0*Cc+d]+g1*band_b[1*Cc+d]+g2*band_b[2*Cc+d];
}

// ------- pack weights to bf16: CAB convs [co][tap][ci_pad], fc1 [768][192], fc2 [192][384], aggr [192][192] -------
__global__ void __launch_bounds__(256) k_packw(const float* __restrict__ w1, const float* __restrict__ w2,
    const float* __restrict__ fw1, const float* __restrict__ fw2, const float* __restrict__ aw,
    ushort* __restrict__ Wg1, ushort* __restrict__ Wg2, ushort* __restrict__ Wp1,
    ushort* __restrict__ Wp2, ushort* __restrict__ Wpa){
  int t = blockIdx.x*256 + threadIdx.x;
  if(t < 64*9*192){
    int co = t/(9*192); int rem = t%(9*192); int tap = rem/192; int ci = rem%192;
    float v = (co<CRr && ci<Cc) ? w1[((size_t)(co*Cc+ci))*9 + tap] : 0.f;
    Wg1[t] = (ushort)f2bf(v);
  }
  if(t < 192*9*64){
    int co = t/(9*64); int rem = t%(9*64); int tap = rem/64; int ci = rem%64;
    float v = (co<Cc && ci<CRr) ? w2[((size_t)(co*CRr+ci))*9 + tap] : 0.f;
    Wg2[t] = (ushort)f2bf(v);
  }
  if(t < 768*192){
    int j=t/192, k=t%192;
    Wp1[t] = (ushort)f2bf((j<H2 && k<Cc)? fw1[(size_t)j*Cc+k] : 0.f);
  }
  if(t < 192*384){
    int j=t/384, k=t%384;
    Wp2[t] = (ushort)f2bf((j<Cc && k<HID)? fw2[(size_t)j*HID+k] : 0.f);
  }
  if(t < 192*192){
    int j=t/192, k=t%192;
    Wpa[t] = (ushort)f2bf((j<Cc && k<Cc)? aw[(size_t)j*Cc+k] : 0.f);
  }
}

// ---------------- forward DFT along x (real -> complex, 49 freqs) ----------------
__global__ void __launch_bounds__(256) k_fwd_x(const float* __restrict__ ximg, float* __restrict__ V){
  __shared__ float img[HWn];
  __shared__ float cs[96], sn[96];
  int bc = blockIdx.x; int t = threadIdx.x;
  const float* src = ximg + (size_t)bc*HWn;
  for(int i=t;i<HWn;i+=256) img[i]=src[i];
  if(t<96){ float th = (float)t * TWOPI_96; cs[t]=cosf(th); sn[t]=sinf(th); }
  __syncthreads();
  float* dst = V + (size_t)bc*SPL;
  for(int o=t;o<96*NF;o+=256){
    int y=o/NF, kx=o%NF;
    float re=0.f, im=0.f; int m=0;
    const float* row = img + y*96;
    for(int xx=0; xx<96; ++xx){
      float v=row[xx];
      re += v*cs[m]; im -= v*sn[m];
      m += kx; if(m>=96) m-=96;
    }
    dst[o*2]=re; dst[o*2+1]=im;
  }
}

// ---------------- forward DFT along y (complex -> complex), ortho 1/96, IN-PLACE ----------------
__global__ void __launch_bounds__(256) k_fwd_y(float* __restrict__ S){
  __shared__ float vb[SPL];
  __shared__ float cs[96], sn[96];
  int bc=blockIdx.x, t=threadIdx.x;
  float* pl = S + (size_t)bc*SPL;
  for(int i=t;i<SPL;i+=256) vb[i]=pl[i];
  if(t<96){ float th = (float)t * TWOPI_96; cs[t]=cosf(th); sn[t]=sinf(th); }
  __syncthreads();
  for(int o=t;o<96*NF;o+=256){
    int ky=o/NF, kx=o%NF;
    float re=0.f, im=0.f; int m=0;
    for(int y=0;y<96;++y){
      float vr=vb[(y*NF+kx)*2], vi=vb[(y*NF+kx)*2+1];
      float c=cs[m], s=sn[m];
      re += vr*c + vi*s;
      im += vi*c - vr*s;
      m += ky; if(m>=96) m-=96;
    }
    pl[o*2]=re*(1.0f/96.0f); pl[o*2+1]=im*(1.0f/96.0f);
  }
}

// ---------------- per-frequency band channel mix: Y = g_bk * W_k @ X, IN-PLACE ----------------
__global__ void __launch_bounds__(256) k_bandmix(float* __restrict__ S, const float* __restrict__ band_w,
                          const float* __restrict__ gates){
  __shared__ float xs[Cc*50];
  int b = blockIdx.x; int ky = blockIdx.y; int half = blockIdx.z;
  int kx0 = half*25; int nkx = half? 24:25;
  int t=threadIdx.x;
  for(int i=t;i<Cc*nkx*2;i+=256){
    int c = i/(nkx*2); int r = i%(nkx*2);
    xs[c*50+r] = S[ (size_t)(b*Cc+c)*SPL + ky*(NF*2) + kx0*2 + r ];
  }
  __syncthreads();
  float yy = -1.0f + 2.0f*(float)ky/95.0f;
  for(int o=t;o<Cc*nkx;o+=256){
    int d = o/nkx, kxl = o%nkx; int kx = kx0+kxl;
    float xxf = (float)kx/48.0f;
    float rr = sqrtf(yy*yy+xxf*xxf);
    int k = (rr<=0.25f)?0:((rr<=0.6f)?1:2);
    float g = gates[b*3+k];
    const float* wr = band_w + ((size_t)k*Cc + d)*Cc;
    float re=0.f, im=0.f;
    for(int c=0;c<Cc;++c){
      float w=wr[c];
      re += w*xs[c*50 + kxl*2];
      im += w*xs[c*50 + kxl*2 + 1];
    }
    size_t off = (size_t)(b*Cc+d)*SPL + ky*(NF*2) + kx*2;
    S[off]=g*re; S[off+1]=g*im;
  }
}

// ---------------- inverse DFT along ky (complex -> complex, e^{+i}), IN-PLACE ----------------
__global__ void __launch_bounds__(256) k_inv_y(float* __restrict__ S){
  __shared__ float vb[SPL];
  __shared__ float cs[96], sn[96];
  int bd=blockIdx.x, t=threadIdx.x;
  float* pl = S + (size_t)bd*SPL;
  for(int i=t;i<SPL;i+=256) vb[i]=pl[i];
  if(t<96){ float th = (float)t * TWOPI_96; cs[t]=cosf(th); sn[t]=sinf(th); }
  __syncthreads();
  for(int o=t;o<96*NF;o+=256){
    int y=o/NF, kx=o%NF;
    float re=0.f, im=0.f; int m=0;
    for(int ky=0;ky<96;++ky){
      float vr=vb[(ky*NF+kx)*2], vi=vb[(ky*NF+kx)*2+1];
      float c=cs[m], s=sn[m];
      re += vr*c - vi*s;
      im += vr*s + vi*c;
      m += y; if(m>=96) m-=96;
    }
    pl[o*2]=re; pl[o*2+1]=im;
  }
}

// -------- inverse rDFT along kx + combine, IN-PLACE into spec plane (first 9216 floats) --------
__global__ void __launch_bounds__(256) k_inv_x(float* __restrict__ S, const float* __restrict__ ximg,
                        const float* __restrict__ biasb){
  __shared__ float tb[SPL];
  __shared__ float cs[96], sn[96];
  int bd = blockIdx.x; int t=threadIdx.x;
  int b = bd / Cc; int d = bd % Cc;
  float* pl = S + (size_t)bd*SPL;
  for(int i=t;i<SPL;i+=256) tb[i]=pl[i];
  if(t<96){ float th = (float)t * TWOPI_96; cs[t]=cosf(th); sn[t]=sinf(th); }
  __syncthreads();
  float bias = biasb[b*Cc+d];
  const float* xs = ximg + (size_t)bd*HWn;
  for(int o=t;o<HWn;o+=256){
    int y=o/96, xx=o%96;
    float acc=0.f; int m=0;
    const float* row = tb + y*(NF*2);
    for(int kx=0;kx<NF;++kx){
      float wgt = (kx==0||kx==48)?1.0f:2.0f;
      acc += wgt*(row[kx*2]*cs[m] - row[kx*2+1]*sn[m]);
      m += xx; if(m>=96) m-=96;
    }
    pl[o] = xs[o] + FFT_RES*(acc*(1.0f/96.0f) + bias);
  }
}

// ---------------- CAB 3x3 conv as implicit-GEMM MFMA ----------------
template<typename TIN, int CIN, int KPAD, int NCHUNK, bool ACT, bool OUTBF>
__global__ void __launch_bounds__(256) k_cab(const TIN* __restrict__ xin, const ushort* __restrict__ Wg,
    const float* __restrict__ bias, void* __restrict__ outv, int COUT, int istride){
  __shared__ short As[4*98*36];   // 28224 B; also reused for epilogue transpose
  int y0 = blockIdx.x*2;
  int ct = blockIdx.y;
  int b  = blockIdx.z;
  int t = threadIdx.x;
  int w = t>>6, lane = t&63, kq = lane>>4, lr = lane&15;
  f4v acc[3][4] = {};
  for(int ch=0; ch<NCHUNK; ++ch){
    int ci0 = ch*32;
    __syncthreads();
    for(int i=t;i<4*98*32;i+=256){
      int ci = i/392; int rem = i%392; int row = rem/98; int pxh = rem%98;
      int gy = y0 - 1 + row; int px = pxh - 1;
      int cig = ci0 + ci;
      short sv = 0;
      if((unsigned)gy<96u && (unsigned)px<96u && cig<CIN){
        if constexpr (std::is_same<TIN,float>::value)
          sv = f2bf(xin[(size_t)(b*CIN+cig)*istride + gy*96 + px]);
        else
          sv = (short)xin[(size_t)(b*CIN+cig)*istride + gy*96 + px];
      }
      As[(row*98+pxh)*36 + ci] = sv;
    }
    __syncthreads();
#pragma unroll
    for(int tap=0; tap<9; ++tap){
      int ky = tap/3, kx = tap%3;
      s8v bfr[4];
#pragma unroll
      for(int ts=0;ts<4;ts++)
        bfr[ts] = *(const s8v*)&Wg[((size_t)(ct*64 + ts*16 + lr)*9 + tap)*KPAD + ci0 + kq*8];
#pragma unroll
      for(int s=0;s<3;s++){
        int mt = w + 4*s;
        int orow = mt/6, px = (mt%6)*16 + lr;
        s8v af = *(const s8v*)&As[((orow+ky)*98 + px + kx)*36 + kq*8];
#pragma unroll
        for(int ts=0;ts<4;ts++)
          acc[s][ts] = __builtin_amdgcn_mfma_f32_16x16x32_bf16(af, bfr[ts], acc[s][ts], 0,0,0);
      }
    }
  }
  // epilogue
  if(OUTBF){
    __syncthreads();
    short* cT = As;   // [64 co][200] bf16
#pragma unroll
    for(int ts=0;ts<4;ts++){
      int cog = ct*64 + ts*16 + lr;
      float bb = (cog<COUT)? bias[cog] : 0.f;
#pragma unroll
      for(int s=0;s<3;s++){
#pragma unroll
        for(int reg=0;reg<4;reg++){
          int px = (w+4*s)*16 + kq*4 + reg;
          float v = acc[s][ts][reg] + bb;
          if(ACT) v = geluf(v);
          cT[(ts*16+lr)*200 + px] = f2bf(v);
        }
      }
    }
    __syncthreads();
    ushort* out = (ushort*)outv;
    for(int i=t;i<64*192;i+=256){
      int co=i/192, px=i%192;
      int cog = ct*64+co;
      if(cog<COUT) out[(size_t)(b*COUT+cog)*HWn + y0*96 + px] = (ushort)cT[co*200+px];
    }
  } else {
    float* cF = (float*)As;  // [32 co][200] fp32 per half
    float* out = (float*)outv;
    for(int h=0;h<2;h++){
      __syncthreads();
#pragma unroll
      for(int tt=0;tt<2;tt++){
        int ts = 2*h+tt;
        int cog = ct*64 + ts*16 + lr;
        float bb = (cog<COUT)? bias[cog] : 0.f;
#pragma unroll
        for(int s=0;s<3;s++){
#pragma unroll
          for(int reg=0;reg<4;reg++){
            int px = (w+4*s)*16 + kq*4 + reg;
            cF[(tt*16+lr)*200 + px] = acc[s][ts][reg] + bb;
          }
        }
      }
      __syncthreads();
      for(int i=t;i<32*192;i+=256){
        int co=i/192, px=i%192;
        int cog = ct*64 + h*32 + co;
        if(cog<COUT) out[(size_t)(b*COUT+cog)*HWn + y0*96 + px] = cF[co*200+px];
      }
    }
  }
}

// ---------------- ECA ----------------
__global__ void k_eca(const float* __restrict__ gap, const float* __restrict__ ew, float* __restrict__ s){
  int i = blockIdx.x*blockDim.x + threadIdx.x;
  if(i>=Bb*Cc) return;
  int b=i/Cc, c=i%Cc;
  float z=0.f;
  for(int j=0;j<5;j++){ int cc=c-2+j; if(cc>=0&&cc<Cc) z+=gap[b*Cc+cc]*ew[j]; }
  s[i]=sigm(z);
}

// ---------------- plk 13x13 conv (16->16) + fused dynamic depthwise 3x3 ----------------
__global__ void __launch_bounds__(256) k_plk(const float* __restrict__ ximg, const float* __restrict__ plk,
    const float* __restrict__ dkb, float* __restrict__ attn){
  __shared__ float tile[44*44];
  __shared__ float wl[169];
  __shared__ float dk9[9];
  int tile_id=blockIdx.x; int co=blockIdx.y; int b=blockIdx.z;
  int ty0=(tile_id/3)*32, tx0=(tile_id%3)*32;
  int t=threadIdx.x;
  int px0=(t%16)*2, py0=(t/16)*2;
  if(t<9) dk9[t]=dkb[b*144+co*9+t];
  float a00=0,a01=0,a10=0,a11=0;
  for(int ci=0;ci<PD;++ci){
    __syncthreads();
    for(int i=t;i<44*44;i+=256){
      int ly=i/44, lx=i%44;
      int gy=ty0+ly-6, gx=tx0+lx-6;
      float v=0.f;
      if((unsigned)gy<96u&&(unsigned)gx<96u) v=ximg[((size_t)(b*Cc+ci)*96+gy)*96+gx];
      tile[i]=v;
    }
    for(int i=t;i<169;i+=256) wl[i]=plk[((size_t)(co*PD+ci)*169)+i];
    __syncthreads();
    for(int rr2=0; rr2<14; ++rr2){
      float rowv[14];
      const float* trow = tile + (py0+rr2)*44 + px0;
#pragma unroll
      for(int i=0;i<14;i++) rowv[i]=trow[i];
      if(rr2<13){
        const float* wr = wl + rr2*13;
#pragma unroll
        for(int kx=0;kx<13;kx++){ float w=wr[kx]; a00+=w*rowv[kx]; a01+=w*rowv[kx+1]; }
      }
      if(rr2>=1){
        const float* wr = wl + (rr2-1)*13;
#pragma unroll
        for(int kx=0;kx<13;kx++){ float w=wr[kx]; a10+=w*rowv[kx]; a11+=w*rowv[kx+1]; }
      }
    }
    if(ci==co){
#pragma unroll
      for(int ky=0;ky<3;ky++)
#pragma unroll
        for(int kx=0;kx<3;kx++){
          float w=dk9[ky*3+kx];
          a00+=w*tile[(py0+5+ky)*44+px0+5+kx];
          a01+=w*tile[(py0+5+ky)*44+px0+6+kx];
          a10+=w*tile[(py0+6+ky)*44+px0+5+kx];
          a11+=w*tile[(py0+6+ky)*44+px0+6+kx];
        }
    }
  }
  int gy=ty0+py0, gx=tx0+px0;
  float* dst = attn + (size_t)(b*PD+co)*HWn;
  dst[gy*96+gx]=a00; dst[gy*96+gx+1]=a01; dst[(gy+1)*96+gx]=a10; dst[(gy+1)*96+gx+1]=a11;
}

// ---------------- aggr as MFMA GEMM + residual + conv_x scale -> xm (B,N,C) ----------------
__global__ void __launch_bounds__(256) k_aggrm(const float* __restrict__ x, const float* __restrict__ attn,
   const float* __restrict__ ximg, const float* __restrict__ ycab, const ushort* __restrict__ Wpa,
   const float* __restrict__ aggb, const float* __restrict__ svec, float* __restrict__ xm){
  __shared__ short smem[64*200];   // As ; reused as cF (fp32 64x68) in epilogue
  short* As = smem;
  int rt = blockIdx.x, ct = blockIdx.y;
  int t = threadIdx.x;
  int w = t>>6, lane = t&63, kq = lane>>4, lr = lane&15;
  int grow0 = rt*64; int b = grow0/HWn; int n0 = grow0%HWn;
  // stage A vectorized: item = (kk, rblk): 8 consecutive rows
  for(int i=t;i<8*192;i+=256){
    int rblk=i&7, kk=i>>3;
    int r0=rblk*8;
    if(kk<Cc){
      const float* src = (kk<PD)? attn + (size_t)(b*PD+kk)*HWn + n0 + r0
                                : ximg + (size_t)(b*Cc+kk)*HWn + n0 + r0;
      float4 v0 = *(const float4*)src;
      float4 v1 = *(const float4*)(src+4);
      As[(r0+0)*200+kk]=f2bf(v0.x); As[(r0+1)*200+kk]=f2bf(v0.y);
      As[(r0+2)*200+kk]=f2bf(v0.z); As[(r0+3)*200+kk]=f2bf(v0.w);
      As[(r0+4)*200+kk]=f2bf(v1.x); As[(r0+5)*200+kk]=f2bf(v1.y);
      As[(r0+6)*200+kk]=f2bf(v1.z); As[(r0+7)*200+kk]=f2bf(v1.w);
    } else {
#pragma unroll
      for(int q=0;q<8;q++) As[(r0+q)*200+kk]=0;
    }
  }
  __syncthreads();
  f4v acc[4]={};
  int arow=(w*16+lr)*200 + kq*8;
#pragma unroll
  for(int k0=0;k0<192;k0+=32){
    s8v af = *(const s8v*)&As[arow+k0];
#pragma unroll
    for(int ts=0;ts<4;ts++){
      s8v wf = *(const s8v*)&Wpa[(size_t)(ct*64+ts*16+lr)*192 + kq*8 + k0];
      acc[ts]=__builtin_amdgcn_mfma_f32_16x16x32_bf16(af,wf,acc[ts],0,0,0);
    }
  }
  __syncthreads();
  // epilogue: cF[m][j] = acc + aggb + CONV_SCALE*svec*ycab  (stride 68, conflict-free)
  float* cF = (float*)smem;
#pragma unroll
  for(int ts=0;ts<4;ts++){
    int j = ts*16+lr;
    int jc = ct*64 + j;
    float bb=0.f, sv=0.f;
    if(jc<Cc){ bb=aggb[jc]; sv=CONV_SCALE*svec[b*Cc+jc]; }
    const float* yrow = ycab + ((jc<Cc)? (size_t)(b*Cc+jc)*HWn + n0 : 0);
#pragma unroll
    for(int reg=0;reg<4;reg++){
      int m = w*16 + kq*4 + reg;
      float v = 0.f;
      if(jc<Cc) v = acc[ts][reg] + bb + sv*yrow[m];
      cF[m*68+j] = v;
    }
  }
  __syncthreads();
  for(int i=t;i<64*64;i+=256){
    int m=i>>6, j=i&63;
    int jc=ct*64+j;
    if(jc<Cc){
      size_t o = (size_t)(grow0+m)*Cc + jc;
      xm[o] = x[o] + cF[m*68+j];
    }
  }
}

// ---------------- LN2 fused: stats + normalize + bf16 cast, K padded 180->192 ----------------
__global__ void __launch_bounds__(256) k_ln2(const float* __restrict__ xm, const float* __restrict__ g2,
    const float* __restrict__ b2, ushort* __restrict__ xn2){
  int w = (blockIdx.x*256 + threadIdx.x)>>6;
  int lane = threadIdx.x&63;
  const float* row = xm + (size_t)w*Cc;
  float s=0,sq=0;
  for(int e=lane;e<Cc;e+=64){ float v=row[e]; s+=v; sq+=v*v; }
  s=wredsum(s); sq=wredsum(sq);
  float m=s*(1.0f/180.0f); float v=sq*(1.0f/180.0f)-m*m;
  float rstd=rsqrtf(v+EPSLN);
  ushort* orow = xn2 + (size_t)w*192;
  for(int e=lane;e<192;e+=64){
    float val = (e<Cc)? (row[e]-m)*rstd*g2[e]+b2[e] : 0.f;
    orow[e] = (ushort)f2bf(val);
  }
}

// -------- fc1 MFMA, W direct from packed global, A frags in registers, ct loop --------
__global__ void __launch_bounds__(256) k_fc1(const ushort* __restrict__ xn2,
    const ushort* __restrict__ Wp, const float* __restrict__ fb, ushort* __restrict__ t1){
  __shared__ short cT[64*72];   // 9216 B epilogue transpose
  int rt = blockIdx.x;
  int t = threadIdx.x;
  int w = t>>6, lane = t&63, kq = lane>>4, lr = lane&15;
  int grow0 = rt*64;
  int bb_ = grow0/HWn, n0 = grow0%HWn;
  // A fragments: row (grow0 + w*16 + lr), cols kq*8 + 32*k6 — coalesced 64B/row
  s8v af[6];
  const ushort* arow = xn2 + (size_t)(grow0 + w*16 + lr)*192 + kq*8;
#pragma unroll
  for(int k6=0;k6<6;k6++) af[k6] = *(const s8v*)(arow + k6*32);
  for(int ct=0; ct<12; ++ct){
    f4v acc[4]={};
#pragma unroll
    for(int k6=0;k6<6;k6++){
#pragma unroll
      for(int ts=0;ts<4;ts++){
        s8v wf = *(const s8v*)&Wp[(size_t)(ct*64+ts*16+lr)*192 + kq*8 + k6*32];
        acc[ts]=__builtin_amdgcn_mfma_f32_16x16x32_bf16(af[k6],wf,acc[ts],0,0,0);
      }
    }
    __syncthreads();
#pragma unroll
    for(int ts=0;ts<4;ts++){
      int j = ts*16+lr;
      int jc = ct*64+j;
      float bb = (jc<H2)? fb[jc] : 0.f;
#pragma unroll
      for(int reg=0;reg<4;reg++){
        int m = w*16 + kq*4 + reg;
        cT[j*72+m] = f2bf(acc[ts][reg]+bb);
      }
    }
    __syncthreads();
    for(int i=t;i<4096;i+=256){
      int j=i>>6, m=i&63;
      int jc=ct*64+j;
      if(jc<H2) t1[((size_t)(bb_*H2+jc))*HWn + n0 + m] = (ushort)cT[j*72+m];
    }
  }
}

// ---------------- depthwise 3x3 on t1 + GLU -> pg (B,360,HW) bf16 ----------------
__global__ void __launch_bounds__(256) k_dwglu(const bf16* __restrict__ t1, const float* __restrict__ dww,
    const float* __restrict__ dwb, bf16* __restrict__ pg){
  __shared__ float ta[34*34];
  __shared__ float tg[34*34];
  int tile_id=blockIdx.x; int c=blockIdx.y; int b=blockIdx.z;
  int ty0=(tile_id/3)*32, tx0=(tile_id%3)*32;
  int t=threadIdx.x;
  int px0=(t%16)*2, py0=(t/16)*2;
  for(int i=t;i<34*34;i+=256){
    int ly=i/34, lx=i%34; int gy=ty0+ly-1, gx=tx0+lx-1;
    bool ok=((unsigned)gy<96u&&(unsigned)gx<96u);
    ta[i]= ok? __bfloat162float(t1[((size_t)(b*H2+c)*96+gy)*96+gx]) :0.f;
    tg[i]= ok? __bfloat162float(t1[((size_t)(b*H2+c+HID)*96+gy)*96+gx]) :0.f;
  }
  __syncthreads();
  float wp[9],wg[9];
#pragma unroll
  for(int i=0;i<9;i++){ wp[i]=dww[c*9+i]; wg[i]=dww[(c+HID)*9+i]; }
  float bp=dwb[c], bg=dwb[c+HID];
#pragma unroll
  for(int oy=0;oy<2;oy++)
#pragma unroll
    for(int ox=0;ox<2;ox++){
      float p=bp,g=bg;
#pragma unroll
      for(int ky=0;ky<3;ky++)
#pragma unroll
        for(int kx=0;kx<3;kx++){
          p+=wp[ky*3+kx]*ta[(py0+oy+ky)*34+px0+ox+kx];
          g+=wg[ky*3+kx]*tg[(py0+oy+ky)*34+px0+ox+kx];
        }
      float val = p * g * sigm(g);
      pg[((size_t)(b*HID+c)*96 + ty0+py0+oy)*96 + tx0+px0+ox] = __float2bfloat16(val);
    }
}

// ---------------- fc2 MFMA + residual -> out (B,N,C); W direct, single K=384 pass ----------------
__global__ void __launch_bounds__(256) k_fc2(const ushort* __restrict__ pg, const float* __restrict__ xm,
    const ushort* __restrict__ Wp, const float* __restrict__ fb, float* __restrict__ out){
  __shared__ short As[64*392];   // 50176 B
  int rt = blockIdx.x, ct = blockIdx.y;
  int t = threadIdx.x;
  int w = t>>6, lane = t&63, kq = lane>>4, lr = lane&15;
  int grow0 = rt*64; int b = grow0/HWn; int n0 = grow0%HWn;
  // stage A (transpose) vectorized: item = (kc, rblk), 8 consecutive rows via s8v
  for(int i=t;i<8*HID;i+=256){
    int rblk=i&7, kc=i>>3;
    int r0=rblk*8;
    s8v v = *(const s8v*)&pg[((size_t)(b*HID+kc))*HWn + n0 + r0];
#pragma unroll
    for(int q=0;q<8;q++) As[(r0+q)*392 + kc] = v[q];
  }
  for(int i=t;i<64*24;i+=256){
    int r=i/24, kk=i%24;
    As[r*392 + HID + kk] = 0;
  }
  __syncthreads();
  f4v acc[4]={};
  int arow=(w*16+lr)*392 + kq*8;
#pragma unroll
  for(int k0=0;k0<384;k0+=32){
    s8v af = *(const s8v*)&As[arow+k0];
#pragma unroll
    for(int ts=0;ts<4;ts++){
      s8v wf = *(const s8v*)&Wp[(size_t)(ct*64+ts*16+lr)*384 + kq*8 + k0];
      acc[ts]=__builtin_amdgcn_mfma_f32_16x16x32_bf16(af,wf,acc[ts],0,0,0);
    }
  }
#pragma unroll
  for(int ts=0;ts<4;ts++){
    int jc = ct*64 + ts*16 + lr;
    if(jc>=Cc) continue;
    float bb = fb[jc];
#pragma unroll
    for(int reg=0;reg<4;reg++){
      int m = w*16 + kq*4 + reg;
      size_t o = (size_t)(grow0+m)*Cc + jc;
      out[o] = xm[o] + acc[ts][reg] + bb;
    }
  }
}

extern "C" void kernel_launch(void* const* d_in, const int* in_sizes, int n_in,
                              void* d_out, int out_size, void* d_ws, size_t ws_size,
                              hipStream_t stream){
  (void)in_sizes; (void)n_in; (void)out_size; (void)ws_size;
  const float* x     = (const float*)d_in[0];
  const float* ln1_g = (const float*)d_in[3];
  const float* ln1_b = (const float*)d_in[4];
  const float* band_w= (const float*)d_in[5];
  const float* band_b= (const float*)d_in[6];
  const float* gate_w= (const float*)d_in[7];
  const float* gate_b= (const float*)d_in[8];
  const float* cab_w1= (const float*)d_in[9];
  const float* cab_b1= (const float*)d_in[10];
  const float* cab_w2= (const float*)d_in[11];
  const float* cab_b2= (const float*)d_in[12];
  const float* eca_w = (const float*)d_in[13];
  const float* plkw  = (const float*)d_in[14];
  const float* dwc_w1= (const float*)d_in[15];
  const float* dwc_b1= (const float*)d_in[16];
  const float* dwc_w2= (const float*)d_in[17];
  const float* dwc_b2= (const float*)d_in[18];
  const float* aggr_w= (const float*)d_in[19];
  const float* aggr_b= (const float*)d_in[20];
  const float* ln2_g = (const float*)d_in[21];
  const float* ln2_b = (const float*)d_in[22];
  const float* fc1_w = (const float*)d_in[23];
  const float* fc1_b = (const float*)d_in[24];
  const float* dw_w  = (const float*)d_in[25];
  const float* dw_b  = (const float*)d_in[26];
  const float* fc2_w = (const float*)d_in[27];
  const float* fc2_b = (const float*)d_in[28];

  float* ws = (float*)d_ws;
  // persistent region
  float* xm   = ws;                      // 13,271,040
  float* m1   = ws + 13271040;           // 1,440
  float* gates= ws + 13272480;           // 32
  float* dkb  = ws + 13272512;           // 1,152
  float* biasb= ws + 13273664;           // 1,440
  float* gapb = ws + 13275104;           // 1,440
  float* svec = ws + 13276544;           // 1,440 -> 13,277,984
  ushort* Wg1 = (ushort*)(ws + 13278000);// 110,592 shorts = 55,296 fl -> 13,333,296
  ushort* Wg2 = (ushort*)(ws + 13333296);// 110,592 shorts -> 13,388,592
  ushort* Wp1 = (ushort*)(ws + 13388592);// 147,456 shorts = 73,728 fl -> 13,462,320
  ushort* Wp2 = (ushort*)(ws + 13462320);// 73,728 shorts = 36,864 fl -> 13,499,184
  ushort* Wpa = (ushort*)(ws + 13499184);// 36,864 shorts = 18,432 fl -> 13,517,616
  float* big  = ws + 13517696;
  // phase 1 inside big:
  float* ximg = big;                     // 13,271,040
  float* spec = big + 13271040;          // 13,547,520 (xfft in first 9216 of each 9408 plane)
  ushort* mid = (ushort*)(big + 26818560); // 4,423,680 bf16 = 2,211,840 float slots
  float* attn = big + 29030400;          // 1,179,648 -> phase-1 top = 30,210,048
  float* ycab = spec;                    // reuse (stride 9216), spec dead after conv1
  // phase 2 aliases big:
  ushort* t1  = (ushort*)big;                    // 26,542,080 float slots
  float*  reg2= big + 26542080;
  ushort* xn2 = (ushort*)reg2;                   // 7,077,888 float slots (ln2->fc1)
  ushort* pgb = (ushort*)reg2;                   // 13,271,040 float slots (dwglu->fc2)
  // total = 13,517,696 + 39,813,120 = 53,330,816 floats (~213 MB)

  k_packw<<<576,256,0,stream>>>(cab_w1, cab_w2, fc1_w, fc2_w, aggr_w, Wg1, Wg2, Wp1, Wp2, Wpa);
  k_ln1<<<2304,256,0,stream>>>(x, ln1_g, ln1_b, ximg);
  k_plane_mean<<<1440,256,0,stream>>>(ximg, m1);
  k_small<<<1,64,0,stream>>>(m1, gate_w, gate_b, dwc_w1, dwc_b1, dwc_w2, dwc_b2, band_b, gates, dkb, biasb);
  k_fwd_x<<<1440,256,0,stream>>>(ximg, spec);
  k_fwd_y<<<1440,256,0,stream>>>(spec);
  k_bandmix<<<dim3(Bb,96,2),256,0,stream>>>(spec, band_w, gates);
  k_inv_y<<<1440,256,0,stream>>>(spec);
  k_inv_x<<<1440,256,0,stream>>>(spec, ximg, biasb);
  k_cab<float, Cc, 192, 6, true,  true ><<<dim3(48,1,Bb),256,0,stream>>>(spec, Wg1, cab_b1, (void*)mid, CRr, SPL);
  k_cab<ushort, CRr, 64, 2, false, false><<<dim3(48,3,Bb),256,0,stream>>>(mid, Wg2, cab_b2, (void*)ycab, Cc, HWn);
  k_plane_mean<<<1440,256,0,stream>>>(ycab, gapb);
  k_eca<<<6,256,0,stream>>>(gapb, eca_w, svec);
  k_plk<<<dim3(9,PD,Bb),256,0,stream>>>(ximg, plkw, dkb, attn);
  k_aggrm<<<dim3(1152,3),256,0,stream>>>(x, attn, ximg, ycab, Wpa, aggr_b, svec, xm);
  k_ln2<<<18432,256,0,stream>>>(xm, ln2_g, ln2_b, xn2);
  k_fc1<<<1152,256,0,stream>>>(xn2, Wp1, fc1_b, t1);
  k_dwglu<<<dim3(9,HID,Bb),256,0,stream>>>((const bf16*)t1, dw_w, dw_b, (bf16*)pgb);
  k_fc2<<<dim3(1152,3),256,0,stream>>>(pgb, xm, Wp2, fc2_b, (float*)d_out);
}

// Round 7
// 1552.119 us; speedup vs baseline: 2.3403x; 1.4324x over previous
//
#include <hip/hip_runtime.h>
#include <hip/hip_bf16.h>
#include <math.h>
#include <type_traits>

#define Bb 8
#define Cc 180
#define HWn 9216
#define PD 16
#define CRr 60
#define HID 360
#define H2 720
#define NF 49
#define SPL 9408   /* spectral plane stride in floats: 96*49*2 */
#define CONV_SCALE 0.01f
#define FFT_RES 0.15f
#define EPSLN 1e-5f
#define TWOPI_96 0.06544984694978735f

typedef __hip_bfloat16 bf16;
typedef unsigned short ushort;
typedef __attribute__((ext_vector_type(8))) short s8v;   // 8 bf16 (4 VGPRs) MFMA A/B frag
typedef __attribute__((ext_vector_type(4))) float f4v;   // MFMA C/D frag

__device__ __forceinline__ float geluf(float x){ return 0.5f*x*(1.0f+erff(x*0.7071067811865476f)); }
__device__ __forceinline__ float sigm(float x){ return 1.0f/(1.0f+expf(-x)); }
__device__ __forceinline__ short f2bf(float f){
  unsigned u = __float_as_uint(f);
  u += 0x7fff + ((u>>16)&1);
  return (short)(u>>16);
}
__device__ __forceinline__ float wredsum(float v){
#pragma unroll
  for(int m=1;m<64;m<<=1) v += __shfl_xor(v,m,64);
  return v;
}

// ---------------- LN1 + transpose to (B,C,H,W) ----------------
__global__ void __launch_bounds__(256) k_ln1(const float* __restrict__ x, const float* __restrict__ g,
                      const float* __restrict__ be, float* __restrict__ ximg){
  __shared__ float sb[32*Cc];
  int b = blockIdx.x / 288;
  int n0 = (blockIdx.x % 288) * 32;
  int t = threadIdx.x;
  const float* src = x + (size_t)(b*HWn + n0)*Cc;
  for(int i=t;i<32*Cc;i+=256) sb[i]=src[i];
  __syncthreads();
  int w = t>>6, lane = t&63;
  for(int pi=0; pi<8; ++pi){
    int p = w*8+pi;
    float s=0.f, sq=0.f;
    for(int e=lane;e<Cc;e+=64){ float v=sb[p*Cc+e]; s+=v; sq+=v*v; }
    s = wredsum(s); sq = wredsum(sq);
    float mean = s*(1.0f/180.0f);
    float var = sq*(1.0f/180.0f) - mean*mean;
    float rstd = rsqrtf(var + EPSLN);
    for(int e=lane;e<Cc;e+=64){ float v=sb[p*Cc+e]; sb[p*Cc+e] = (v-mean)*rstd*g[e]+be[e]; }
  }
  __syncthreads();
  for(int i=t;i<32*Cc;i+=256){
    int c = i/32, p = i%32;
    ximg[(size_t)(b*Cc+c)*HWn + n0 + p] = sb[p*Cc+c];
  }
}

// ---------------- plane mean (9216 -> 1) ----------------
__global__ void __launch_bounds__(256) k_plane_mean(const float* __restrict__ in, float* __restrict__ out){
  __shared__ float red[4];
  int pl = blockIdx.x; int t = threadIdx.x;
  const float* p = in + (size_t)pl*HWn;
  float s=0.f;
  for(int i=t;i<HWn;i+=256) s+=p[i];
  s = wredsum(s);
  if((t&63)==0) red[t>>6]=s;
  __syncthreads();
  if(t==0) out[pl] = (red[0]+red[1]+red[2]+red[3]) * (1.0f/9216.0f);
}

// ---------------- small: gates, hdn->dk, fft bias ----------------
__global__ void k_small(const float* __restrict__ m1, const float* __restrict__ gate_w,
   const float* __restrict__ gate_b, const float* __restrict__ dwc_w1, const float* __restrict__ dwc_b1,
   const float* __restrict__ dwc_w2, const float* __restrict__ dwc_b2, const float* __restrict__ band_b,
   float* __restrict__ gates, float* __restrict__ dkb, float* __restrict__ biasb){
  int b = threadIdx.x;
  if(b>=Bb) return;
  const float* m = m1 + b*Cc;
  float gv[3];
  for(int k=0;k<3;k++){ float a=gate_b[k]; for(int c=0;c<Cc;c++) a+=m[c]*gate_w[k*Cc+c]; gv[k]=sigm(a);}
  float e0=expf(gv[0]), e1=expf(gv[1]), e2=expf(gv[2]); float inv=1.0f/(e0+e1+e2);
  float g0=e0*inv,g1=e1*inv,g2=e2*inv;
  gates[b*3+0]=g0; gates[b*3+1]=g1; gates[b*3+2]=g2;
  float hd[8];
  for(int j=0;j<8;j++){ float a=dwc_b1[j]; for(int c=0;c<PD;c++) a+=m[c]*dwc_w1[j*PD+c]; hd[j]=geluf(a);}
  for(int i=0;i<144;i++){ float a=dwc_b2[i]; for(int j=0;j<8;j++) a+=hd[j]*dwc_w2[i*8+j]; dkb[b*144+i]=a; }
  for(int d=0;d<Cc;d++) biasb[b*Cc+d] = g0*band_b[0*Cc+d]+g1*band_b[1*Cc+d]+g2*band_b[2*Cc+d];
}

// ------- pack weights to bf16 + DFT twiddle matrices -------
__global__ void __launch_bounds__(256) k_packw(const float* __restrict__ w1, const float* __restrict__ w2,
    const float* __restrict__ fw1, const float* __restrict__ fw2, const float* __restrict__ aw,
    ushort* __restrict__ Wg1, ushort* __restrict__ Wg2, ushort* __restrict__ Wp1,
    ushort* __restrict__ Wp2, ushort* __restrict__ Wpa,
    ushort* __restrict__ Bfx, ushort* __restrict__ Tm, ushort* __restrict__ Bix){
  int t = blockIdx.x*256 + threadIdx.x;
  if(t < 64*9*192){
    int co = t/(9*192); int rem = t%(9*192); int tap = rem/192; int ci = rem%192;
    float v = (co<CRr && ci<Cc) ? w1[((size_t)(co*Cc+ci))*9 + tap] : 0.f;
    Wg1[t] = (ushort)f2bf(v);
  }
  if(t < 192*9*64){
    int co = t/(9*64); int rem = t%(9*64); int tap = rem/64; int ci = rem%64;
    float v = (co<Cc && ci<CRr) ? w2[((size_t)(co*CRr+ci))*9 + tap] : 0.f;
    Wg2[t] = (ushort)f2bf(v);
  }
  if(t < 768*192){
    int j=t/192, k=t%192;
    Wp1[t] = (ushort)f2bf((j<H2 && k<Cc)? fw1[(size_t)j*Cc+k] : 0.f);
  }
  if(t < 192*384){
    int j=t/384, k=t%384;
    Wp2[t] = (ushort)f2bf((j<Cc && k<HID)? fw2[(size_t)j*HID+k] : 0.f);
  }
  if(t < 192*192){
    int j=t/192, k=t%192;
    Wpa[t] = (ushort)f2bf((j<Cc && k<Cc)? aw[(size_t)j*Cc+k] : 0.f);
  }
  // Bfx[112 n][96 k] : fwd-x twiddle (ortho 1/96 folded)
  if(t < 112*96){
    int n=t/96, k=t%96;
    float v=0.f;
    if(n<98){
      int kx=n>>1; int m=(k*kx)%96; float th=(float)m*TWOPI_96;
      v = ((n&1)? -sinf(th) : cosf(th)) * (1.0f/96.0f);
    }
    Bfx[t] = (ushort)f2bf(v);
  }
  // Tm[96 r][192 k] : y-transform twiddle (shared fwd/inv)
  if(t < 96*192){
    int r=t/192, k=t%192;
    int c=k>>1; int m=(r*c)%96; float th=(float)m*TWOPI_96;
    float v = (k&1)? sinf(th) : cosf(th);
    Tm[t] = (ushort)f2bf(v);
  }
  // Bix[96 n][128 k] : inv-x twiddle (wgt and 1/96 folded)
  if(t < 96*128){
    int n=t/128, k=t%128;
    float v=0.f;
    if(k<98){
      int kx=k>>1; float wgt=(kx==0||kx==48)?1.0f:2.0f;
      int m=(n*kx)%96; float th=(float)m*TWOPI_96;
      v = ((k&1)? -wgt*sinf(th) : wgt*cosf(th)) * (1.0f/96.0f);
    }
    Bix[t] = (ushort)f2bf(v);
  }
}

// ---------------- fused forward 2D rDFT (per plane), MFMA ----------------
__global__ void __launch_bounds__(256) k_fft_fwd(const float* __restrict__ ximg,
    const ushort* __restrict__ Bfx, const ushort* __restrict__ Tm, float* __restrict__ S){
  __shared__ __align__(16) short Asi[96*104];
  __shared__ __align__(16) short Bv[112*200];
  int bc = blockIdx.x; int t = threadIdx.x;
  int w=t>>6, lane=t&63, kq=lane>>4, lr=lane&15;
  const float* src = ximg + (size_t)bc*HWn;
  for(int i=t;i<1152;i+=256){
    int y=i/12, seg=i%12;
    float4 v0 = *(const float4*)(src + y*96 + seg*8);
    float4 v1 = *(const float4*)(src + y*96 + seg*8 + 4);
    s8v pk;
    pk[0]=f2bf(v0.x); pk[1]=f2bf(v0.y); pk[2]=f2bf(v0.z); pk[3]=f2bf(v0.w);
    pk[4]=f2bf(v1.x); pk[5]=f2bf(v1.y); pk[6]=f2bf(v1.z); pk[7]=f2bf(v1.w);
    *(s8v*)&Asi[y*104+seg*8] = pk;
  }
  __syncthreads();
  // stage1: V[y][n] = img @ Bfx^T ; write (V, -i*V) into Bv[n][2y,2y+1]
  for(int tile=w; tile<42; tile+=4){
    int mt=tile/7, nt=tile%7;
    f4v acc={};
#pragma unroll
    for(int ks=0;ks<3;ks++){
      s8v af = *(const s8v*)&Asi[(mt*16+lr)*104 + kq*8 + ks*32];
      s8v bf = *(const s8v*)&Bfx[(size_t)(nt*16+lr)*96 + kq*8 + ks*32];
      acc = __builtin_amdgcn_mfma_f32_16x16x32_bf16(af,bf,acc,0,0,0);
    }
    int n = nt*16+lr;
    float sgn = (n&1)? -1.f : 1.f;
#pragma unroll
    for(int reg=0;reg<4;reg++){
      int y = mt*16+kq*4+reg;
      float v = acc[reg];
      float p = __shfl_xor(v,1);
      unsigned pack = ((unsigned)(ushort)f2bf(sgn*p)<<16) | (ushort)(unsigned short)f2bf(v);
      *(unsigned*)&Bv[n*200 + 2*y] = pack;
    }
  }
  __syncthreads();
  // stage2: X[ky][n] = Tm @ Bv^T -> global fp32 spec plane
  float* dst = S + (size_t)bc*SPL;
  for(int tile=w; tile<42; tile+=4){
    int mt=tile/7, nt=tile%7;
    f4v acc={};
#pragma unroll
    for(int ks=0;ks<6;ks++){
      s8v af = *(const s8v*)&Tm[(size_t)(mt*16+lr)*192 + kq*8 + ks*32];
      s8v bf = *(const s8v*)&Bv[(nt*16+lr)*200 + kq*8 + ks*32];
      acc = __builtin_amdgcn_mfma_f32_16x16x32_bf16(af,bf,acc,0,0,0);
    }
    int n = nt*16+lr;
    if(n<98){
#pragma unroll
      for(int reg=0;reg<4;reg++){
        int ky = mt*16+kq*4+reg;
        dst[ky*98 + n] = acc[reg];
      }
    }
  }
}

// ---------------- fused inverse 2D rDFT + combine (per plane), MFMA, in-place ----------------
__global__ void __launch_bounds__(256) k_fft_inv(float* __restrict__ S, const float* __restrict__ ximg,
    const float* __restrict__ biasb, const ushort* __restrict__ Tm, const ushort* __restrict__ Bix){
  __shared__ __align__(16) short Bv[112*200];
  __shared__ __align__(16) short T2s[96*136];
  int bd = blockIdx.x; int t=threadIdx.x;
  int w=t>>6, lane=t&63, kq=lane>>4, lr=lane&15;
  int b = bd/Cc, d = bd%Cc;
  float* pl = S + (size_t)bd*SPL;
  // zero Bv rows n=98..111 and T2s cols 112..135
  for(int i=t;i<1400;i+=256) ((unsigned*)&Bv[98*200])[i] = 0u;
  for(int i=t;i<1152;i+=256){ int y=i/12, c=i%12; *(unsigned*)&T2s[y*136+112+c*2] = 0u; }
  // build Bv from Yhat with +i twist (partner via shfl)
  for(int i=t;i<9408;i+=256){
    float v = pl[i];
    float p = __shfl_xor(v,1);
    int ky = i/98, n = i%98;
    float tw = (n&1)? p : -p;
    unsigned pack = ((unsigned)(ushort)f2bf(tw)<<16) | (ushort)(unsigned short)f2bf(v);
    *(unsigned*)&Bv[n*200 + 2*ky] = pack;
  }
  __syncthreads();
  // stage1: T2[y][n] = Tm @ Bv^T -> LDS
  for(int tile=w; tile<42; tile+=4){
    int mt=tile/7, nt=tile%7;
    f4v acc={};
#pragma unroll
    for(int ks=0;ks<6;ks++){
      s8v af = *(const s8v*)&Tm[(size_t)(mt*16+lr)*192 + kq*8 + ks*32];
      s8v bf = *(const s8v*)&Bv[(nt*16+lr)*200 + kq*8 + ks*32];
      acc = __builtin_amdgcn_mfma_f32_16x16x32_bf16(af,bf,acc,0,0,0);
    }
    int n = nt*16+lr;
#pragma unroll
    for(int reg=0;reg<4;reg++){
      int y = mt*16+kq*4+reg;
      T2s[y*136 + n] = f2bf(acc[reg]);   // n<112; cols 98..111 are zeros (Bv rows zeroed)
    }
  }
  __syncthreads();
  // stage2: out[y][xx] = T2 @ Bix^T ; combine with ximg + bias, in-place
  float bias = biasb[b*Cc+d];
  const float* xs = ximg + (size_t)bd*HWn;
  for(int tile=w; tile<36; tile+=4){
    int mt=tile/6, nt=tile%6;
    f4v acc={};
#pragma unroll
    for(int ks=0;ks<4;ks++){
      s8v af = *(const s8v*)&T2s[(mt*16+lr)*136 + kq*8 + ks*32];
      s8v bf = *(const s8v*)&Bix[(size_t)(nt*16+lr)*128 + kq*8 + ks*32];
      acc = __builtin_amdgcn_mfma_f32_16x16x32_bf16(af,bf,acc,0,0,0);
    }
    int xx = nt*16+lr;
#pragma unroll
    for(int reg=0;reg<4;reg++){
      int y = mt*16+kq*4+reg;
      int o = y*96+xx;
      pl[o] = xs[o] + FFT_RES*(acc[reg] + bias);
    }
  }
}

// ---------------- per-frequency band channel mix: Y = g_bk * W_k @ X, IN-PLACE ----------------
__global__ void __launch_bounds__(256) k_bandmix(float* __restrict__ S, const float* __restrict__ band_w,
                          const float* __restrict__ gates){
  __shared__ float xs[Cc*50];
  int b = blockIdx.x; int ky = blockIdx.y; int half = blockIdx.z;
  int kx0 = half*25; int nkx = half? 24:25;
  int t=threadIdx.x;
  for(int i=t;i<Cc*nkx*2;i+=256){
    int c = i/(nkx*2); int r = i%(nkx*2);
    xs[c*50+r] = S[ (size_t)(b*Cc+c)*SPL + ky*(NF*2) + kx0*2 + r ];
  }
  __syncthreads();
  float yy = -1.0f + 2.0f*(float)ky/95.0f;
  for(int o=t;o<Cc*nkx;o+=256){
    int d = o/nkx, kxl = o%nkx; int kx = kx0+kxl;
    float xxf = (float)kx/48.0f;
    float rr = sqrtf(yy*yy+xxf*xxf);
    int k = (rr<=0.25f)?0:((rr<=0.6f)?1:2);
    float g = gates[b*3+k];
    const float* wr = band_w + ((size_t)k*Cc + d)*Cc;
    float re=0.f, im=0.f;
    for(int c=0;c<Cc;++c){
      float w=wr[c];
      re += w*xs[c*50 + kxl*2];
      im += w*xs[c*50 + kxl*2 + 1];
    }
    size_t off = (size_t)(b*Cc+d)*SPL + ky*(NF*2) + kx*2;
    S[off]=g*re; S[off+1]=g*im;
  }
}

// ---------------- CAB 3x3 conv as implicit-GEMM MFMA ----------------
template<typename TIN, int CIN, int KPAD, int NCHUNK, bool ACT, bool OUTBF>
__global__ void __launch_bounds__(256) k_cab(const TIN* __restrict__ xin, const ushort* __restrict__ Wg,
    const float* __restrict__ bias, void* __restrict__ outv, int COUT, int istride){
  __shared__ short As[4*98*36];   // 28224 B; also reused for epilogue transpose
  int y0 = blockIdx.x*2;
  int ct = blockIdx.y;
  int b  = blockIdx.z;
  int t = threadIdx.x;
  int w = t>>6, lane = t&63, kq = lane>>4, lr = lane&15;
  f4v acc[3][4] = {};
  for(int ch=0; ch<NCHUNK; ++ch){
    int ci0 = ch*32;
    __syncthreads();
    for(int i=t;i<4*98*32;i+=256){
      int ci = i/392; int rem = i%392; int row = rem/98; int pxh = rem%98;
      int gy = y0 - 1 + row; int px = pxh - 1;
      int cig = ci0 + ci;
      short sv = 0;
      if((unsigned)gy<96u && (unsigned)px<96u && cig<CIN){
        if constexpr (std::is_same<TIN,float>::value)
          sv = f2bf(xin[(size_t)(b*CIN+cig)*istride + gy*96 + px]);
        else
          sv = (short)xin[(size_t)(b*CIN+cig)*istride + gy*96 + px];
      }
      As[(row*98+pxh)*36 + ci] = sv;
    }
    __syncthreads();
#pragma unroll
    for(int tap=0; tap<9; ++tap){
      int ky = tap/3, kx = tap%3;
      s8v bfr[4];
#pragma unroll
      for(int ts=0;ts<4;ts++)
        bfr[ts] = *(const s8v*)&Wg[((size_t)(ct*64 + ts*16 + lr)*9 + tap)*KPAD + ci0 + kq*8];
#pragma unroll
      for(int s=0;s<3;s++){
        int mt = w + 4*s;
        int orow = mt/6, px = (mt%6)*16 + lr;
        s8v af = *(const s8v*)&As[((orow+ky)*98 + px + kx)*36 + kq*8];
#pragma unroll
        for(int ts=0;ts<4;ts++)
          acc[s][ts] = __builtin_amdgcn_mfma_f32_16x16x32_bf16(af, bfr[ts], acc[s][ts], 0,0,0);
      }
    }
  }
  // epilogue
  if(OUTBF){
    __syncthreads();
    short* cT = As;   // [64 co][200] bf16
#pragma unroll
    for(int ts=0;ts<4;ts++){
      int cog = ct*64 + ts*16 + lr;
      float bb = (cog<COUT)? bias[cog] : 0.f;
#pragma unroll
      for(int s=0;s<3;s++){
#pragma unroll
        for(int reg=0;reg<4;reg++){
          int px = (w+4*s)*16 + kq*4 + reg;
          float v = acc[s][ts][reg] + bb;
          if(ACT) v = geluf(v);
          cT[(ts*16+lr)*200 + px] = f2bf(v);
        }
      }
    }
    __syncthreads();
    ushort* out = (ushort*)outv;
    for(int i=t;i<64*192;i+=256){
      int co=i/192, px=i%192;
      int cog = ct*64+co;
      if(cog<COUT) out[(size_t)(b*COUT+cog)*HWn + y0*96 + px] = (ushort)cT[co*200+px];
    }
  } else {
    float* cF = (float*)As;  // [32 co][200] fp32 per half
    float* out = (float*)outv;
    for(int h=0;h<2;h++){
      __syncthreads();
#pragma unroll
      for(int tt=0;tt<2;tt++){
        int ts = 2*h+tt;
        int cog = ct*64 + ts*16 + lr;
        float bb = (cog<COUT)? bias[cog] : 0.f;
#pragma unroll
        for(int s=0;s<3;s++){
#pragma unroll
          for(int reg=0;reg<4;reg++){
            int px = (w+4*s)*16 + kq*4 + reg;
            cF[(tt*16+lr)*200 + px] = acc[s][ts][reg] + bb;
          }
        }
      }
      __syncthreads();
      for(int i=t;i<32*192;i+=256){
        int co=i/192, px=i%192;
        int cog = ct*64 + h*32 + co;
        if(cog<COUT) out[(size_t)(b*COUT+cog)*HWn + y0*96 + px] = cF[co*200+px];
      }
    }
  }
}

// ---------------- ECA ----------------
__global__ void k_eca(const float* __restrict__ gap, const float* __restrict__ ew, float* __restrict__ s){
  int i = blockIdx.x*blockDim.x + threadIdx.x;
  if(i>=Bb*Cc) return;
  int b=i/Cc, c=i%Cc;
  float z=0.f;
  for(int j=0;j<5;j++){ int cc=c-2+j; if(cc>=0&&cc<Cc) z+=gap[b*Cc+cc]*ew[j]; }
  s[i]=sigm(z);
}

// ---------------- plk 13x13 conv (16->16) + fused dynamic depthwise 3x3 ----------------
__global__ void __launch_bounds__(256) k_plk(const float* __restrict__ ximg, const float* __restrict__ plk,
    const float* __restrict__ dkb, float* __restrict__ attn){
  __shared__ float tile[44*44];
  __shared__ float wl[169];
  __shared__ float dk9[9];
  int tile_id=blockIdx.x; int co=blockIdx.y; int b=blockIdx.z;
  int ty0=(tile_id/3)*32, tx0=(tile_id%3)*32;
  int t=threadIdx.x;
  int px0=(t%16)*2, py0=(t/16)*2;
  if(t<9) dk9[t]=dkb[b*144+co*9+t];
  float a00=0,a01=0,a10=0,a11=0;
  for(int ci=0;ci<PD;++ci){
    __syncthreads();
    for(int i=t;i<44*44;i+=256){
      int ly=i/44, lx=i%44;
      int gy=ty0+ly-6, gx=tx0+lx-6;
      float v=0.f;
      if((unsigned)gy<96u&&(unsigned)gx<96u) v=ximg[((size_t)(b*Cc+ci)*96+gy)*96+gx];
      tile[i]=v;
    }
    for(int i=t;i<169;i+=256) wl[i]=plk[((size_t)(co*PD+ci)*169)+i];
    __syncthreads();
    for(int rr2=0; rr2<14; ++rr2){
      float rowv[14];
      const float* trow = tile + (py0+rr2)*44 + px0;
#pragma unroll
      for(int i=0;i<14;i++) rowv[i]=trow[i];
      if(rr2<13){
        const float* wr = wl + rr2*13;
#pragma unroll
        for(int kx=0;kx<13;kx++){ float w=wr[kx]; a00+=w*rowv[kx]; a01+=w*rowv[kx+1]; }
      }
      if(rr2>=1){
        const float* wr = wl + (rr2-1)*13;
#pragma unroll
        for(int kx=0;kx<13;kx++){ float w=wr[kx]; a10+=w*rowv[kx]; a11+=w*rowv[kx+1]; }
      }
    }
    if(ci==co){
#pragma unroll
      for(int ky=0;ky<3;ky++)
#pragma unroll
        for(int kx=0;kx<3;kx++){
          float w=dk9[ky*3+kx];
          a00+=w*tile[(py0+5+ky)*44+px0+5+kx];
          a01+=w*tile[(py0+5+ky)*44+px0+6+kx];
          a10+=w*tile[(py0+6+ky)*44+px0+5+kx];
          a11+=w*tile[(py0+6+ky)*44+px0+6+kx];
        }
    }
  }
  int gy=ty0+py0, gx=tx0+px0;
  float* dst = attn + (size_t)(b*PD+co)*HWn;
  dst[gy*96+gx]=a00; dst[gy*96+gx+1]=a01; dst[(gy+1)*96+gx]=a10; dst[(gy+1)*96+gx+1]=a11;
}

// ---------------- aggr as MFMA GEMM + residual + conv_x scale -> xm (B,N,C) ----------------
__global__ void __launch_bounds__(256) k_aggrm(const float* __restrict__ x, const float* __restrict__ attn,
   const float* __restrict__ ximg, const float* __restrict__ ycab, const ushort* __restrict__ Wpa,
   const float* __restrict__ aggb, const float* __restrict__ svec, float* __restrict__ xm){
  __shared__ short smem[64*200];   // As ; reused as cF (fp32 64x68) in epilogue
  short* As = smem;
  int rt = blockIdx.x, ct = blockIdx.y;
  int t = threadIdx.x;
  int w = t>>6, lane = t&63, kq = lane>>4, lr = lane&15;
  int grow0 = rt*64; int b = grow0/HWn; int n0 = grow0%HWn;
  for(int i=t;i<8*192;i+=256){
    int rblk=i&7, kk=i>>3;
    int r0=rblk*8;
    if(kk<Cc){
      const float* src = (kk<PD)? attn + (size_t)(b*PD+kk)*HWn + n0 + r0
                                : ximg + (size_t)(b*Cc+kk)*HWn + n0 + r0;
      float4 v0 = *(const float4*)src;
      float4 v1 = *(const float4*)(src+4);
      As[(r0+0)*200+kk]=f2bf(v0.x); As[(r0+1)*200+kk]=f2bf(v0.y);
      As[(r0+2)*200+kk]=f2bf(v0.z); As[(r0+3)*200+kk]=f2bf(v0.w);
      As[(r0+4)*200+kk]=f2bf(v1.x); As[(r0+5)*200+kk]=f2bf(v1.y);
      As[(r0+6)*200+kk]=f2bf(v1.z); As[(r0+7)*200+kk]=f2bf(v1.w);
    } else {
#pragma unroll
      for(int q=0;q<8;q++) As[(r0+q)*200+kk]=0;
    }
  }
  __syncthreads();
  f4v acc[4]={};
  int arow=(w*16+lr)*200 + kq*8;
#pragma unroll
  for(int k0=0;k0<192;k0+=32){
    s8v af = *(const s8v*)&As[arow+k0];
#pragma unroll
    for(int ts=0;ts<4;ts++){
      s8v wf = *(const s8v*)&Wpa[(size_t)(ct*64+ts*16+lr)*192 + kq*8 + k0];
      acc[ts]=__builtin_amdgcn_mfma_f32_16x16x32_bf16(af,wf,acc[ts],0,0,0);
    }
  }
  __syncthreads();
  float* cF = (float*)smem;
#pragma unroll
  for(int ts=0;ts<4;ts++){
    int j = ts*16+lr;
    int jc = ct*64 + j;
    float bb=0.f, sv=0.f;
    if(jc<Cc){ bb=aggb[jc]; sv=CONV_SCALE*svec[b*Cc+jc]; }
    const float* yrow = ycab + ((jc<Cc)? (size_t)(b*Cc+jc)*HWn + n0 : 0);
#pragma unroll
    for(int reg=0;reg<4;reg++){
      int m = w*16 + kq*4 + reg;
      float v = 0.f;
      if(jc<Cc) v = acc[ts][reg] + bb + sv*yrow[m];
      cF[m*68+j] = v;
    }
  }
  __syncthreads();
  for(int i=t;i<64*64;i+=256){
    int m=i>>6, j=i&63;
    int jc=ct*64+j;
    if(jc<Cc){
      size_t o = (size_t)(grow0+m)*Cc + jc;
      xm[o] = x[o] + cF[m*68+j];
    }
  }
}

// ---------------- LN2 fused: stats + normalize + bf16 cast, K padded 180->192 ----------------
__global__ void __launch_bounds__(256) k_ln2(const float* __restrict__ xm, const float* __restrict__ g2,
    const float* __restrict__ b2, ushort* __restrict__ xn2){
  int w = (blockIdx.x*256 + threadIdx.x)>>6;
  int lane = threadIdx.x&63;
  const float* row = xm + (size_t)w*Cc;
  float s=0,sq=0;
  for(int e=lane;e<Cc;e+=64){ float v=row[e]; s+=v; sq+=v*v; }
  s=wredsum(s); sq=wredsum(sq);
  float m=s*(1.0f/180.0f); float v=sq*(1.0f/180.0f)-m*m;
  float rstd=rsqrtf(v+EPSLN);
  ushort* orow = xn2 + (size_t)w*192;
  for(int e=lane;e<192;e+=64){
    float val = (e<Cc)? (row[e]-m)*rstd*g2[e]+b2[e] : 0.f;
    orow[e] = (ushort)f2bf(val);
  }
}

// -------- fc1 MFMA, W direct from packed global, A frags in registers, ct loop --------
__global__ void __launch_bounds__(256) k_fc1(const ushort* __restrict__ xn2,
    const ushort* __restrict__ Wp, const float* __restrict__ fb, ushort* __restrict__ t1){
  __shared__ short cT[64*72];   // 9216 B epilogue transpose
  int rt = blockIdx.x;
  int t = threadIdx.x;
  int w = t>>6, lane = t&63, kq = lane>>4, lr = lane&15;
  int grow0 = rt*64;
  int bb_ = grow0/HWn, n0 = grow0%HWn;
  s8v af[6];
  const ushort* arow = xn2 + (size_t)(grow0 + w*16 + lr)*192 + kq*8;
#pragma unroll
  for(int k6=0;k6<6;k6++) af[k6] = *(const s8v*)(arow + k6*32);
  for(int ct=0; ct<12; ++ct){
    f4v acc[4]={};
#pragma unroll
    for(int k6=0;k6<6;k6++){
#pragma unroll
      for(int ts=0;ts<4;ts++){
        s8v wf = *(const s8v*)&Wp[(size_t)(ct*64+ts*16+lr)*192 + kq*8 + k6*32];
        acc[ts]=__builtin_amdgcn_mfma_f32_16x16x32_bf16(af[k6],wf,acc[ts],0,0,0);
      }
    }
    __syncthreads();
#pragma unroll
    for(int ts=0;ts<4;ts++){
      int j = ts*16+lr;
      int jc = ct*64+j;
      float bb = (jc<H2)? fb[jc] : 0.f;
#pragma unroll
      for(int reg=0;reg<4;reg++){
        int m = w*16 + kq*4 + reg;
        cT[j*72+m] = f2bf(acc[ts][reg]+bb);
      }
    }
    __syncthreads();
    for(int i=t;i<4096;i+=256){
      int j=i>>6, m=i&63;
      int jc=ct*64+j;
      if(jc<H2) t1[((size_t)(bb_*H2+jc))*HWn + n0 + m] = (ushort)cT[j*72+m];
    }
  }
}

// ---------------- depthwise 3x3 on t1 + GLU -> pg (B,360,HW) bf16 ----------------
__global__ void __launch_bounds__(256) k_dwglu(const bf16* __restrict__ t1, const float* __restrict__ dww,
    const float* __restrict__ dwb, bf16* __restrict__ pg){
  __shared__ float ta[34*34];
  __shared__ float tg[34*34];
  int tile_id=blockIdx.x; int c=blockIdx.y; int b=blockIdx.z;
  int ty0=(tile_id/3)*32, tx0=(tile_id%3)*32;
  int t=threadIdx.x;
  int px0=(t%16)*2, py0=(t/16)*2;
  for(int i=t;i<34*34;i+=256){
    int ly=i/34, lx=i%34; int gy=ty0+ly-1, gx=tx0+lx-1;
    bool ok=((unsigned)gy<96u&&(unsigned)gx<96u);
    ta[i]= ok? __bfloat162float(t1[((size_t)(b*H2+c)*96+gy)*96+gx]) :0.f;
    tg[i]= ok? __bfloat162float(t1[((size_t)(b*H2+c+HID)*96+gy)*96+gx]) :0.f;
  }
  __syncthreads();
  float wp[9],wg[9];
#pragma unroll
  for(int i=0;i<9;i++){ wp[i]=dww[c*9+i]; wg[i]=dww[(c+HID)*9+i]; }
  float bp=dwb[c], bg=dwb[c+HID];
#pragma unroll
  for(int oy=0;oy<2;oy++)
#pragma unroll
    for(int ox=0;ox<2;ox++){
      float p=bp,g=bg;
#pragma unroll
      for(int ky=0;ky<3;ky++)
#pragma unroll
        for(int kx=0;kx<3;kx++){
          p+=wp[ky*3+kx]*ta[(py0+oy+ky)*34+px0+ox+kx];
          g+=wg[ky*3+kx]*tg[(py0+oy+ky)*34+px0+ox+kx];
        }
      float val = p * g * sigm(g);
      pg[((size_t)(b*HID+c)*96 + ty0+py0+oy)*96 + tx0+px0+ox] = __float2bfloat16(val);
    }
}

// ---------------- fc2 MFMA + residual -> out (B,N,C); W direct, single K=384 pass ----------------
__global__ void __launch_bounds__(256) k_fc2(const ushort* __restrict__ pg, const float* __restrict__ xm,
    const ushort* __restrict__ Wp, const float* __restrict__ fb, float* __restrict__ out){
  __shared__ short As[64*392];   // 50176 B
  int rt = blockIdx.x, ct = blockIdx.y;
  int t = threadIdx.x;
  int w = t>>6, lane = t&63, kq = lane>>4, lr = lane&15;
  int grow0 = rt*64; int b = grow0/HWn; int n0 = grow0%HWn;
  for(int i=t;i<8*HID;i+=256){
    int rblk=i&7, kc=i>>3;
    int r0=rblk*8;
    s8v v = *(const s8v*)&pg[((size_t)(b*HID+kc))*HWn + n0 + r0];
#pragma unroll
    for(int q=0;q<8;q++) As[(r0+q)*392 + kc] = v[q];
  }
  for(int i=t;i<64*24;i+=256){
    int r=i/24, kk=i%24;
    As[r*392 + HID + kk] = 0;
  }
  __syncthreads();
  f4v acc[4]={};
  int arow=(w*16+lr)*392 + kq*8;
#pragma unroll
  for(int k0=0;k0<384;k0+=32){
    s8v af = *(const s8v*)&As[arow+k0];
#pragma unroll
    for(int ts=0;ts<4;ts++){
      s8v wf = *(const s8v*)&Wp[(size_t)(ct*64+ts*16+lr)*384 + kq*8 + k0];
      acc[ts]=__builtin_amdgcn_mfma_f32_16x16x32_bf16(af,wf,acc[ts],0,0,0);
    }
  }
#pragma unroll
  for(int ts=0;ts<4;ts++){
    int jc = ct*64 + ts*16 + lr;
    if(jc>=Cc) continue;
    float bb = fb[jc];
#pragma unroll
    for(int reg=0;reg<4;reg++){
      int m = w*16 + kq*4 + reg;
      size_t o = (size_t)(grow0+m)*Cc + jc;
      out[o] = xm[o] + acc[ts][reg] + bb;
    }
  }
}

extern "C" void kernel_launch(void* const* d_in, const int* in_sizes, int n_in,
                              void* d_out, int out_size, void* d_ws, size_t ws_size,
                              hipStream_t stream){
  (void)in_sizes; (void)n_in; (void)out_size; (void)ws_size;
  const float* x     = (const float*)d_in[0];
  const float* ln1_g = (const float*)d_in[3];
  const float* ln1_b = (const float*)d_in[4];
  const float* band_w= (const float*)d_in[5];
  const float* band_b= (const float*)d_in[6];
  const float* gate_w= (const float*)d_in[7];
  const float* gate_b= (const float*)d_in[8];
  const float* cab_w1= (const float*)d_in[9];
  const float* cab_b1= (const float*)d_in[10];
  const float* cab_w2= (const float*)d_in[11];
  const float* cab_b2= (const float*)d_in[12];
  const float* eca_w = (const float*)d_in[13];
  const float* plkw  = (const float*)d_in[14];
  const float* dwc_w1= (const float*)d_in[15];
  const float* dwc_b1= (const float*)d_in[16];
  const float* dwc_w2= (const float*)d_in[17];
  const float* dwc_b2= (const float*)d_in[18];
  const float* aggr_w= (const float*)d_in[19];
  const float* aggr_b= (const float*)d_in[20];
  const float* ln2_g = (const float*)d_in[21];
  const float* ln2_b = (const float*)d_in[22];
  const float* fc1_w = (const float*)d_in[23];
  const float* fc1_b = (const float*)d_in[24];
  const float* dw_w  = (const float*)d_in[25];
  const float* dw_b  = (const float*)d_in[26];
  const float* fc2_w = (const float*)d_in[27];
  const float* fc2_b = (const float*)d_in[28];

  float* ws = (float*)d_ws;
  // persistent region
  float* xm   = ws;                      // 13,271,040
  float* m1   = ws + 13271040;           // 1,440
  float* gates= ws + 13272480;           // 32
  float* dkb  = ws + 13272512;           // 1,152
  float* biasb= ws + 13273664;           // 1,440
  float* gapb = ws + 13275104;           // 1,440
  float* svec = ws + 13276544;           // 1,440 -> 13,277,984
  ushort* Wg1 = (ushort*)(ws + 13278000);// 110,592 sh -> 13,333,296
  ushort* Wg2 = (ushort*)(ws + 13333296);// 110,592 sh -> 13,388,592
  ushort* Wp1 = (ushort*)(ws + 13388592);// 147,456 sh -> 13,462,320
  ushort* Wp2 = (ushort*)(ws + 13462320);//  73,728 sh -> 13,499,184
  ushort* Wpa = (ushort*)(ws + 13499184);//  36,864 sh -> 13,517,616
  ushort* Bfx = (ushort*)(ws + 13517616);//  10,752 sh -> 13,522,992
  ushort* Tmw = (ushort*)(ws + 13522992);//  18,432 sh -> 13,532,208
  ushort* Bix = (ushort*)(ws + 13532208);//  12,288 sh -> 13,538,352
  float* big  = ws + 13538432;
  // phase 1 inside big:
  float* ximg = big;                     // 13,271,040
  float* spec = big + 13271040;          // 13,547,520 (xfft in first 9216 of each 9408 plane)
  ushort* mid = (ushort*)(big + 26818560); // 4,423,680 bf16
  float* attn = big + 29030400;          // 1,179,648 -> phase-1 top = 30,210,048
  float* ycab = spec;                    // reuse (stride 9216), spec dead after conv1
  // phase 2 aliases big:
  ushort* t1  = (ushort*)big;                    // 26,542,080 float slots
  float*  reg2= big + 26542080;
  ushort* xn2 = (ushort*)reg2;                   // (ln2->fc1)
  ushort* pgb = (ushort*)reg2;                   // (dwglu->fc2)
  // total ≈ 13,538,432 + 39,813,120 floats ≈ 213 MB

  k_packw<<<576,256,0,stream>>>(cab_w1, cab_w2, fc1_w, fc2_w, aggr_w, Wg1, Wg2, Wp1, Wp2, Wpa, Bfx, Tmw, Bix);
  k_ln1<<<2304,256,0,stream>>>(x, ln1_g, ln1_b, ximg);
  k_plane_mean<<<1440,256,0,stream>>>(ximg, m1);
  k_small<<<1,64,0,stream>>>(m1, gate_w, gate_b, dwc_w1, dwc_b1, dwc_w2, dwc_b2, band_b, gates, dkb, biasb);
  k_fft_fwd<<<1440,256,0,stream>>>(ximg, Bfx, Tmw, spec);
  k_bandmix<<<dim3(Bb,96,2),256,0,stream>>>(spec, band_w, gates);
  k_fft_inv<<<1440,256,0,stream>>>(spec, ximg, biasb, Tmw, Bix);
  k_cab<float, Cc, 192, 6, true,  true ><<<dim3(48,1,Bb),256,0,stream>>>(spec, Wg1, cab_b1, (void*)mid, CRr, SPL);
  k_cab<ushort, CRr, 64, 2, false, false><<<dim3(48,3,Bb),256,0,stream>>>(mid, Wg2, cab_b2, (void*)ycab, Cc, HWn);
  k_plane_mean<<<1440,256,0,stream>>>(ycab, gapb);
  k_eca<<<6,256,0,stream>>>(gapb, eca_w, svec);
  k_plk<<<dim3(9,PD,Bb),256,0,stream>>>(ximg, plkw, dkb, attn);
  k_aggrm<<<dim3(1152,3),256,0,stream>>>(x, attn, ximg, ycab, Wpa, aggr_b, svec, xm);
  k_ln2<<<18432,256,0,stream>>>(xm, ln2_g, ln2_b, xn2);
  k_fc1<<<1152,256,0,stream>>>(xn2, Wp1, fc1_b, t1);
  k_dwglu<<<dim3(9,HID,Bb),256,0,stream>>>((const bf16*)t1, dw_w, dw_b, (bf16*)pgb);
  k_fc2<<<dim3(1152,3),256,0,stream>>>(pgb, xm, Wp2, fc2_b, (float*)d_out);
}

// Round 8
// 1463.755 us; speedup vs baseline: 2.4816x; 1.0604x over previous
//
#include <hip/hip_runtime.h>
#include <hip/hip_bf16.h>
#include <math.h>
#include <type_traits>

#define Bb 8
#define Cc 180
#define HWn 9216
#define PD 16
#define CRr 60
#define HID 360
#define H2 720
#define NF 49
#define SPL 9408   /* spectral plane stride in floats: 96*49*2 */
#define CONV_SCALE 0.01f
#define FFT_RES 0.15f
#define EPSLN 1e-5f
#define TWOPI_96 0.06544984694978735f

typedef __hip_bfloat16 bf16;
typedef unsigned short ushort;
typedef __attribute__((ext_vector_type(8))) short s8v;   // 8 bf16 (4 VGPRs) MFMA A/B frag
typedef __attribute__((ext_vector_type(4))) float f4v;   // MFMA C/D frag

__device__ __forceinline__ float geluf(float x){ return 0.5f*x*(1.0f+erff(x*0.7071067811865476f)); }
__device__ __forceinline__ float sigm(float x){ return 1.0f/(1.0f+expf(-x)); }
__device__ __forceinline__ short f2bf(float f){
  unsigned u = __float_as_uint(f);
  u += 0x7fff + ((u>>16)&1);
  return (short)(u>>16);
}
__device__ __forceinline__ float wredsum(float v){
#pragma unroll
  for(int m=1;m<64;m<<=1) v += __shfl_xor(v,m,64);
  return v;
}

// ---------------- LN1 + transpose to (B,C,H,W) ----------------
__global__ void __launch_bounds__(256) k_ln1(const float* __restrict__ x, const float* __restrict__ g,
                      const float* __restrict__ be, float* __restrict__ ximg){
  __shared__ float sb[32*Cc];
  int b = blockIdx.x / 288;
  int n0 = (blockIdx.x % 288) * 32;
  int t = threadIdx.x;
  const float* src = x + (size_t)(b*HWn + n0)*Cc;
  for(int i=t;i<32*Cc;i+=256) sb[i]=src[i];
  __syncthreads();
  int w = t>>6, lane = t&63;
  for(int pi=0; pi<8; ++pi){
    int p = w*8+pi;
    float s=0.f, sq=0.f;
    for(int e=lane;e<Cc;e+=64){ float v=sb[p*Cc+e]; s+=v; sq+=v*v; }
    s = wredsum(s); sq = wredsum(sq);
    float mean = s*(1.0f/180.0f);
    float var = sq*(1.0f/180.0f) - mean*mean;
    float rstd = rsqrtf(var + EPSLN);
    for(int e=lane;e<Cc;e+=64){ float v=sb[p*Cc+e]; sb[p*Cc+e] = (v-mean)*rstd*g[e]+be[e]; }
  }
  __syncthreads();
  for(int i=t;i<32*Cc;i+=256){
    int c = i/32, p = i%32;
    ximg[(size_t)(b*Cc+c)*HWn + n0 + p] = sb[p*Cc+c];
  }
}

// ---------------- plane mean (9216 -> 1) ----------------
__global__ void __launch_bounds__(256) k_plane_mean(const float* __restrict__ in, float* __restrict__ out){
  __shared__ float red[4];
  int pl = blockIdx.x; int t = threadIdx.x;
  const float* p = in + (size_t)pl*HWn;
  float s=0.f;
  for(int i=t;i<HWn;i+=256) s+=p[i];
  s = wredsum(s);
  if((t&63)==0) red[t>>6]=s;
  __syncthreads();
  if(t==0) out[pl] = (red[0]+red[1]+red[2]+red[3]) * (1.0f/9216.0f);
}

// ---------------- small: gates, hdn->dk, fft bias ----------------
__global__ void k_small(const float* __restrict__ m1, const float* __restrict__ gate_w,
   const float* __restrict__ gate_b, const float* __restrict__ dwc_w1, const float* __restrict__ dwc_b1,
   const float* __restrict__ dwc_w2, const float* __restrict__ dwc_b2, const float* __restrict__ band_b,
   float* __restrict__ gates, float* __restrict__ dkb, float* __restrict__ biasb){
  int b = threadIdx.x;
  if(b>=Bb) return;
  const float* m = m1 + b*Cc;
  float gv[3];
  for(int k=0;k<3;k++){ float a=gate_b[k]; for(int c=0;c<Cc;c++) a+=m[c]*gate_w[k*Cc+c]; gv[k]=sigm(a);}
  float e0=expf(gv[0]), e1=expf(gv[1]), e2=expf(gv[2]); float inv=1.0f/(e0+e1+e2);
  float g0=e0*inv,g1=e1*inv,g2=e2*inv;
  gates[b*3+0]=g0; gates[b*3+1]=g1; gates[b*3+2]=g2;
  float hd[8];
  for(int j=0;j<8;j++){ float a=dwc_b1[j]; for(int c=0;c<PD;c++) a+=m[c]*dwc_w1[j*PD+c]; hd[j]=geluf(a);}
  for(int i=0;i<144;i++){ float a=dwc_b2[i]; for(int j=0;j<8;j++) a+=hd[j]*dwc_w2[i*8+j]; dkb[b*144+i]=a; }
  for(int d=0;d<Cc;d++) biasb[b*Cc+d] = g0*band_b[0*Cc+d]+g1*band_b[1*Cc+d]+g2*band_b[2*Cc+d];
}

// ------- pack weights to bf16 + DFT twiddle matrices -------
__global__ void __launch_bounds__(256) k_packw(const float* __restrict__ w1, const float* __restrict__ w2,
    const float* __restrict__ fw1, const float* __restrict__ fw2, const float* __restrict__ aw,
    const float* __restrict__ bw,
    ushort* __restrict__ Wg1, ushort* __restrict__ Wg2, ushort* __restrict__ Wp1,
    ushort* __restrict__ Wp2, ushort* __restrict__ Wpa, ushort* __restrict__ Wbk,
    ushort* __restrict__ Bfx, ushort* __restrict__ Tm, ushort* __restrict__ Bix){
  int t = blockIdx.x*256 + threadIdx.x;
  if(t < 64*9*192){
    int co = t/(9*192); int rem = t%(9*192); int tap = rem/192; int ci = rem%192;
    float v = (co<CRr && ci<Cc) ? w1[((size_t)(co*Cc+ci))*9 + tap] : 0.f;
    Wg1[t] = (ushort)f2bf(v);
  }
  if(t < 192*9*64){
    int co = t/(9*64); int rem = t%(9*64); int tap = rem/64; int ci = rem%64;
    float v = (co<Cc && ci<CRr) ? w2[((size_t)(co*CRr+ci))*9 + tap] : 0.f;
    Wg2[t] = (ushort)f2bf(v);
  }
  if(t < 768*192){
    int j=t/192, k=t%192;
    Wp1[t] = (ushort)f2bf((j<H2 && k<Cc)? fw1[(size_t)j*Cc+k] : 0.f);
  }
  if(t < 192*384){
    int j=t/384, k=t%384;
    Wp2[t] = (ushort)f2bf((j<Cc && k<HID)? fw2[(size_t)j*HID+k] : 0.f);
  }
  if(t < 192*192){
    int j=t/192, k=t%192;
    Wpa[t] = (ushort)f2bf((j<Cc && k<Cc)? aw[(size_t)j*Cc+k] : 0.f);
  }
  // Wbk[3][192 d][192 c] : band channel-mix weights
  if(t < 3*192*192){
    int k=t/(192*192); int rem=t%(192*192); int j=rem/192, c=rem%192;
    Wbk[t] = (ushort)f2bf((j<Cc && c<Cc)? bw[((size_t)k*Cc + j)*Cc + c] : 0.f);
  }
  // Bfx[112 n][96 k] : fwd-x twiddle (ortho 1/96 folded)
  if(t < 112*96){
    int n=t/96, k=t%96;
    float v=0.f;
    if(n<98){
      int kx=n>>1; int m=(k*kx)%96; float th=(float)m*TWOPI_96;
      v = ((n&1)? -sinf(th) : cosf(th)) * (1.0f/96.0f);
    }
    Bfx[t] = (ushort)f2bf(v);
  }
  // Tm[96 r][192 k] : y-transform twiddle (shared fwd/inv)
  if(t < 96*192){
    int r=t/192, k=t%192;
    int c=k>>1; int m=(r*c)%96; float th=(float)m*TWOPI_96;
    float v = (k&1)? sinf(th) : cosf(th);
    Tm[t] = (ushort)f2bf(v);
  }
  // Bix[96 n][128 k] : inv-x twiddle (wgt and 1/96 folded)
  if(t < 96*128){
    int n=t/128, k=t%128;
    float v=0.f;
    if(k<98){
      int kx=k>>1; float wgt=(kx==0||kx==48)?1.0f:2.0f;
      int m=(n*kx)%96; float th=(float)m*TWOPI_96;
      v = ((k&1)? -wgt*sinf(th) : wgt*cosf(th)) * (1.0f/96.0f);
    }
    Bix[t] = (ushort)f2bf(v);
  }
}

// ---------------- fused forward 2D rDFT (per plane), MFMA ----------------
__global__ void __launch_bounds__(256) k_fft_fwd(const float* __restrict__ ximg,
    const ushort* __restrict__ Bfx, const ushort* __restrict__ Tm, float* __restrict__ S){
  __shared__ __align__(16) short Asi[96*104];
  __shared__ __align__(16) short Bv[112*200];
  int bc = blockIdx.x; int t = threadIdx.x;
  int w=t>>6, lane=t&63, kq=lane>>4, lr=lane&15;
  const float* src = ximg + (size_t)bc*HWn;
  for(int i=t;i<1152;i+=256){
    int y=i/12, seg=i%12;
    float4 v0 = *(const float4*)(src + y*96 + seg*8);
    float4 v1 = *(const float4*)(src + y*96 + seg*8 + 4);
    s8v pk;
    pk[0]=f2bf(v0.x); pk[1]=f2bf(v0.y); pk[2]=f2bf(v0.z); pk[3]=f2bf(v0.w);
    pk[4]=f2bf(v1.x); pk[5]=f2bf(v1.y); pk[6]=f2bf(v1.z); pk[7]=f2bf(v1.w);
    *(s8v*)&Asi[y*104+seg*8] = pk;
  }
  __syncthreads();
  // stage1: V[y][n] = img @ Bfx^T ; write (V, -i*V) into Bv[n][2y,2y+1]
  for(int tile=w; tile<42; tile+=4){
    int mt=tile/7, nt=tile%7;
    f4v acc={};
#pragma unroll
    for(int ks=0;ks<3;ks++){
      s8v af = *(const s8v*)&Asi[(mt*16+lr)*104 + kq*8 + ks*32];
      s8v bf = *(const s8v*)&Bfx[(size_t)(nt*16+lr)*96 + kq*8 + ks*32];
      acc = __builtin_amdgcn_mfma_f32_16x16x32_bf16(af,bf,acc,0,0,0);
    }
    int n = nt*16+lr;
    float sgn = (n&1)? -1.f : 1.f;
#pragma unroll
    for(int reg=0;reg<4;reg++){
      int y = mt*16+kq*4+reg;
      float v = acc[reg];
      float p = __shfl_xor(v,1);
      unsigned pack = ((unsigned)(ushort)f2bf(sgn*p)<<16) | (ushort)(unsigned short)f2bf(v);
      *(unsigned*)&Bv[n*200 + 2*y] = pack;
    }
  }
  __syncthreads();
  // stage2: X[ky][n] = Tm @ Bv^T -> global fp32 spec plane
  float* dst = S + (size_t)bc*SPL;
  for(int tile=w; tile<42; tile+=4){
    int mt=tile/7, nt=tile%7;
    f4v acc={};
#pragma unroll
    for(int ks=0;ks<6;ks++){
      s8v af = *(const s8v*)&Tm[(size_t)(mt*16+lr)*192 + kq*8 + ks*32];
      s8v bf = *(const s8v*)&Bv[(nt*16+lr)*200 + kq*8 + ks*32];
      acc = __builtin_amdgcn_mfma_f32_16x16x32_bf16(af,bf,acc,0,0,0);
    }
    int n = nt*16+lr;
    if(n<98){
#pragma unroll
      for(int reg=0;reg<4;reg++){
        int ky = mt*16+kq*4+reg;
        dst[ky*98 + n] = acc[reg];
      }
    }
  }
}

// ---------------- fused inverse 2D rDFT + combine (per plane), MFMA, in-place ----------------
__global__ void __launch_bounds__(256) k_fft_inv(float* __restrict__ S, const float* __restrict__ ximg,
    const float* __restrict__ biasb, const ushort* __restrict__ Tm, const ushort* __restrict__ Bix){
  __shared__ __align__(16) short Bv[112*200];
  __shared__ __align__(16) short T2s[96*136];
  int bd = blockIdx.x; int t=threadIdx.x;
  int w=t>>6, lane=t&63, kq=lane>>4, lr=lane&15;
  int b = bd/Cc, d = bd%Cc;
  float* pl = S + (size_t)bd*SPL;
  // zero Bv rows n=98..111 and T2s cols 112..135
  for(int i=t;i<1400;i+=256) ((unsigned*)&Bv[98*200])[i] = 0u;
  for(int i=t;i<1152;i+=256){ int y=i/12, c=i%12; *(unsigned*)&T2s[y*136+112+c*2] = 0u; }
  // build Bv from Yhat with +i twist (partner via shfl)
  for(int i=t;i<9408;i+=256){
    float v = pl[i];
    float p = __shfl_xor(v,1);
    int ky = i/98, n = i%98;
    float tw = (n&1)? p : -p;
    unsigned pack = ((unsigned)(ushort)f2bf(tw)<<16) | (ushort)(unsigned short)f2bf(v);
    *(unsigned*)&Bv[n*200 + 2*ky] = pack;
  }
  __syncthreads();
  // stage1: T2[y][n] = Tm @ Bv^T -> LDS
  for(int tile=w; tile<42; tile+=4){
    int mt=tile/7, nt=tile%7;
    f4v acc={};
#pragma unroll
    for(int ks=0;ks<6;ks++){
      s8v af = *(const s8v*)&Tm[(size_t)(mt*16+lr)*192 + kq*8 + ks*32];
      s8v bf = *(const s8v*)&Bv[(nt*16+lr)*200 + kq*8 + ks*32];
      acc = __builtin_amdgcn_mfma_f32_16x16x32_bf16(af,bf,acc,0,0,0);
    }
    int n = nt*16+lr;
#pragma unroll
    for(int reg=0;reg<4;reg++){
      int y = mt*16+kq*4+reg;
      T2s[y*136 + n] = f2bf(acc[reg]);
    }
  }
  __syncthreads();
  // stage2: out[y][xx] = T2 @ Bix^T ; combine with ximg + bias, in-place
  float bias = biasb[b*Cc+d];
  const float* xs = ximg + (size_t)bd*HWn;
  for(int tile=w; tile<36; tile+=4){
    int mt=tile/6, nt=tile%6;
    f4v acc={};
#pragma unroll
    for(int ks=0;ks<4;ks++){
      s8v af = *(const s8v*)&T2s[(mt*16+lr)*136 + kq*8 + ks*32];
      s8v bf = *(const s8v*)&Bix[(size_t)(nt*16+lr)*128 + kq*8 + ks*32];
      acc = __builtin_amdgcn_mfma_f32_16x16x32_bf16(af,bf,acc,0,0,0);
    }
    int xx = nt*16+lr;
#pragma unroll
    for(int reg=0;reg<4;reg++){
      int y = mt*16+kq*4+reg;
      int o = y*96+xx;
      pl[o] = xs[o] + FFT_RES*(acc[reg] + bias);
    }
  }
}

// ---------------- band channel mix as MFMA GEMM, IN-PLACE, per-column band select ----------------
__global__ void __launch_bounds__(256) k_bandmixm(float* __restrict__ S, const ushort* __restrict__ Wbk,
                          const float* __restrict__ gates){
  __shared__ __align__(16) short Bs[64*200];
  int f2base = blockIdx.x*64;
  int b = blockIdx.y;
  int t = threadIdx.x;
  int w=t>>6, lane=t&63, kq=lane>>4, lr=lane&15;
  // stage X-tile transposed: Bs[r=f2local][c], bf16, K padded to 192
  for(int i=t;i<8*192;i+=256){
    int rblk=i&7, kk=i>>3;
    int r0=rblk*8;
    if(kk<Cc){
      const float* src = S + (size_t)(b*Cc+kk)*SPL + f2base + r0;
      float4 v0 = *(const float4*)src;
      float4 v1 = *(const float4*)(src+4);
      Bs[(r0+0)*200+kk]=f2bf(v0.x); Bs[(r0+1)*200+kk]=f2bf(v0.y);
      Bs[(r0+2)*200+kk]=f2bf(v0.z); Bs[(r0+3)*200+kk]=f2bf(v0.w);
      Bs[(r0+4)*200+kk]=f2bf(v1.x); Bs[(r0+5)*200+kk]=f2bf(v1.y);
      Bs[(r0+6)*200+kk]=f2bf(v1.z); Bs[(r0+7)*200+kk]=f2bf(v1.w);
    } else {
#pragma unroll
      for(int q=0;q<8;q++) Bs[(r0+q)*200+kk]=0;
    }
  }
  // block-wide band mask (64 cols, one per lane; all waves compute same)
  unsigned bmask;
  {
    int col = f2base + lane;
    int ky = col/98, n = col%98, kx = n>>1;
    float yy = -1.0f + 2.0f*(float)ky/95.0f;
    float xxf = (float)kx/48.0f;
    float rr = sqrtf(yy*yy+xxf*xxf);
    int k = (rr<=0.25f)?0:((rr<=0.6f)?1:2);
    unsigned m = 1u<<k;
#pragma unroll
    for(int s=1;s<64;s<<=1) m |= __shfl_xor(m,s);
    bmask = m;
  }
  // per-lane band/gate for my 4 C-columns (f2local = w*16 + kq*4 + reg)
  int kb[4]; float gv[4];
#pragma unroll
  for(int reg=0;reg<4;reg++){
    int col = f2base + w*16 + kq*4 + reg;
    int ky = col/98, n = col%98, kx = n>>1;
    float yy = -1.0f + 2.0f*(float)ky/95.0f;
    float xxf = (float)kx/48.0f;
    float rr = sqrtf(yy*yy+xxf*xxf);
    kb[reg] = (rr<=0.25f)?0:((rr<=0.6f)?1:2);
    gv[reg] = gates[b*3+kb[reg]];
  }
  __syncthreads();
  s8v af[6];
#pragma unroll
  for(int k6=0;k6<6;k6++) af[k6] = *(const s8v*)&Bs[(w*16+lr)*200 + kq*8 + k6*32];
  float res[12][4];
  for(int k=0;k<3;k++){
    if(!(bmask&(1u<<k))) continue;
    for(int ts=0;ts<12;ts++){
      f4v acc={};
#pragma unroll
      for(int k6=0;k6<6;k6++){
        s8v wf = *(const s8v*)&Wbk[((size_t)(k*192 + ts*16+lr))*192 + kq*8 + k6*32];
        acc = __builtin_amdgcn_mfma_f32_16x16x32_bf16(af[k6],wf,acc,0,0,0);
      }
#pragma unroll
      for(int reg=0;reg<4;reg++) if(kb[reg]==k) res[ts][reg]=gv[reg]*acc[reg];
    }
  }
  // write back: each lane stores float4 (4 consecutive f2) per d-row
#pragma unroll
  for(int ts=0;ts<12;ts++){
    int d = ts*16+lr;
    if(d<Cc){
      float4 o; o.x=res[ts][0]; o.y=res[ts][1]; o.z=res[ts][2]; o.w=res[ts][3];
      *(float4*)(S + (size_t)(b*Cc+d)*SPL + f2base + w*16 + kq*4) = o;
    }
  }
}

// ---------------- CAB 3x3 conv as implicit-GEMM MFMA ----------------
template<typename TIN, int CIN, int KPAD, int NCHUNK, bool ACT, bool OUTBF>
__global__ void __launch_bounds__(256) k_cab(const TIN* __restrict__ xin, const ushort* __restrict__ Wg,
    const float* __restrict__ bias, void* __restrict__ outv, int COUT, int istride){
  __shared__ short As[4*98*36];   // 28224 B; also reused for epilogue transpose
  int y0 = blockIdx.x*2;
  int ct = blockIdx.y;
  int b  = blockIdx.z;
  int t = threadIdx.x;
  int w = t>>6, lane = t&63, kq = lane>>4, lr = lane&15;
  f4v acc[3][4] = {};
  for(int ch=0; ch<NCHUNK; ++ch){
    int ci0 = ch*32;
    __syncthreads();
    for(int i=t;i<4*98*32;i+=256){
      int ci = i/392; int rem = i%392; int row = rem/98; int pxh = rem%98;
      int gy = y0 - 1 + row; int px = pxh - 1;
      int cig = ci0 + ci;
      short sv = 0;
      if((unsigned)gy<96u && (unsigned)px<96u && cig<CIN){
        if constexpr (std::is_same<TIN,float>::value)
          sv = f2bf(xin[(size_t)(b*CIN+cig)*istride + gy*96 + px]);
        else
          sv = (short)xin[(size_t)(b*CIN+cig)*istride + gy*96 + px];
      }
      As[(row*98+pxh)*36 + ci] = sv;
    }
    __syncthreads();
#pragma unroll
    for(int tap=0; tap<9; ++tap){
      int ky = tap/3, kx = tap%3;
      s8v bfr[4];
#pragma unroll
      for(int ts=0;ts<4;ts++)
        bfr[ts] = *(const s8v*)&Wg[((size_t)(ct*64 + ts*16 + lr)*9 + tap)*KPAD + ci0 + kq*8];
#pragma unroll
      for(int s=0;s<3;s++){
        int mt = w + 4*s;
        int orow = mt/6, px = (mt%6)*16 + lr;
        s8v af = *(const s8v*)&As[((orow+ky)*98 + px + kx)*36 + kq*8];
#pragma unroll
        for(int ts=0;ts<4;ts++)
          acc[s][ts] = __builtin_amdgcn_mfma_f32_16x16x32_bf16(af, bfr[ts], acc[s][ts], 0,0,0);
      }
    }
  }
  // epilogue
  if(OUTBF){
    __syncthreads();
    short* cT = As;   // [64 co][200] bf16
#pragma unroll
    for(int ts=0;ts<4;ts++){
      int cog = ct*64 + ts*16 + lr;
      float bb = (cog<COUT)? bias[cog] : 0.f;
#pragma unroll
      for(int s=0;s<3;s++){
#pragma unroll
        for(int reg=0;reg<4;reg++){
          int px = (w+4*s)*16 + kq*4 + reg;
          float v = acc[s][ts][reg] + bb;
          if(ACT) v = geluf(v);
          cT[(ts*16+lr)*200 + px] = f2bf(v);
        }
      }
    }
    __syncthreads();
    ushort* out = (ushort*)outv;
    for(int i=t;i<64*192;i+=256){
      int co=i/192, px=i%192;
      int cog = ct*64+co;
      if(cog<COUT) out[(size_t)(b*COUT+cog)*HWn + y0*96 + px] = (ushort)cT[co*200+px];
    }
  } else {
    float* cF = (float*)As;  // [32 co][200] fp32 per half
    float* out = (float*)outv;
    for(int h=0;h<2;h++){
      __syncthreads();
#pragma unroll
      for(int tt=0;tt<2;tt++){
        int ts = 2*h+tt;
        int cog = ct*64 + ts*16 + lr;
        float bb = (cog<COUT)? bias[cog] : 0.f;
#pragma unroll
        for(int s=0;s<3;s++){
#pragma unroll
          for(int reg=0;reg<4;reg++){
            int px = (w+4*s)*16 + kq*4 + reg;
            cF[(tt*16+lr)*200 + px] = acc[s][ts][reg] + bb;
          }
        }
      }
      __syncthreads();
      for(int i=t;i<32*192;i+=256){
        int co=i/192, px=i%192;
        int cog = ct*64 + h*32 + co;
        if(cog<COUT) out[(size_t)(b*COUT+cog)*HWn + y0*96 + px] = cF[co*200+px];
      }
    }
  }
}

// ---------------- ECA ----------------
__global__ void k_eca(const float* __restrict__ gap, const float* __restrict__ ew, float* __restrict__ s){
  int i = blockIdx.x*blockDim.x + threadIdx.x;
  if(i>=Bb*Cc) return;
  int b=i/Cc, c=i%Cc;
  float z=0.f;
  for(int j=0;j<5;j++){ int cc=c-2+j; if(cc>=0&&cc<Cc) z+=gap[b*Cc+cc]*ew[j]; }
  s[i]=sigm(z);
}

// ---------------- plk 13x13 conv (16->16) + fused dynamic depthwise 3x3 ----------------
__global__ void __launch_bounds__(256) k_plk(const float* __restrict__ ximg, const float* __restrict__ plk,
    const float* __restrict__ dkb, float* __restrict__ attn){
  __shared__ float tile[44*44];
  __shared__ float wl[169];
  __shared__ float dk9[9];
  int tile_id=blockIdx.x; int co=blockIdx.y; int b=blockIdx.z;
  int ty0=(tile_id/3)*32, tx0=(tile_id%3)*32;
  int t=threadIdx.x;
  int px0=(t%16)*2, py0=(t/16)*2;
  if(t<9) dk9[t]=dkb[b*144+co*9+t];
  float a00=0,a01=0,a10=0,a11=0;
  for(int ci=0;ci<PD;++ci){
    __syncthreads();
    for(int i=t;i<44*44;i+=256){
      int ly=i/44, lx=i%44;
      int gy=ty0+ly-6, gx=tx0+lx-6;
      float v=0.f;
      if((unsigned)gy<96u&&(unsigned)gx<96u) v=ximg[((size_t)(b*Cc+ci)*96+gy)*96+gx];
      tile[i]=v;
    }
    for(int i=t;i<169;i+=256) wl[i]=plk[((size_t)(co*PD+ci)*169)+i];
    __syncthreads();
    for(int rr2=0; rr2<14; ++rr2){
      float rowv[14];
      const float* trow = tile + (py0+rr2)*44 + px0;
#pragma unroll
      for(int i=0;i<14;i++) rowv[i]=trow[i];
      if(rr2<13){
        const float* wr = wl + rr2*13;
#pragma unroll
        for(int kx=0;kx<13;kx++){ float w=wr[kx]; a00+=w*rowv[kx]; a01+=w*rowv[kx+1]; }
      }
      if(rr2>=1){
        const float* wr = wl + (rr2-1)*13;
#pragma unroll
        for(int kx=0;kx<13;kx++){ float w=wr[kx]; a10+=w*rowv[kx]; a11+=w*rowv[kx+1]; }
      }
    }
    if(ci==co){
#pragma unroll
      for(int ky=0;ky<3;ky++)
#pragma unroll
        for(int kx=0;kx<3;kx++){
          float w=dk9[ky*3+kx];
          a00+=w*tile[(py0+5+ky)*44+px0+5+kx];
          a01+=w*tile[(py0+5+ky)*44+px0+6+kx];
          a10+=w*tile[(py0+6+ky)*44+px0+5+kx];
          a11+=w*tile[(py0+6+ky)*44+px0+6+kx];
        }
    }
  }
  int gy=ty0+py0, gx=tx0+px0;
  float* dst = attn + (size_t)(b*PD+co)*HWn;
  dst[gy*96+gx]=a00; dst[gy*96+gx+1]=a01; dst[(gy+1)*96+gx]=a10; dst[(gy+1)*96+gx+1]=a11;
}

// ---------------- aggr as MFMA GEMM + residual + conv_x scale -> xm (B,N,C) ----------------
__global__ void __launch_bounds__(256) k_aggrm(const float* __restrict__ x, const float* __restrict__ attn,
   const float* __restrict__ ximg, const float* __restrict__ ycab, const ushort* __restrict__ Wpa,
   const float* __restrict__ aggb, const float* __restrict__ svec, float* __restrict__ xm){
  __shared__ short smem[64*200];   // As ; reused as cF (fp32 64x68) in epilogue
  short* As = smem;
  int rt = blockIdx.x, ct = blockIdx.y;
  int t = threadIdx.x;
  int w = t>>6, lane = t&63, kq = lane>>4, lr = lane&15;
  int grow0 = rt*64; int b = grow0/HWn; int n0 = grow0%HWn;
  for(int i=t;i<8*192;i+=256){
    int rblk=i&7, kk=i>>3;
    int r0=rblk*8;
    if(kk<Cc){
      const float* src = (kk<PD)? attn + (size_t)(b*PD+kk)*HWn + n0 + r0
                                : ximg + (size_t)(b*Cc+kk)*HWn + n0 + r0;
      float4 v0 = *(const float4*)src;
      float4 v1 = *(const float4*)(src+4);
      As[(r0+0)*200+kk]=f2bf(v0.x); As[(r0+1)*200+kk]=f2bf(v0.y);
      As[(r0+2)*200+kk]=f2bf(v0.z); As[(r0+3)*200+kk]=f2bf(v0.w);
      As[(r0+4)*200+kk]=f2bf(v1.x); As[(r0+5)*200+kk]=f2bf(v1.y);
      As[(r0+6)*200+kk]=f2bf(v1.z); As[(r0+7)*200+kk]=f2bf(v1.w);
    } else {
#pragma unroll
      for(int q=0;q<8;q++) As[(r0+q)*200+kk]=0;
    }
  }
  __syncthreads();
  f4v acc[4]={};
  int arow=(w*16+lr)*200 + kq*8;
#pragma unroll
  for(int k0=0;k0<192;k0+=32){
    s8v af = *(const s8v*)&As[arow+k0];
#pragma unroll
    for(int ts=0;ts<4;ts++){
      s8v wf = *(const s8v*)&Wpa[(size_t)(ct*64+ts*16+lr)*192 + kq*8 + k0];
      acc[ts]=__builtin_amdgcn_mfma_f32_16x16x32_bf16(af,wf,acc[ts],0,0,0);
    }
  }
  __syncthreads();
  float* cF = (float*)smem;
#pragma unroll
  for(int ts=0;ts<4;ts++){
    int j = ts*16+lr;
    int jc = ct*64 + j;
    float bb=0.f, sv=0.f;
    if(jc<Cc){ bb=aggb[jc]; sv=CONV_SCALE*svec[b*Cc+jc]; }
    const float* yrow = ycab + ((jc<Cc)? (size_t)(b*Cc+jc)*HWn + n0 : 0);
#pragma unroll
    for(int reg=0;reg<4;reg++){
      int m = w*16 + kq*4 + reg;
      float v = 0.f;
      if(jc<Cc) v = acc[ts][reg] + bb + sv*yrow[m];
      cF[m*68+j] = v;
    }
  }
  __syncthreads();
  for(int i=t;i<64*64;i+=256){
    int m=i>>6, j=i&63;
    int jc=ct*64+j;
    if(jc<Cc){
      size_t o = (size_t)(grow0+m)*Cc + jc;
      xm[o] = x[o] + cF[m*68+j];
    }
  }
}

// ---------------- LN2 fused: stats + normalize + bf16 cast, K padded 180->192 ----------------
__global__ void __launch_bounds__(256) k_ln2(const float* __restrict__ xm, const float* __restrict__ g2,
    const float* __restrict__ b2, ushort* __restrict__ xn2){
  int w = (blockIdx.x*256 + threadIdx.x)>>6;
  int lane = threadIdx.x&63;
  const float* row = xm + (size_t)w*Cc;
  float s=0,sq=0;
  for(int e=lane;e<Cc;e+=64){ float v=row[e]; s+=v; sq+=v*v; }
  s=wredsum(s); sq=wredsum(sq);
  float m=s*(1.0f/180.0f); float v=sq*(1.0f/180.0f)-m*m;
  float rstd=rsqrtf(v+EPSLN);
  ushort* orow = xn2 + (size_t)w*192;
  for(int e=lane;e<192;e+=64){
    float val = (e<Cc)? (row[e]-m)*rstd*g2[e]+b2[e] : 0.f;
    orow[e] = (ushort)f2bf(val);
  }
}

// -------- fc1 MFMA, W direct from packed global, A frags in registers, ct loop --------
__global__ void __launch_bounds__(256) k_fc1(const ushort* __restrict__ xn2,
    const ushort* __restrict__ Wp, const float* __restrict__ fb, ushort* __restrict__ t1){
  __shared__ short cT[64*72];   // 9216 B epilogue transpose
  int rt = blockIdx.x;
  int t = threadIdx.x;
  int w = t>>6, lane = t&63, kq = lane>>4, lr = lane&15;
  int grow0 = rt*64;
  int bb_ = grow0/HWn, n0 = grow0%HWn;
  s8v af[6];
  const ushort* arow = xn2 + (size_t)(grow0 + w*16 + lr)*192 + kq*8;
#pragma unroll
  for(int k6=0;k6<6;k6++) af[k6] = *(const s8v*)(arow + k6*32);
  for(int ct=0; ct<12; ++ct){
    f4v acc[4]={};
#pragma unroll
    for(int k6=0;k6<6;k6++){
#pragma unroll
      for(int ts=0;ts<4;ts++){
        s8v wf = *(const s8v*)&Wp[(size_t)(ct*64+ts*16+lr)*192 + kq*8 + k6*32];
        acc[ts]=__builtin_amdgcn_mfma_f32_16x16x32_bf16(af[k6],wf,acc[ts],0,0,0);
      }
    }
    __syncthreads();
#pragma unroll
    for(int ts=0;ts<4;ts++){
      int j = ts*16+lr;
      int jc = ct*64+j;
      float bb = (jc<H2)? fb[jc] : 0.f;
#pragma unroll
      for(int reg=0;reg<4;reg++){
        int m = w*16 + kq*4 + reg;
        cT[j*72+m] = f2bf(acc[ts][reg]+bb);
      }
    }
    __syncthreads();
    for(int i=t;i<4096;i+=256){
      int j=i>>6, m=i&63;
      int jc=ct*64+j;
      if(jc<H2) t1[((size_t)(bb_*H2+jc))*HWn + n0 + m] = (ushort)cT[j*72+m];
    }
  }
}

// ---------------- depthwise 3x3 on t1 + GLU -> pg (B,360,HW) bf16 ----------------
__global__ void __launch_bounds__(256) k_dwglu(const bf16* __restrict__ t1, const float* __restrict__ dww,
    const float* __restrict__ dwb, bf16* __restrict__ pg){
  __shared__ float ta[34*34];
  __shared__ float tg[34*34];
  int tile_id=blockIdx.x; int c=blockIdx.y; int b=blockIdx.z;
  int ty0=(tile_id/3)*32, tx0=(tile_id%3)*32;
  int t=threadIdx.x;
  int px0=(t%16)*2, py0=(t/16)*2;
  for(int i=t;i<34*34;i+=256){
    int ly=i/34, lx=i%34; int gy=ty0+ly-1, gx=tx0+lx-1;
    bool ok=((unsigned)gy<96u&&(unsigned)gx<96u);
    ta[i]= ok? __bfloat162float(t1[((size_t)(b*H2+c)*96+gy)*96+gx]) :0.f;
    tg[i]= ok? __bfloat162float(t1[((size_t)(b*H2+c+HID)*96+gy)*96+gx]) :0.f;
  }
  __syncthreads();
  float wp[9],wg[9];
#pragma unroll
  for(int i=0;i<9;i++){ wp[i]=dww[c*9+i]; wg[i]=dww[(c+HID)*9+i]; }
  float bp=dwb[c], bg=dwb[c+HID];
#pragma unroll
  for(int oy=0;oy<2;oy++)
#pragma unroll
    for(int ox=0;ox<2;ox++){
      float p=bp,g=bg;
#pragma unroll
      for(int ky=0;ky<3;ky++)
#pragma unroll
        for(int kx=0;kx<3;kx++){
          p+=wp[ky*3+kx]*ta[(py0+oy+ky)*34+px0+ox+kx];
          g+=wg[ky*3+kx]*tg[(py0+oy+ky)*34+px0+ox+kx];
        }
      float val = p * g * sigm(g);
      pg[((size_t)(b*HID+c)*96 + ty0+py0+oy)*96 + tx0+px0+ox] = __float2bfloat16(val);
    }
}

// ---------------- fc2 MFMA + residual -> out (B,N,C); W direct, single K=384 pass ----------------
__global__ void __launch_bounds__(256) k_fc2(const ushort* __restrict__ pg, const float* __restrict__ xm,
    const ushort* __restrict__ Wp, const float* __restrict__ fb, float* __restrict__ out){
  __shared__ short As[64*392];   // 50176 B
  int rt = blockIdx.x, ct = blockIdx.y;
  int t = threadIdx.x;
  int w = t>>6, lane = t&63, kq = lane>>4, lr = lane&15;
  int grow0 = rt*64; int b = grow0/HWn; int n0 = grow0%HWn;
  for(int i=t;i<8*HID;i+=256){
    int rblk=i&7, kc=i>>3;
    int r0=rblk*8;
    s8v v = *(const s8v*)&pg[((size_t)(b*HID+kc))*HWn + n0 + r0];
#pragma unroll
    for(int q=0;q<8;q++) As[(r0+q)*392 + kc] = v[q];
  }
  for(int i=t;i<64*24;i+=256){
    int r=i/24, kk=i%24;
    As[r*392 + HID + kk] = 0;
  }
  __syncthreads();
  f4v acc[4]={};
  int arow=(w*16+lr)*392 + kq*8;
#pragma unroll
  for(int k0=0;k0<384;k0+=32){
    s8v af = *(const s8v*)&As[arow+k0];
#pragma unroll
    for(int ts=0;ts<4;ts++){
      s8v wf = *(const s8v*)&Wp[(size_t)(ct*64+ts*16+lr)*384 + kq*8 + k0];
      acc[ts]=__builtin_amdgcn_mfma_f32_16x16x32_bf16(af,wf,acc[ts],0,0,0);
    }
  }
#pragma unroll
  for(int ts=0;ts<4;ts++){
    int jc = ct*64 + ts*16 + lr;
    if(jc>=Cc) continue;
    float bb = fb[jc];
#pragma unroll
    for(int reg=0;reg<4;reg++){
      int m = w*16 + kq*4 + reg;
      size_t o = (size_t)(grow0+m)*Cc + jc;
      out[o] = xm[o] + acc[ts][reg] + bb;
    }
  }
}

extern "C" void kernel_launch(void* const* d_in, const int* in_sizes, int n_in,
                              void* d_out, int out_size, void* d_ws, size_t ws_size,
                              hipStream_t stream){
  (void)in_sizes; (void)n_in; (void)out_size; (void)ws_size;
  const float* x     = (const float*)d_in[0];
  const float* ln1_g = (const float*)d_in[3];
  const float* ln1_b = (const float*)d_in[4];
  const float* band_w= (const float*)d_in[5];
  const float* band_b= (const float*)d_in[6];
  const float* gate_w= (const float*)d_in[7];
  const float* gate_b= (const float*)d_in[8];
  const float* cab_w1= (const float*)d_in[9];
  const float* cab_b1= (const float*)d_in[10];
  const float* cab_w2= (const float*)d_in[11];
  const float* cab_b2= (const float*)d_in[12];
  const float* eca_w = (const float*)d_in[13];
  const float* plkw  = (const float*)d_in[14];
  const float* dwc_w1= (const float*)d_in[15];
  const float* dwc_b1= (const float*)d_in[16];
  const float* dwc_w2= (const float*)d_in[17];
  const float* dwc_b2= (const float*)d_in[18];
  const float* aggr_w= (const float*)d_in[19];
  const float* aggr_b= (const float*)d_in[20];
  const float* ln2_g = (const float*)d_in[21];
  const float* ln2_b = (const float*)d_in[22];
  const float* fc1_w = (const float*)d_in[23];
  const float* fc1_b = (const float*)d_in[24];
  const float* dw_w  = (const float*)d_in[25];
  const float* dw_b  = (const float*)d_in[26];
  const float* fc2_w = (const float*)d_in[27];
  const float* fc2_b = (const float*)d_in[28];

  float* ws = (float*)d_ws;
  // persistent region
  float* xm   = ws;                      // 13,271,040
  float* m1   = ws + 13271040;           // 1,440
  float* gates= ws + 13272480;           // 32
  float* dkb  = ws + 13272512;           // 1,152
  float* biasb= ws + 13273664;           // 1,440
  float* gapb = ws + 13275104;           // 1,440
  float* svec = ws + 13276544;           // 1,440 -> 13,277,984
  ushort* Wg1 = (ushort*)(ws + 13278000);// 110,592 sh -> 13,333,296
  ushort* Wg2 = (ushort*)(ws + 13333296);// 110,592 sh -> 13,388,592
  ushort* Wp1 = (ushort*)(ws + 13388592);// 147,456 sh -> 13,462,320
  ushort* Wp2 = (ushort*)(ws + 13462320);//  73,728 sh -> 13,499,184
  ushort* Wpa = (ushort*)(ws + 13499184);//  36,864 sh -> 13,517,616
  ushort* Bfx = (ushort*)(ws + 13517616);//  10,752 sh -> 13,522,992
  ushort* Tmw = (ushort*)(ws + 13522992);//  18,432 sh -> 13,532,208
  ushort* Bix = (ushort*)(ws + 13532208);//  12,288 sh -> 13,538,352
  ushort* Wbk = (ushort*)(ws + 13538352);// 110,592 sh -> 13,593,648
  float* big  = ws + 13593728;
  // phase 1 inside big:
  float* ximg = big;                     // 13,271,040
  float* spec = big + 13271040;          // 13,547,520 (xfft in first 9216 of each 9408 plane)
  ushort* mid = (ushort*)(big + 26818560); // 4,423,680 bf16
  float* attn = big + 29030400;          // 1,179,648 -> phase-1 top = 30,210,048
  float* ycab = spec;                    // reuse (stride 9216), spec dead after conv1
  // phase 2 aliases big:
  ushort* t1  = (ushort*)big;                    // 26,542,080 float slots
  float*  reg2= big + 26542080;
  ushort* xn2 = (ushort*)reg2;                   // (ln2->fc1)
  ushort* pgb = (ushort*)reg2;                   // (dwglu->fc2)
  // total ≈ 13,593,728 + 39,813,120 floats ≈ 213.6 MB

  k_packw<<<576,256,0,stream>>>(cab_w1, cab_w2, fc1_w, fc2_w, aggr_w, band_w,
                                Wg1, Wg2, Wp1, Wp2, Wpa, Wbk, Bfx, Tmw, Bix);
  k_ln1<<<2304,256,0,stream>>>(x, ln1_g, ln1_b, ximg);
  k_plane_mean<<<1440,256,0,stream>>>(ximg, m1);
  k_small<<<1,64,0,stream>>>(m1, gate_w, gate_b, dwc_w1, dwc_b1, dwc_w2, dwc_b2, band_b, gates, dkb, biasb);
  k_fft_fwd<<<1440,256,0,stream>>>(ximg, Bfx, Tmw, spec);
  k_bandmixm<<<dim3(147,Bb),256,0,stream>>>(spec, Wbk, gates);
  k_fft_inv<<<1440,256,0,stream>>>(spec, ximg, biasb, Tmw, Bix);
  k_cab<float, Cc, 192, 6, true,  true ><<<dim3(48,1,Bb),256,0,stream>>>(spec, Wg1, cab_b1, (void*)mid, CRr, SPL);
  k_cab<ushort, CRr, 64, 2, false, false><<<dim3(48,3,Bb),256,0,stream>>>(mid, Wg2, cab_b2, (void*)ycab, Cc, HWn);
  k_plane_mean<<<1440,256,0,stream>>>(ycab, gapb);
  k_eca<<<6,256,0,stream>>>(gapb, eca_w, svec);
  k_plk<<<dim3(9,PD,Bb),256,0,stream>>>(ximg, plkw, dkb, attn);
  k_aggrm<<<dim3(1152,3),256,0,stream>>>(x, attn, ximg, ycab, Wpa, aggr_b, svec, xm);
  k_ln2<<<18432,256,0,stream>>>(xm, ln2_g, ln2_b, xn2);
  k_fc1<<<1152,256,0,stream>>>(xn2, Wp1, fc1_b, t1);
  k_dwglu<<<dim3(9,HID,Bb),256,0,stream>>>((const bf16*)t1, dw_w, dw_b, (bf16*)pgb);
  k_fc2<<<dim3(1152,3),256,0,stream>>>(pgb, xm, Wp2, fc2_b, (float*)d_out);
}

// Round 9
// 1402.672 us; speedup vs baseline: 2.5896x; 1.0435x over previous
//
#include <hip/hip_runtime.h>
#include <hip/hip_bf16.h>
#include <math.h>
#include <type_traits>

#define Bb 8
#define Cc 180
#define HWn 9216
#define PD 16
#define CRr 60
#define HID 360
#define H2 720
#define NF 49
#define SPL 9408   /* spectral plane stride in floats: 96*49*2 */
#define CONV_SCALE 0.01f
#define FFT_RES 0.15f
#define EPSLN 1e-5f
#define TWOPI_96 0.06544984694978735f

typedef __hip_bfloat16 bf16;
typedef unsigned short ushort;
typedef __attribute__((ext_vector_type(8))) short s8v;   // 8 bf16 (4 VGPRs) MFMA A/B frag
typedef __attribute__((ext_vector_type(4))) float f4v;   // MFMA C/D frag

__device__ __forceinline__ float geluf(float x){ return 0.5f*x*(1.0f+erff(x*0.7071067811865476f)); }
__device__ __forceinline__ float sigm(float x){ return 1.0f/(1.0f+expf(-x)); }
__device__ __forceinline__ short f2bf(float f){
  unsigned u = __float_as_uint(f);
  u += 0x7fff + ((u>>16)&1);
  return (short)(u>>16);
}
__device__ __forceinline__ float wredsum(float v){
#pragma unroll
  for(int m=1;m<64;m<<=1) v += __shfl_xor(v,m,64);
  return v;
}

// ---------------- LN1 + transpose to (B,C,H,W) ----------------
__global__ void __launch_bounds__(256) k_ln1(const float* __restrict__ x, const float* __restrict__ g,
                      const float* __restrict__ be, float* __restrict__ ximg){
  __shared__ float sb[32*Cc];
  int b = blockIdx.x / 288;
  int n0 = (blockIdx.x % 288) * 32;
  int t = threadIdx.x;
  const float* src = x + (size_t)(b*HWn + n0)*Cc;
  for(int i=t;i<32*Cc;i+=256) sb[i]=src[i];
  __syncthreads();
  int w = t>>6, lane = t&63;
  for(int pi=0; pi<8; ++pi){
    int p = w*8+pi;
    float s=0.f, sq=0.f;
    for(int e=lane;e<Cc;e+=64){ float v=sb[p*Cc+e]; s+=v; sq+=v*v; }
    s = wredsum(s); sq = wredsum(sq);
    float mean = s*(1.0f/180.0f);
    float var = sq*(1.0f/180.0f) - mean*mean;
    float rstd = rsqrtf(var + EPSLN);
    for(int e=lane;e<Cc;e+=64){ float v=sb[p*Cc+e]; sb[p*Cc+e] = (v-mean)*rstd*g[e]+be[e]; }
  }
  __syncthreads();
  for(int i=t;i<32*Cc;i+=256){
    int c = i/32, p = i%32;
    ximg[(size_t)(b*Cc+c)*HWn + n0 + p] = sb[p*Cc+c];
  }
}

// ---------------- plane mean (9216 -> 1) ----------------
__global__ void __launch_bounds__(256) k_plane_mean(const float* __restrict__ in, float* __restrict__ out){
  __shared__ float red[4];
  int pl = blockIdx.x; int t = threadIdx.x;
  const float* p = in + (size_t)pl*HWn;
  float s=0.f;
  for(int i=t;i<HWn;i+=256) s+=p[i];
  s = wredsum(s);
  if((t&63)==0) red[t>>6]=s;
  __syncthreads();
  if(t==0) out[pl] = (red[0]+red[1]+red[2]+red[3]) * (1.0f/9216.0f);
}

// ---------------- small: gates, hdn->dk, fft bias ----------------
__global__ void k_small(const float* __restrict__ m1, const float* __restrict__ gate_w,
   const float* __restrict__ gate_b, const float* __restrict__ dwc_w1, const float* __restrict__ dwc_b1,
   const float* __restrict__ dwc_w2, const float* __restrict__ dwc_b2, const float* __restrict__ band_b,
   float* __restrict__ gates, float* __restrict__ dkb, float* __restrict__ biasb){
  int b = threadIdx.x;
  if(b>=Bb) return;
  const float* m = m1 + b*Cc;
  float gv[3];
  for(int k=0;k<3;k++){ float a=gate_b[k]; for(int c=0;c<Cc;c++) a+=m[c]*gate_w[k*Cc+c]; gv[k]=sigm(a);}
  float e0=expf(gv[0]), e1=expf(gv[1]), e2=expf(gv[2]); float inv=1.0f/(e0+e1+e2);
  float g0=e0*inv,g1=e1*inv,g2=e2*inv;
  gates[b*3+0]=g0; gates[b*3+1]=g1; gates[b*3+2]=g2;
  float hd[8];
  for(int j=0;j<8;j++){ float a=dwc_b1[j]; for(int c=0;c<PD;c++) a+=m[c]*dwc_w1[j*PD+c]; hd[j]=geluf(a);}
  for(int i=0;i<144;i++){ float a=dwc_b2[i]; for(int j=0;j<8;j++) a+=hd[j]*dwc_w2[i*8+j]; dkb[b*144+i]=a; }
  for(int d=0;d<Cc;d++) biasb[b*Cc+d] = g0*band_b[0*Cc+d]+g1*band_b[1*Cc+d]+g2*band_b[2*Cc+d];
}

// ------- pack weights to bf16 + DFT twiddle matrices -------
__global__ void __launch_bounds__(256) k_packw(const float* __restrict__ w1, const float* __restrict__ w2,
    const float* __restrict__ fw1, const float* __restrict__ fw2, const float* __restrict__ aw,
    const float* __restrict__ bw,
    ushort* __restrict__ Wg1, ushort* __restrict__ Wg2, ushort* __restrict__ Wp1,
    ushort* __restrict__ Wp2, ushort* __restrict__ Wpa, ushort* __restrict__ Wbk,
    ushort* __restrict__ Bfx, ushort* __restrict__ Tm, ushort* __restrict__ Bix){
  int t = blockIdx.x*256 + threadIdx.x;
  if(t < 64*9*192){
    int co = t/(9*192); int rem = t%(9*192); int tap = rem/192; int ci = rem%192;
    float v = (co<CRr && ci<Cc) ? w1[((size_t)(co*Cc+ci))*9 + tap] : 0.f;
    Wg1[t] = (ushort)f2bf(v);
  }
  if(t < 192*9*64){
    int co = t/(9*64); int rem = t%(9*64); int tap = rem/64; int ci = rem%64;
    float v = (co<Cc && ci<CRr) ? w2[((size_t)(co*CRr+ci))*9 + tap] : 0.f;
    Wg2[t] = (ushort)f2bf(v);
  }
  if(t < 768*192){
    int j=t/192, k=t%192;
    Wp1[t] = (ushort)f2bf((j<H2 && k<Cc)? fw1[(size_t)j*Cc+k] : 0.f);
  }
  if(t < 192*384){
    int j=t/384, k=t%384;
    Wp2[t] = (ushort)f2bf((j<Cc && k<HID)? fw2[(size_t)j*HID+k] : 0.f);
  }
  if(t < 192*192){
    int j=t/192, k=t%192;
    Wpa[t] = (ushort)f2bf((j<Cc && k<Cc)? aw[(size_t)j*Cc+k] : 0.f);
  }
  // Wbk[3][192 d][192 c] : band channel-mix weights
  if(t < 3*192*192){
    int k=t/(192*192); int rem=t%(192*192); int j=rem/192, c=rem%192;
    Wbk[t] = (ushort)f2bf((j<Cc && c<Cc)? bw[((size_t)k*Cc + j)*Cc + c] : 0.f);
  }
  // Bfx[112 n][96 k] : fwd-x twiddle (ortho 1/96 folded)
  if(t < 112*96){
    int n=t/96, k=t%96;
    float v=0.f;
    if(n<98){
      int kx=n>>1; int m=(k*kx)%96; float th=(float)m*TWOPI_96;
      v = ((n&1)? -sinf(th) : cosf(th)) * (1.0f/96.0f);
    }
    Bfx[t] = (ushort)f2bf(v);
  }
  // Tm[96 r][192 k] : y-transform twiddle (shared fwd/inv)
  if(t < 96*192){
    int r=t/192, k=t%192;
    int c=k>>1; int m=(r*c)%96; float th=(float)m*TWOPI_96;
    float v = (k&1)? sinf(th) : cosf(th);
    Tm[t] = (ushort)f2bf(v);
  }
  // Bix[96 n][128 k] : inv-x twiddle (wgt and 1/96 folded)
  if(t < 96*128){
    int n=t/128, k=t%128;
    float v=0.f;
    if(k<98){
      int kx=k>>1; float wgt=(kx==0||kx==48)?1.0f:2.0f;
      int m=(n*kx)%96; float th=(float)m*TWOPI_96;
      v = ((k&1)? -wgt*sinf(th) : wgt*cosf(th)) * (1.0f/96.0f);
    }
    Bix[t] = (ushort)f2bf(v);
  }
}

// ------- pack plk + per-batch dynamic depthwise into Wdk[b][co][13ky][7kxp][2tl*16ci] bf16 -------
__global__ void __launch_bounds__(256) k_packplk(const float* __restrict__ plk,
    const float* __restrict__ dkb, ushort* __restrict__ Wdk){
  int t = blockIdx.x*256 + threadIdx.x;
  if(t >= Bb*PD*13*7*32) return;
  int k = t & 31; int rest = t >> 5;
  int kxp = rest % 7; rest /= 7;
  int ky = rest % 13; rest /= 13;
  int co = rest % PD; int b = rest / PD;
  int tl = k >> 4, ci = k & 15;
  int kx = kxp*2 + tl;
  float v = 0.f;
  if(kx < 13){
    v = plk[((size_t)(co*PD+ci)*13 + ky)*13 + kx];
    if(ci==co && ky>=5 && ky<8 && kx>=5 && kx<8)
      v += dkb[b*144 + co*9 + (ky-5)*3 + (kx-5)];
  }
  Wdk[t] = (ushort)f2bf(v);
}

// ---------------- fused forward 2D rDFT (per plane), MFMA ----------------
__global__ void __launch_bounds__(256) k_fft_fwd(const float* __restrict__ ximg,
    const ushort* __restrict__ Bfx, const ushort* __restrict__ Tm, float* __restrict__ S){
  __shared__ __align__(16) short Asi[96*104];
  __shared__ __align__(16) short Bv[112*200];
  int bc = blockIdx.x; int t = threadIdx.x;
  int w=t>>6, lane=t&63, kq=lane>>4, lr=lane&15;
  const float* src = ximg + (size_t)bc*HWn;
  for(int i=t;i<1152;i+=256){
    int y=i/12, seg=i%12;
    float4 v0 = *(const float4*)(src + y*96 + seg*8);
    float4 v1 = *(const float4*)(src + y*96 + seg*8 + 4);
    s8v pk;
    pk[0]=f2bf(v0.x); pk[1]=f2bf(v0.y); pk[2]=f2bf(v0.z); pk[3]=f2bf(v0.w);
    pk[4]=f2bf(v1.x); pk[5]=f2bf(v1.y); pk[6]=f2bf(v1.z); pk[7]=f2bf(v1.w);
    *(s8v*)&Asi[y*104+seg*8] = pk;
  }
  __syncthreads();
  // stage1: V[y][n] = img @ Bfx^T ; write (V, -i*V) into Bv[n][2y,2y+1]
  for(int tile=w; tile<42; tile+=4){
    int mt=tile/7, nt=tile%7;
    f4v acc={};
#pragma unroll
    for(int ks=0;ks<3;ks++){
      s8v af = *(const s8v*)&Asi[(mt*16+lr)*104 + kq*8 + ks*32];
      s8v bf = *(const s8v*)&Bfx[(size_t)(nt*16+lr)*96 + kq*8 + ks*32];
      acc = __builtin_amdgcn_mfma_f32_16x16x32_bf16(af,bf,acc,0,0,0);
    }
    int n = nt*16+lr;
    float sgn = (n&1)? -1.f : 1.f;
#pragma unroll
    for(int reg=0;reg<4;reg++){
      int y = mt*16+kq*4+reg;
      float v = acc[reg];
      float p = __shfl_xor(v,1);
      unsigned pack = ((unsigned)(ushort)f2bf(sgn*p)<<16) | (ushort)(unsigned short)f2bf(v);
      *(unsigned*)&Bv[n*200 + 2*y] = pack;
    }
  }
  __syncthreads();
  // stage2: X[ky][n] = Tm @ Bv^T -> global fp32 spec plane
  float* dst = S + (size_t)bc*SPL;
  for(int tile=w; tile<42; tile+=4){
    int mt=tile/7, nt=tile%7;
    f4v acc={};
#pragma unroll
    for(int ks=0;ks<6;ks++){
      s8v af = *(const s8v*)&Tm[(size_t)(mt*16+lr)*192 + kq*8 + ks*32];
      s8v bf = *(const s8v*)&Bv[(nt*16+lr)*200 + kq*8 + ks*32];
      acc = __builtin_amdgcn_mfma_f32_16x16x32_bf16(af,bf,acc,0,0,0);
    }
    int n = nt*16+lr;
    if(n<98){
#pragma unroll
      for(int reg=0;reg<4;reg++){
        int ky = mt*16+kq*4+reg;
        dst[ky*98 + n] = acc[reg];
      }
    }
  }
}

// ---------------- fused inverse 2D rDFT + combine (per plane), MFMA, in-place ----------------
__global__ void __launch_bounds__(256) k_fft_inv(float* __restrict__ S, const float* __restrict__ ximg,
    const float* __restrict__ biasb, const ushort* __restrict__ Tm, const ushort* __restrict__ Bix){
  __shared__ __align__(16) short Bv[112*200];
  __shared__ __align__(16) short T2s[96*136];
  int bd = blockIdx.x; int t=threadIdx.x;
  int w=t>>6, lane=t&63, kq=lane>>4, lr=lane&15;
  int b = bd/Cc, d = bd%Cc;
  float* pl = S + (size_t)bd*SPL;
  // zero Bv rows n=98..111 and T2s cols 112..135
  for(int i=t;i<1400;i+=256) ((unsigned*)&Bv[98*200])[i] = 0u;
  for(int i=t;i<1152;i+=256){ int y=i/12, c=i%12; *(unsigned*)&T2s[y*136+112+c*2] = 0u; }
  // build Bv from Yhat with +i twist (partner via shfl)
  for(int i=t;i<9408;i+=256){
    float v = pl[i];
    float p = __shfl_xor(v,1);
    int ky = i/98, n = i%98;
    float tw = (n&1)? p : -p;
    unsigned pack = ((unsigned)(ushort)f2bf(tw)<<16) | (ushort)(unsigned short)f2bf(v);
    *(unsigned*)&Bv[n*200 + 2*ky] = pack;
  }
  __syncthreads();
  // stage1: T2[y][n] = Tm @ Bv^T -> LDS
  for(int tile=w; tile<42; tile+=4){
    int mt=tile/7, nt=tile%7;
    f4v acc={};
#pragma unroll
    for(int ks=0;ks<6;ks++){
      s8v af = *(const s8v*)&Tm[(size_t)(mt*16+lr)*192 + kq*8 + ks*32];
      s8v bf = *(const s8v*)&Bv[(nt*16+lr)*200 + kq*8 + ks*32];
      acc = __builtin_amdgcn_mfma_f32_16x16x32_bf16(af,bf,acc,0,0,0);
    }
    int n = nt*16+lr;
#pragma unroll
    for(int reg=0;reg<4;reg++){
      int y = mt*16+kq*4+reg;
      T2s[y*136 + n] = f2bf(acc[reg]);
    }
  }
  __syncthreads();
  // stage2: out[y][xx] = T2 @ Bix^T ; combine with ximg + bias, in-place
  float bias = biasb[b*Cc+d];
  const float* xs = ximg + (size_t)bd*HWn;
  for(int tile=w; tile<36; tile+=4){
    int mt=tile/6, nt=tile%6;
    f4v acc={};
#pragma unroll
    for(int ks=0;ks<4;ks++){
      s8v af = *(const s8v*)&T2s[(mt*16+lr)*136 + kq*8 + ks*32];
      s8v bf = *(const s8v*)&Bix[(size_t)(nt*16+lr)*128 + kq*8 + ks*32];
      acc = __builtin_amdgcn_mfma_f32_16x16x32_bf16(af,bf,acc,0,0,0);
    }
    int xx = nt*16+lr;
#pragma unroll
    for(int reg=0;reg<4;reg++){
      int y = mt*16+kq*4+reg;
      int o = y*96+xx;
      pl[o] = xs[o] + FFT_RES*(acc[reg] + bias);
    }
  }
}

// ---------------- band channel mix as MFMA GEMM, IN-PLACE, per-column band select ----------------
__global__ void __launch_bounds__(256) k_bandmixm(float* __restrict__ S, const ushort* __restrict__ Wbk,
                          const float* __restrict__ gates){
  __shared__ __align__(16) short Bs[64*200];
  int f2base = blockIdx.x*64;
  int b = blockIdx.y;
  int t = threadIdx.x;
  int w=t>>6, lane=t&63, kq=lane>>4, lr=lane&15;
  // stage X-tile transposed: Bs[r=f2local][c], bf16, K padded to 192
  for(int i=t;i<8*192;i+=256){
    int rblk=i&7, kk=i>>3;
    int r0=rblk*8;
    if(kk<Cc){
      const float* src = S + (size_t)(b*Cc+kk)*SPL + f2base + r0;
      float4 v0 = *(const float4*)src;
      float4 v1 = *(const float4*)(src+4);
      Bs[(r0+0)*200+kk]=f2bf(v0.x); Bs[(r0+1)*200+kk]=f2bf(v0.y);
      Bs[(r0+2)*200+kk]=f2bf(v0.z); Bs[(r0+3)*200+kk]=f2bf(v0.w);
      Bs[(r0+4)*200+kk]=f2bf(v1.x); Bs[(r0+5)*200+kk]=f2bf(v1.y);
      Bs[(r0+6)*200+kk]=f2bf(v1.z); Bs[(r0+7)*200+kk]=f2bf(v1.w);
    } else {
#pragma unroll
      for(int q=0;q<8;q++) Bs[(r0+q)*200+kk]=0;
    }
  }
  // block-wide band mask (64 cols, one per lane; all waves compute same)
  unsigned bmask;
  {
    int col = f2base + lane;
    int ky = col/98, n = col%98, kx = n>>1;
    float yy = -1.0f + 2.0f*(float)ky/95.0f;
    float xxf = (float)kx/48.0f;
    float rr = sqrtf(yy*yy+xxf*xxf);
    int k = (rr<=0.25f)?0:((rr<=0.6f)?1:2);
    unsigned m = 1u<<k;
#pragma unroll
    for(int s=1;s<64;s<<=1) m |= __shfl_xor(m,s);
    bmask = m;
  }
  // per-lane band/gate for my 4 C-columns (f2local = w*16 + kq*4 + reg)
  int kb[4]; float gv[4];
#pragma unroll
  for(int reg=0;reg<4;reg++){
    int col = f2base + w*16 + kq*4 + reg;
    int ky = col/98, n = col%98, kx = n>>1;
    float yy = -1.0f + 2.0f*(float)ky/95.0f;
    float xxf = (float)kx/48.0f;
    float rr = sqrtf(yy*yy+xxf*xxf);
    kb[reg] = (rr<=0.25f)?0:((rr<=0.6f)?1:2);
    gv[reg] = gates[b*3+kb[reg]];
  }
  __syncthreads();
  s8v af[6];
#pragma unroll
  for(int k6=0;k6<6;k6++) af[k6] = *(const s8v*)&Bs[(w*16+lr)*200 + kq*8 + k6*32];
  float res[12][4];
  for(int k=0;k<3;k++){
    if(!(bmask&(1u<<k))) continue;
    for(int ts=0;ts<12;ts++){
      f4v acc={};
#pragma unroll
      for(int k6=0;k6<6;k6++){
        s8v wf = *(const s8v*)&Wbk[((size_t)(k*192 + ts*16+lr))*192 + kq*8 + k6*32];
        acc = __builtin_amdgcn_mfma_f32_16x16x32_bf16(af[k6],wf,acc,0,0,0);
      }
#pragma unroll
      for(int reg=0;reg<4;reg++) if(kb[reg]==k) res[ts][reg]=gv[reg]*acc[reg];
    }
  }
  // write back: each lane stores float4 (4 consecutive f2) per d-row
#pragma unroll
  for(int ts=0;ts<12;ts++){
    int d = ts*16+lr;
    if(d<Cc){
      float4 o; o.x=res[ts][0]; o.y=res[ts][1]; o.z=res[ts][2]; o.w=res[ts][3];
      *(float4*)(S + (size_t)(b*Cc+d)*SPL + f2base + w*16 + kq*4) = o;
    }
  }
}

// ---------------- CAB 3x3 conv as implicit-GEMM MFMA ----------------
template<typename TIN, int CIN, int KPAD, int NCHUNK, bool ACT, bool OUTBF>
__global__ void __launch_bounds__(256) k_cab(const TIN* __restrict__ xin, const ushort* __restrict__ Wg,
    const float* __restrict__ bias, void* __restrict__ outv, int COUT, int istride){
  __shared__ short As[4*98*36];   // 28224 B; also reused for epilogue transpose
  int y0 = blockIdx.x*2;
  int ct = blockIdx.y;
  int b  = blockIdx.z;
  int t = threadIdx.x;
  int w = t>>6, lane = t&63, kq = lane>>4, lr = lane&15;
  f4v acc[3][4] = {};
  for(int ch=0; ch<NCHUNK; ++ch){
    int ci0 = ch*32;
    __syncthreads();
    for(int i=t;i<4*98*32;i+=256){
      int ci = i/392; int rem = i%392; int row = rem/98; int pxh = rem%98;
      int gy = y0 - 1 + row; int px = pxh - 1;
      int cig = ci0 + ci;
      short sv = 0;
      if((unsigned)gy<96u && (unsigned)px<96u && cig<CIN){
        if constexpr (std::is_same<TIN,float>::value)
          sv = f2bf(xin[(size_t)(b*CIN+cig)*istride + gy*96 + px]);
        else
          sv = (short)xin[(size_t)(b*CIN+cig)*istride + gy*96 + px];
      }
      As[(row*98+pxh)*36 + ci] = sv;
    }
    __syncthreads();
#pragma unroll
    for(int tap=0; tap<9; ++tap){
      int ky = tap/3, kx = tap%3;
      s8v bfr[4];
#pragma unroll
      for(int ts=0;ts<4;ts++)
        bfr[ts] = *(const s8v*)&Wg[((size_t)(ct*64 + ts*16 + lr)*9 + tap)*KPAD + ci0 + kq*8];
#pragma unroll
      for(int s=0;s<3;s++){
        int mt = w + 4*s;
        int orow = mt/6, px = (mt%6)*16 + lr;
        s8v af = *(const s8v*)&As[((orow+ky)*98 + px + kx)*36 + kq*8];
#pragma unroll
        for(int ts=0;ts<4;ts++)
          acc[s][ts] = __builtin_amdgcn_mfma_f32_16x16x32_bf16(af, bfr[ts], acc[s][ts], 0,0,0);
      }
    }
  }
  // epilogue
  if(OUTBF){
    __syncthreads();
    short* cT = As;   // [64 co][200] bf16
#pragma unroll
    for(int ts=0;ts<4;ts++){
      int cog = ct*64 + ts*16 + lr;
      float bb = (cog<COUT)? bias[cog] : 0.f;
#pragma unroll
      for(int s=0;s<3;s++){
#pragma unroll
        for(int reg=0;reg<4;reg++){
          int px = (w+4*s)*16 + kq*4 + reg;
          float v = acc[s][ts][reg] + bb;
          if(ACT) v = geluf(v);
          cT[(ts*16+lr)*200 + px] = f2bf(v);
        }
      }
    }
    __syncthreads();
    ushort* out = (ushort*)outv;
    for(int i=t;i<64*192;i+=256){
      int co=i/192, px=i%192;
      int cog = ct*64+co;
      if(cog<COUT) out[(size_t)(b*COUT+cog)*HWn + y0*96 + px] = (ushort)cT[co*200+px];
    }
  } else {
    float* cF = (float*)As;  // [32 co][200] fp32 per half
    float* out = (float*)outv;
    for(int h=0;h<2;h++){
      __syncthreads();
#pragma unroll
      for(int tt=0;tt<2;tt++){
        int ts = 2*h+tt;
        int cog = ct*64 + ts*16 + lr;
        float bb = (cog<COUT)? bias[cog] : 0.f;
#pragma unroll
        for(int s=0;s<3;s++){
#pragma unroll
          for(int reg=0;reg<4;reg++){
            int px = (w+4*s)*16 + kq*4 + reg;
            cF[(tt*16+lr)*200 + px] = acc[s][ts][reg] + bb;
          }
        }
      }
      __syncthreads();
      for(int i=t;i<32*192;i+=256){
        int co=i/192, px=i%192;
        int cog = ct*64 + h*32 + co;
        if(cog<COUT) out[(size_t)(b*COUT+cog)*HWn + y0*96 + px] = cF[co*200+px];
      }
    }
  }
}

// ---------------- ECA ----------------
__global__ void k_eca(const float* __restrict__ gap, const float* __restrict__ ew, float* __restrict__ s){
  int i = blockIdx.x*blockDim.x + threadIdx.x;
  if(i>=Bb*Cc) return;
  int b=i/Cc, c=i%Cc;
  float z=0.f;
  for(int j=0;j<5;j++){ int cc=c-2+j; if(cc>=0&&cc<Cc) z+=gap[b*Cc+cc]*ew[j]; }
  s[i]=sigm(z);
}

// ------- plk 13x13 + fused dynamic dw3x3 as implicit-GEMM MFMA (tap-pair K=32) -------
__global__ void __launch_bounds__(256) k_plkm(const float* __restrict__ ximg,
    const ushort* __restrict__ Wdk, float* __restrict__ attn){
  __shared__ short As[15*109*20];   // 65,400 B; pxh stride 20 shorts (40B) -> conflict-free
  int y0 = blockIdx.x*3;
  int b  = blockIdx.y;
  int t = threadIdx.x;
  int w = t>>6, lane = t&63, kq = lane>>4, lr = lane&15;
  // stage: As[row][pxh][ci] ; row = y0-6 .. y0+8 ; pxh-6 = px -6..102 (col 108 zero)
  for(int i=t;i<PD*15*109;i+=256){
    int ci = i/(15*109); int rem = i%(15*109);
    int row = rem/109, pxh = rem%109;
    int gy = y0 + row - 6, gx = pxh - 6;
    short sv = 0;
    if((unsigned)gy<96u && (unsigned)gx<96u)
      sv = f2bf(ximg[(size_t)(b*Cc+ci)*HWn + gy*96 + gx]);
    As[(row*109+pxh)*20 + ci] = sv;
  }
  __syncthreads();
  f4v acc[5] = {};
  const ushort* wb = Wdk + ((size_t)(b*PD+lr)*13)*7*32 + kq*8;
  for(int ky=0;ky<13;ky++){
#pragma unroll
    for(int kxp=0;kxp<7;kxp++){
      s8v bfr = *(const s8v*)(wb + (ky*7+kxp)*32);
      int ti=0;
      for(int mt=w; mt<18; mt+=4, ti++){
        int yo = mt/6, o = (mt%6)*16;
        s8v af = *(const s8v*)&As[((yo+ky)*109 + o + lr + 2*kxp + (kq>>1))*20 + (kq&1)*8];
        acc[ti] = __builtin_amdgcn_mfma_f32_16x16x32_bf16(af, bfr, acc[ti], 0,0,0);
      }
    }
  }
  // epilogue: C col = lr = co ; rows = px (4 consecutive) -> float4 stores
  int ti=0;
  for(int mt=w; mt<18; mt+=4, ti++){
    int yo = mt/6, o = (mt%6)*16 + kq*4;
    float4 ov; ov.x=acc[ti][0]; ov.y=acc[ti][1]; ov.z=acc[ti][2]; ov.w=acc[ti][3];
    *(float4*)&attn[(size_t)(b*PD+lr)*HWn + (y0+yo)*96 + o] = ov;
  }
}

// ---------------- aggr as MFMA GEMM + residual + conv_x scale -> xm (B,N,C) ----------------
__global__ void __launch_bounds__(256) k_aggrm(const float* __restrict__ x, const float* __restrict__ attn,
   const float* __restrict__ ximg, const float* __restrict__ ycab, const ushort* __restrict__ Wpa,
   const float* __restrict__ aggb, const float* __restrict__ svec, float* __restrict__ xm){
  __shared__ short smem[64*200];   // As ; reused as cF (fp32 64x68) in epilogue
  short* As = smem;
  int rt = blockIdx.x, ct = blockIdx.y;
  int t = threadIdx.x;
  int w = t>>6, lane = t&63, kq = lane>>4, lr = lane&15;
  int grow0 = rt*64; int b = grow0/HWn; int n0 = grow0%HWn;
  for(int i=t;i<8*192;i+=256){
    int rblk=i&7, kk=i>>3;
    int r0=rblk*8;
    if(kk<Cc){
      const float* src = (kk<PD)? attn + (size_t)(b*PD+kk)*HWn + n0 + r0
                                : ximg + (size_t)(b*Cc+kk)*HWn + n0 + r0;
      float4 v0 = *(const float4*)src;
      float4 v1 = *(const float4*)(src+4);
      As[(r0+0)*200+kk]=f2bf(v0.x); As[(r0+1)*200+kk]=f2bf(v0.y);
      As[(r0+2)*200+kk]=f2bf(v0.z); As[(r0+3)*200+kk]=f2bf(v0.w);
      As[(r0+4)*200+kk]=f2bf(v1.x); As[(r0+5)*200+kk]=f2bf(v1.y);
      As[(r0+6)*200+kk]=f2bf(v1.z); As[(r0+7)*200+kk]=f2bf(v1.w);
    } else {
#pragma unroll
      for(int q=0;q<8;q++) As[(r0+q)*200+kk]=0;
    }
  }
  __syncthreads();
  f4v acc[4]={};
  int arow=(w*16+lr)*200 + kq*8;
#pragma unroll
  for(int k0=0;k0<192;k0+=32){
    s8v af = *(const s8v*)&As[arow+k0];
#pragma unroll
    for(int ts=0;ts<4;ts++){
      s8v wf = *(const s8v*)&Wpa[(size_t)(ct*64+ts*16+lr)*192 + kq*8 + k0];
      acc[ts]=__builtin_amdgcn_mfma_f32_16x16x32_bf16(af,wf,acc[ts],0,0,0);
    }
  }
  __syncthreads();
  float* cF = (float*)smem;
#pragma unroll
  for(int ts=0;ts<4;ts++){
    int j = ts*16+lr;
    int jc = ct*64 + j;
    float bb=0.f, sv=0.f;
    if(jc<Cc){ bb=aggb[jc]; sv=CONV_SCALE*svec[b*Cc+jc]; }
    const float* yrow = ycab + ((jc<Cc)? (size_t)(b*Cc+jc)*HWn + n0 : 0);
#pragma unroll
    for(int reg=0;reg<4;reg++){
      int m = w*16 + kq*4 + reg;
      float v = 0.f;
      if(jc<Cc) v = acc[ts][reg] + bb + sv*yrow[m];
      cF[m*68+j] = v;
    }
  }
  __syncthreads();
  for(int i=t;i<64*64;i+=256){
    int m=i>>6, j=i&63;
    int jc=ct*64+j;
    if(jc<Cc){
      size_t o = (size_t)(grow0+m)*Cc + jc;
      xm[o] = x[o] + cF[m*68+j];
    }
  }
}

// ---------------- LN2 fused: stats + normalize + bf16 cast, K padded 180->192 ----------------
__global__ void __launch_bounds__(256) k_ln2(const float* __restrict__ xm, const float* __restrict__ g2,
    const float* __restrict__ b2, ushort* __restrict__ xn2){
  int w = (blockIdx.x*256 + threadIdx.x)>>6;
  int lane = threadIdx.x&63;
  const float* row = xm + (size_t)w*Cc;
  float s=0,sq=0;
  for(int e=lane;e<Cc;e+=64){ float v=row[e]; s+=v; sq+=v*v; }
  s=wredsum(s); sq=wredsum(sq);
  float m=s*(1.0f/180.0f); float v=sq*(1.0f/180.0f)-m*m;
  float rstd=rsqrtf(v+EPSLN);
  ushort* orow = xn2 + (size_t)w*192;
  for(int e=lane;e<192;e+=64){
    float val = (e<Cc)? (row[e]-m)*rstd*g2[e]+b2[e] : 0.f;
    orow[e] = (ushort)f2bf(val);
  }
}

// -------- fc1 MFMA, W direct from packed global, A frags in registers, ct loop --------
__global__ void __launch_bounds__(256) k_fc1(const ushort* __restrict__ xn2,
    const ushort* __restrict__ Wp, const float* __restrict__ fb, ushort* __restrict__ t1){
  __shared__ short cT[64*72];   // 9216 B epilogue transpose
  int rt = blockIdx.x;
  int t = threadIdx.x;
  int w = t>>6, lane = t&63, kq = lane>>4, lr = lane&15;
  int grow0 = rt*64;
  int bb_ = grow0/HWn, n0 = grow0%HWn;
  s8v af[6];
  const ushort* arow = xn2 + (size_t)(grow0 + w*16 + lr)*192 + kq*8;
#pragma unroll
  for(int k6=0;k6<6;k6++) af[k6] = *(const s8v*)(arow + k6*32);
  for(int ct=0; ct<12; ++ct){
    f4v acc[4]={};
#pragma unroll
    for(int k6=0;k6<6;k6++){
#pragma unroll
      for(int ts=0;ts<4;ts++){
        s8v wf = *(const s8v*)&Wp[(size_t)(ct*64+ts*16+lr)*192 + kq*8 + k6*32];
        acc[ts]=__builtin_amdgcn_mfma_f32_16x16x32_bf16(af[k6],wf,acc[ts],0,0,0);
      }
    }
    __syncthreads();
#pragma unroll
    for(int ts=0;ts<4;ts++){
      int j = ts*16+lr;
      int jc = ct*64+j;
      float bb = (jc<H2)? fb[jc] : 0.f;
#pragma unroll
      for(int reg=0;reg<4;reg++){
        int m = w*16 + kq*4 + reg;
        cT[j*72+m] = f2bf(acc[ts][reg]+bb);
      }
    }
    __syncthreads();
    for(int i=t;i<4096;i+=256){
      int j=i>>6, m=i&63;
      int jc=ct*64+j;
      if(jc<H2) t1[((size_t)(bb_*H2+jc))*HWn + n0 + m] = (ushort)cT[j*72+m];
    }
  }
}

// ---------------- depthwise 3x3 on t1 + GLU -> pg (B,360,HW) bf16 ----------------
__global__ void __launch_bounds__(256) k_dwglu(const bf16* __restrict__ t1, const float* __restrict__ dww,
    const float* __restrict__ dwb, bf16* __restrict__ pg){
  __shared__ float ta[34*34];
  __shared__ float tg[34*34];
  int tile_id=blockIdx.x; int c=blockIdx.y; int b=blockIdx.z;
  int ty0=(tile_id/3)*32, tx0=(tile_id%3)*32;
  int t=threadIdx.x;
  int px0=(t%16)*2, py0=(t/16)*2;
  for(int i=t;i<34*34;i+=256){
    int ly=i/34, lx=i%34; int gy=ty0+ly-1, gx=tx0+lx-1;
    bool ok=((unsigned)gy<96u&&(unsigned)gx<96u);
    ta[i]= ok? __bfloat162float(t1[((size_t)(b*H2+c)*96+gy)*96+gx]) :0.f;
    tg[i]= ok? __bfloat162float(t1[((size_t)(b*H2+c+HID)*96+gy)*96+gx]) :0.f;
  }
  __syncthreads();
  float wp[9],wg[9];
#pragma unroll
  for(int i=0;i<9;i++){ wp[i]=dww[c*9+i]; wg[i]=dww[(c+HID)*9+i]; }
  float bp=dwb[c], bg=dwb[c+HID];
#pragma unroll
  for(int oy=0;oy<2;oy++)
#pragma unroll
    for(int ox=0;ox<2;ox++){
      float p=bp,g=bg;
#pragma unroll
      for(int ky=0;ky<3;ky++)
#pragma unroll
        for(int kx=0;kx<3;kx++){
          p+=wp[ky*3+kx]*ta[(py0+oy+ky)*34+px0+ox+kx];
          g+=wg[ky*3+kx]*tg[(py0+oy+ky)*34+px0+ox+kx];
        }
      float val = p * g * sigm(g);
      pg[((size_t)(b*HID+c)*96 + ty0+py0+oy)*96 + tx0+px0+ox] = __float2bfloat16(val);
    }
}

// ---------------- fc2 MFMA + residual -> out (B,N,C); W direct, single K=384 pass ----------------
__global__ void __launch_bounds__(256) k_fc2(const ushort* __restrict__ pg, const float* __restrict__ xm,
    const ushort* __restrict__ Wp, const float* __restrict__ fb, float* __restrict__ out){
  __shared__ short As[64*392];   // 50176 B
  int rt = blockIdx.x, ct = blockIdx.y;
  int t = threadIdx.x;
  int w = t>>6, lane = t&63, kq = lane>>4, lr = lane&15;
  int grow0 = rt*64; int b = grow0/HWn; int n0 = grow0%HWn;
  for(int i=t;i<8*HID;i+=256){
    int rblk=i&7, kc=i>>3;
    int r0=rblk*8;
    s8v v = *(const s8v*)&pg[((size_t)(b*HID+kc))*HWn + n0 + r0];
#pragma unroll
    for(int q=0;q<8;q++) As[(r0+q)*392 + kc] = v[q];
  }
  for(int i=t;i<64*24;i+=256){
    int r=i/24, kk=i%24;
    As[r*392 + HID + kk] = 0;
  }
  __syncthreads();
  f4v acc[4]={};
  int arow=(w*16+lr)*392 + kq*8;
#pragma unroll
  for(int k0=0;k0<384;k0+=32){
    s8v af = *(const s8v*)&As[arow+k0];
#pragma unroll
    for(int ts=0;ts<4;ts++){
      s8v wf = *(const s8v*)&Wp[(size_t)(ct*64+ts*16+lr)*384 + kq*8 + k0];
      acc[ts]=__builtin_amdgcn_mfma_f32_16x16x32_bf16(af,wf,acc[ts],0,0,0);
    }
  }
#pragma unroll
  for(int ts=0;ts<4;ts++){
    int jc = ct*64 + ts*16 + lr;
    if(jc>=Cc) continue;
    float bb = fb[jc];
#pragma unroll
    for(int reg=0;reg<4;reg++){
      int m = w*16 + kq*4 + reg;
      size_t o = (size_t)(grow0+m)*Cc + jc;
      out[o] = xm[o] + acc[ts][reg] + bb;
    }
  }
}

extern "C" void kernel_launch(void* const* d_in, const int* in_sizes, int n_in,
                              void* d_out, int out_size, void* d_ws, size_t ws_size,
                              hipStream_t stream){
  (void)in_sizes; (void)n_in; (void)out_size; (void)ws_size;
  const float* x     = (const float*)d_in[0];
  const float* ln1_g = (const float*)d_in[3];
  const float* ln1_b = (const float*)d_in[4];
  const float* band_w= (const float*)d_in[5];
  const float* band_b= (const float*)d_in[6];
  const float* gate_w= (const float*)d_in[7];
  const float* gate_b= (const float*)d_in[8];
  const float* cab_w1= (const float*)d_in[9];
  const float* cab_b1= (const float*)d_in[10];
  const float* cab_w2= (const float*)d_in[11];
  const float* cab_b2= (const float*)d_in[12];
  const float* eca_w = (const float*)d_in[13];
  const float* plkw  = (const float*)d_in[14];
  const float* dwc_w1= (const float*)d_in[15];
  const float* dwc_b1= (const float*)d_in[16];
  const float* dwc_w2= (const float*)d_in[17];
  const float* dwc_b2= (const float*)d_in[18];
  const float* aggr_w= (const float*)d_in[19];
  const float* aggr_b= (const float*)d_in[20];
  const float* ln2_g = (const float*)d_in[21];
  const float* ln2_b = (const float*)d_in[22];
  const float* fc1_w = (const float*)d_in[23];
  const float* fc1_b = (const float*)d_in[24];
  const float* dw_w  = (const float*)d_in[25];
  const float* dw_b  = (const float*)d_in[26];
  const float* fc2_w = (const float*)d_in[27];
  const float* fc2_b = (const float*)d_in[28];

  float* ws = (float*)d_ws;
  // persistent region
  float* xm   = ws;                      // 13,271,040
  float* m1   = ws + 13271040;           // 1,440
  float* gates= ws + 13272480;           // 32
  float* dkb  = ws + 13272512;           // 1,152
  float* biasb= ws + 13273664;           // 1,440
  float* gapb = ws + 13275104;           // 1,440
  float* svec = ws + 13276544;           // 1,440 -> 13,277,984
  ushort* Wg1 = (ushort*)(ws + 13278000);// 110,592 sh -> 13,333,296
  ushort* Wg2 = (ushort*)(ws + 13333296);// 110,592 sh -> 13,388,592
  ushort* Wp1 = (ushort*)(ws + 13388592);// 147,456 sh -> 13,462,320
  ushort* Wp2 = (ushort*)(ws + 13462320);//  73,728 sh -> 13,499,184
  ushort* Wpa = (ushort*)(ws + 13499184);//  36,864 sh -> 13,517,616
  ushort* Bfx = (ushort*)(ws + 13517616);//  10,752 sh -> 13,522,992
  ushort* Tmw = (ushort*)(ws + 13522992);//  18,432 sh -> 13,532,208
  ushort* Bix = (ushort*)(ws + 13532208);//  12,288 sh -> 13,538,352
  ushort* Wbk = (ushort*)(ws + 13538352);// 110,592 sh -> 13,593,648
  ushort* Wdk = (ushort*)(ws + 13593648);// 372,736 sh -> 13,780,016
  float* big  = ws + 13780096;
  // phase 1 inside big:
  float* ximg = big;                     // 13,271,040
  float* spec = big + 13271040;          // 13,547,520 (xfft in first 9216 of each 9408 plane)
  ushort* mid = (ushort*)(big + 26818560); // 4,423,680 bf16
  float* attn = big + 29030400;          // 1,179,648 -> phase-1 top = 30,210,048
  float* ycab = spec;                    // reuse (stride 9216), spec dead after conv1
  // phase 2 aliases big:
  ushort* t1  = (ushort*)big;                    // 26,542,080 float slots
  float*  reg2= big + 26542080;
  ushort* xn2 = (ushort*)reg2;                   // (ln2->fc1)
  ushort* pgb = (ushort*)reg2;                   // (dwglu->fc2)
  // total ≈ 13,780,096 + 39,813,120 floats ≈ 214 MB

  k_packw<<<576,256,0,stream>>>(cab_w1, cab_w2, fc1_w, fc2_w, aggr_w, band_w,
                                Wg1, Wg2, Wp1, Wp2, Wpa, Wbk, Bfx, Tmw, Bix);
  k_ln1<<<2304,256,0,stream>>>(x, ln1_g, ln1_b, ximg);
  k_plane_mean<<<1440,256,0,stream>>>(ximg, m1);
  k_small<<<1,64,0,stream>>>(m1, gate_w, gate_b, dwc_w1, dwc_b1, dwc_w2, dwc_b2, band_b, gates, dkb, biasb);
  k_packplk<<<1456,256,0,stream>>>(plkw, dkb, Wdk);
  k_fft_fwd<<<1440,256,0,stream>>>(ximg, Bfx, Tmw, spec);
  k_bandmixm<<<dim3(147,Bb),256,0,stream>>>(spec, Wbk, gates);
  k_fft_inv<<<1440,256,0,stream>>>(spec, ximg, biasb, Tmw, Bix);
  k_cab<float, Cc, 192, 6, true,  true ><<<dim3(48,1,Bb),256,0,stream>>>(spec, Wg1, cab_b1, (void*)mid, CRr, SPL);
  k_cab<ushort, CRr, 64, 2, false, false><<<dim3(48,3,Bb),256,0,stream>>>(mid, Wg2, cab_b2, (void*)ycab, Cc, HWn);
  k_plane_mean<<<1440,256,0,stream>>>(ycab, gapb);
  k_eca<<<6,256,0,stream>>>(gapb, eca_w, svec);
  k_plkm<<<dim3(32,Bb),256,0,stream>>>(ximg, Wdk, attn);
  k_aggrm<<<dim3(1152,3),256,0,stream>>>(x, attn, ximg, ycab, Wpa, aggr_b, svec, xm);
  k_ln2<<<18432,256,0,stream>>>(xm, ln2_g, ln2_b, xn2);
  k_fc1<<<1152,256,0,stream>>>(xn2, Wp1, fc1_b, t1);
  k_dwglu<<<dim3(9,HID,Bb),256,0,stream>>>((const bf16*)t1, dw_w, dw_b, (bf16*)pgb);
  k_fc2<<<dim3(1152,3),256,0,stream>>>(pgb, xm, Wp2, fc2_b, (float*)d_out);
}

// Round 10
// 1373.257 us; speedup vs baseline: 2.6451x; 1.0214x over previous
//
#include <hip/hip_runtime.h>
#include <hip/hip_bf16.h>
#include <math.h>
#include <type_traits>

#define Bb 8
#define Cc 180
#define HWn 9216
#define PD 16
#define CRr 60
#define HID 360
#define H2 720
#define NF 49
#define SPL 9408   /* spectral plane stride in floats: 96*49*2 */
#define CONV_SCALE 0.01f
#define FFT_RES 0.15f
#define EPSLN 1e-5f
#define TWOPI_96 0.06544984694978735f

typedef __hip_bfloat16 bf16;
typedef unsigned short ushort;
typedef __attribute__((ext_vector_type(8))) short s8v;   // 8 bf16 (4 VGPRs) MFMA A/B frag
typedef __attribute__((ext_vector_type(4))) float f4v;   // MFMA C/D frag
struct us4 { ushort x,y,z,w; };

__device__ __forceinline__ float geluf(float x){ return 0.5f*x*(1.0f+erff(x*0.7071067811865476f)); }
__device__ __forceinline__ float sigm(float x){ return 1.0f/(1.0f+expf(-x)); }
__device__ __forceinline__ short f2bf(float f){
  unsigned u = __float_as_uint(f);
  u += 0x7fff + ((u>>16)&1);
  return (short)(u>>16);
}
__device__ __forceinline__ float wredsum(float v){
#pragma unroll
  for(int m=1;m<64;m<<=1) v += __shfl_xor(v,m,64);
  return v;
}

// ---------------- LN1 + transpose to (B,C,H,W) ----------------
__global__ void __launch_bounds__(256) k_ln1(const float* __restrict__ x, const float* __restrict__ g,
                      const float* __restrict__ be, float* __restrict__ ximg){
  __shared__ float sb[32*Cc];
  int b = blockIdx.x / 288;
  int n0 = (blockIdx.x % 288) * 32;
  int t = threadIdx.x;
  const float* src = x + (size_t)(b*HWn + n0)*Cc;
  for(int i=t;i<32*Cc;i+=256) sb[i]=src[i];
  __syncthreads();
  int w = t>>6, lane = t&63;
  for(int pi=0; pi<8; ++pi){
    int p = w*8+pi;
    float s=0.f, sq=0.f;
    for(int e=lane;e<Cc;e+=64){ float v=sb[p*Cc+e]; s+=v; sq+=v*v; }
    s = wredsum(s); sq = wredsum(sq);
    float mean = s*(1.0f/180.0f);
    float var = sq*(1.0f/180.0f) - mean*mean;
    float rstd = rsqrtf(var + EPSLN);
    for(int e=lane;e<Cc;e+=64){ float v=sb[p*Cc+e]; sb[p*Cc+e] = (v-mean)*rstd*g[e]+be[e]; }
  }
  __syncthreads();
  for(int i=t;i<32*Cc;i+=256){
    int c = i/32, p = i%32;
    ximg[(size_t)(b*Cc+c)*HWn + n0 + p] = sb[p*Cc+c];
  }
}

// ---------------- plane mean (9216 -> 1) ----------------
__global__ void __launch_bounds__(256) k_plane_mean(const float* __restrict__ in, float* __restrict__ out){
  __shared__ float red[4];
  int pl = blockIdx.x; int t = threadIdx.x;
  const float* p = in + (size_t)pl*HWn;
  float s=0.f;
  for(int i=t;i<HWn;i+=256) s+=p[i];
  s = wredsum(s);
  if((t&63)==0) red[t>>6]=s;
  __syncthreads();
  if(t==0) out[pl] = (red[0]+red[1]+red[2]+red[3]) * (1.0f/9216.0f);
}

// ---------------- small: gates, hdn->dk, fft bias ----------------
__global__ void k_small(const float* __restrict__ m1, const float* __restrict__ gate_w,
   const float* __restrict__ gate_b, const float* __restrict__ dwc_w1, const float* __restrict__ dwc_b1,
   const float* __restrict__ dwc_w2, const float* __restrict__ dwc_b2, const float* __restrict__ band_b,
   float* __restrict__ gates, float* __restrict__ dkb, float* __restrict__ biasb){
  int b = threadIdx.x;
  if(b>=Bb) return;
  const float* m = m1 + b*Cc;
  float gv[3];
  for(int k=0;k<3;k++){ float a=gate_b[k]; for(int c=0;c<Cc;c++) a+=m[c]*gate_w[k*Cc+c]; gv[k]=sigm(a);}
  float e0=expf(gv[0]), e1=expf(gv[1]), e2=expf(gv[2]); float inv=1.0f/(e0+e1+e2);
  float g0=e0*inv,g1=e1*inv,g2=e2*inv;
  gates[b*3+0]=g0; gates[b*3+1]=g1; gates[b*3+2]=g2;
  float hd[8];
  for(int j=0;j<8;j++){ float a=dwc_b1[j]; for(int c=0;c<PD;c++) a+=m[c]*dwc_w1[j*PD+c]; hd[j]=geluf(a);}
  for(int i=0;i<144;i++){ float a=dwc_b2[i]; for(int j=0;j<8;j++) a+=hd[j]*dwc_w2[i*8+j]; dkb[b*144+i]=a; }
  for(int d=0;d<Cc;d++) biasb[b*Cc+d] = g0*band_b[0*Cc+d]+g1*band_b[1*Cc+d]+g2*band_b[2*Cc+d];
}

// ------- pack weights to bf16 + DFT twiddle matrices -------
__global__ void __launch_bounds__(256) k_packw(const float* __restrict__ w1, const float* __restrict__ w2,
    const float* __restrict__ fw1, const float* __restrict__ fw2, const float* __restrict__ aw,
    const float* __restrict__ bw,
    ushort* __restrict__ Wg1, ushort* __restrict__ Wg2, ushort* __restrict__ Wp1,
    ushort* __restrict__ Wp2, ushort* __restrict__ Wpa, ushort* __restrict__ Wbk,
    ushort* __restrict__ Bfx, ushort* __restrict__ Tm, ushort* __restrict__ Bix){
  int t = blockIdx.x*256 + threadIdx.x;
  if(t < 64*9*192){
    int co = t/(9*192); int rem = t%(9*192); int tap = rem/192; int ci = rem%192;
    float v = (co<CRr && ci<Cc) ? w1[((size_t)(co*Cc+ci))*9 + tap] : 0.f;
    Wg1[t] = (ushort)f2bf(v);
  }
  if(t < 192*9*64){
    int co = t/(9*64); int rem = t%(9*64); int tap = rem/64; int ci = rem%64;
    float v = (co<Cc && ci<CRr) ? w2[((size_t)(co*CRr+ci))*9 + tap] : 0.f;
    Wg2[t] = (ushort)f2bf(v);
  }
  if(t < 768*192){
    int j=t/192, k=t%192;
    Wp1[t] = (ushort)f2bf((j<H2 && k<Cc)? fw1[(size_t)j*Cc+k] : 0.f);
  }
  if(t < 192*384){
    int j=t/384, k=t%384;
    Wp2[t] = (ushort)f2bf((j<Cc && k<HID)? fw2[(size_t)j*HID+k] : 0.f);
  }
  if(t < 192*192){
    int j=t/192, k=t%192;
    Wpa[t] = (ushort)f2bf((j<Cc && k<Cc)? aw[(size_t)j*Cc+k] : 0.f);
  }
  // Wbk[3][192 d][192 c] : band channel-mix weights
  if(t < 3*192*192){
    int k=t/(192*192); int rem=t%(192*192); int j=rem/192, c=rem%192;
    Wbk[t] = (ushort)f2bf((j<Cc && c<Cc)? bw[((size_t)k*Cc + j)*Cc + c] : 0.f);
  }
  // Bfx[112 n][96 k] : fwd-x twiddle (ortho 1/96 folded)
  if(t < 112*96){
    int n=t/96, k=t%96;
    float v=0.f;
    if(n<98){
      int kx=n>>1; int m=(k*kx)%96; float th=(float)m*TWOPI_96;
      v = ((n&1)? -sinf(th) : cosf(th)) * (1.0f/96.0f);
    }
    Bfx[t] = (ushort)f2bf(v);
  }
  // Tm[96 r][192 k] : y-transform twiddle (shared fwd/inv)
  if(t < 96*192){
    int r=t/192, k=t%192;
    int c=k>>1; int m=(r*c)%96; float th=(float)m*TWOPI_96;
    float v = (k&1)? sinf(th) : cosf(th);
    Tm[t] = (ushort)f2bf(v);
  }
  // Bix[96 n][128 k] : inv-x twiddle (wgt and 1/96 folded)
  if(t < 96*128){
    int n=t/128, k=t%128;
    float v=0.f;
    if(k<98){
      int kx=k>>1; float wgt=(kx==0||kx==48)?1.0f:2.0f;
      int m=(n*kx)%96; float th=(float)m*TWOPI_96;
      v = ((k&1)? -wgt*sinf(th) : wgt*cosf(th)) * (1.0f/96.0f);
    }
    Bix[t] = (ushort)f2bf(v);
  }
}

// ------- pack plk + per-batch dynamic depthwise into Wdk[b][co][13ky][7kxp][2tl*16ci] bf16 -------
__global__ void __launch_bounds__(256) k_packplk(const float* __restrict__ plk,
    const float* __restrict__ dkb, ushort* __restrict__ Wdk){
  int t = blockIdx.x*256 + threadIdx.x;
  if(t >= Bb*PD*13*7*32) return;
  int k = t & 31; int rest = t >> 5;
  int kxp = rest % 7; rest /= 7;
  int ky = rest % 13; rest /= 13;
  int co = rest % PD; int b = rest / PD;
  int tl = k >> 4, ci = k & 15;
  int kx = kxp*2 + tl;
  float v = 0.f;
  if(kx < 13){
    v = plk[((size_t)(co*PD+ci)*13 + ky)*13 + kx];
    if(ci==co && ky>=5 && ky<8 && kx>=5 && kx<8)
      v += dkb[b*144 + co*9 + (ky-5)*3 + (kx-5)];
  }
  Wdk[t] = (ushort)f2bf(v);
}

// ---------------- fused forward 2D rDFT (per plane), MFMA ----------------
__global__ void __launch_bounds__(256) k_fft_fwd(const float* __restrict__ ximg,
    const ushort* __restrict__ Bfx, const ushort* __restrict__ Tm, float* __restrict__ S){
  __shared__ __align__(16) short Asi[96*104];
  __shared__ __align__(16) short Bv[112*200];
  int bc = blockIdx.x; int t = threadIdx.x;
  int w=t>>6, lane=t&63, kq=lane>>4, lr=lane&15;
  const float* src = ximg + (size_t)bc*HWn;
  for(int i=t;i<1152;i+=256){
    int y=i/12, seg=i%12;
    float4 v0 = *(const float4*)(src + y*96 + seg*8);
    float4 v1 = *(const float4*)(src + y*96 + seg*8 + 4);
    s8v pk;
    pk[0]=f2bf(v0.x); pk[1]=f2bf(v0.y); pk[2]=f2bf(v0.z); pk[3]=f2bf(v0.w);
    pk[4]=f2bf(v1.x); pk[5]=f2bf(v1.y); pk[6]=f2bf(v1.z); pk[7]=f2bf(v1.w);
    *(s8v*)&Asi[y*104+seg*8] = pk;
  }
  __syncthreads();
  // stage1: V[y][n] = img @ Bfx^T ; write (V, -i*V) into Bv[n][2y,2y+1]
  for(int tile=w; tile<42; tile+=4){
    int mt=tile/7, nt=tile%7;
    f4v acc={};
#pragma unroll
    for(int ks=0;ks<3;ks++){
      s8v af = *(const s8v*)&Asi[(mt*16+lr)*104 + kq*8 + ks*32];
      s8v bf = *(const s8v*)&Bfx[(size_t)(nt*16+lr)*96 + kq*8 + ks*32];
      acc = __builtin_amdgcn_mfma_f32_16x16x32_bf16(af,bf,acc,0,0,0);
    }
    int n = nt*16+lr;
    float sgn = (n&1)? -1.f : 1.f;
#pragma unroll
    for(int reg=0;reg<4;reg++){
      int y = mt*16+kq*4+reg;
      float v = acc[reg];
      float p = __shfl_xor(v,1);
      unsigned pack = ((unsigned)(ushort)f2bf(sgn*p)<<16) | (ushort)(unsigned short)f2bf(v);
      *(unsigned*)&Bv[n*200 + 2*y] = pack;
    }
  }
  __syncthreads();
  // stage2: X[ky][n] = Tm @ Bv^T -> global fp32 spec plane
  float* dst = S + (size_t)bc*SPL;
  for(int tile=w; tile<42; tile+=4){
    int mt=tile/7, nt=tile%7;
    f4v acc={};
#pragma unroll
    for(int ks=0;ks<6;ks++){
      s8v af = *(const s8v*)&Tm[(size_t)(mt*16+lr)*192 + kq*8 + ks*32];
      s8v bf = *(const s8v*)&Bv[(nt*16+lr)*200 + kq*8 + ks*32];
      acc = __builtin_amdgcn_mfma_f32_16x16x32_bf16(af,bf,acc,0,0,0);
    }
    int n = nt*16+lr;
    if(n<98){
#pragma unroll
      for(int reg=0;reg<4;reg++){
        int ky = mt*16+kq*4+reg;
        dst[ky*98 + n] = acc[reg];
      }
    }
  }
}

// ---------------- fused inverse 2D rDFT + combine (per plane), MFMA, in-place ----------------
__global__ void __launch_bounds__(256) k_fft_inv(float* __restrict__ S, const float* __restrict__ ximg,
    const float* __restrict__ biasb, const ushort* __restrict__ Tm, const ushort* __restrict__ Bix){
  __shared__ __align__(16) short Bv[112*200];
  __shared__ __align__(16) short T2s[96*136];
  int bd = blockIdx.x; int t=threadIdx.x;
  int w=t>>6, lane=t&63, kq=lane>>4, lr=lane&15;
  int b = bd/Cc, d = bd%Cc;
  float* pl = S + (size_t)bd*SPL;
  // zero Bv rows n=98..111 and T2s cols 112..135
  for(int i=t;i<1400;i+=256) ((unsigned*)&Bv[98*200])[i] = 0u;
  for(int i=t;i<1152;i+=256){ int y=i/12, c=i%12; *(unsigned*)&T2s[y*136+112+c*2] = 0u; }
  // build Bv from Yhat with +i twist (partner via shfl)
  for(int i=t;i<9408;i+=256){
    float v = pl[i];
    float p = __shfl_xor(v,1);
    int ky = i/98, n = i%98;
    float tw = (n&1)? p : -p;
    unsigned pack = ((unsigned)(ushort)f2bf(tw)<<16) | (ushort)(unsigned short)f2bf(v);
    *(unsigned*)&Bv[n*200 + 2*ky] = pack;
  }
  __syncthreads();
  // stage1: T2[y][n] = Tm @ Bv^T -> LDS
  for(int tile=w; tile<42; tile+=4){
    int mt=tile/7, nt=tile%7;
    f4v acc={};
#pragma unroll
    for(int ks=0;ks<6;ks++){
      s8v af = *(const s8v*)&Tm[(size_t)(mt*16+lr)*192 + kq*8 + ks*32];
      s8v bf = *(const s8v*)&Bv[(nt*16+lr)*200 + kq*8 + ks*32];
      acc = __builtin_amdgcn_mfma_f32_16x16x32_bf16(af,bf,acc,0,0,0);
    }
    int n = nt*16+lr;
#pragma unroll
    for(int reg=0;reg<4;reg++){
      int y = mt*16+kq*4+reg;
      T2s[y*136 + n] = f2bf(acc[reg]);
    }
  }
  __syncthreads();
  // stage2: out[y][xx] = T2 @ Bix^T ; combine with ximg + bias, in-place
  float bias = biasb[b*Cc+d];
  const float* xs = ximg + (size_t)bd*HWn;
  for(int tile=w; tile<36; tile+=4){
    int mt=tile/6, nt=tile%6;
    f4v acc={};
#pragma unroll
    for(int ks=0;ks<4;ks++){
      s8v af = *(const s8v*)&T2s[(mt*16+lr)*136 + kq*8 + ks*32];
      s8v bf = *(const s8v*)&Bix[(size_t)(nt*16+lr)*128 + kq*8 + ks*32];
      acc = __builtin_amdgcn_mfma_f32_16x16x32_bf16(af,bf,acc,0,0,0);
    }
    int xx = nt*16+lr;
#pragma unroll
    for(int reg=0;reg<4;reg++){
      int y = mt*16+kq*4+reg;
      int o = y*96+xx;
      pl[o] = xs[o] + FFT_RES*(acc[reg] + bias);
    }
  }
}

// ---------------- band channel mix as MFMA GEMM, IN-PLACE, per-column band select ----------------
__global__ void __launch_bounds__(256) k_bandmixm(float* __restrict__ S, const ushort* __restrict__ Wbk,
                          const float* __restrict__ gates){
  __shared__ __align__(16) short Bs[64*200];
  int f2base = blockIdx.x*64;
  int b = blockIdx.y;
  int t = threadIdx.x;
  int w=t>>6, lane=t&63, kq=lane>>4, lr=lane&15;
  // stage X-tile transposed: Bs[r=f2local][c], bf16, K padded to 192
  for(int i=t;i<8*192;i+=256){
    int rblk=i&7, kk=i>>3;
    int r0=rblk*8;
    if(kk<Cc){
      const float* src = S + (size_t)(b*Cc+kk)*SPL + f2base + r0;
      float4 v0 = *(const float4*)src;
      float4 v1 = *(const float4*)(src+4);
      Bs[(r0+0)*200+kk]=f2bf(v0.x); Bs[(r0+1)*200+kk]=f2bf(v0.y);
      Bs[(r0+2)*200+kk]=f2bf(v0.z); Bs[(r0+3)*200+kk]=f2bf(v0.w);
      Bs[(r0+4)*200+kk]=f2bf(v1.x); Bs[(r0+5)*200+kk]=f2bf(v1.y);
      Bs[(r0+6)*200+kk]=f2bf(v1.z); Bs[(r0+7)*200+kk]=f2bf(v1.w);
    } else {
#pragma unroll
      for(int q=0;q<8;q++) Bs[(r0+q)*200+kk]=0;
    }
  }
  // block-wide band mask (64 cols, one per lane; all waves compute same)
  unsigned bmask;
  {
    int col = f2base + lane;
    int ky = col/98, n = col%98, kx = n>>1;
    float yy = -1.0f + 2.0f*(float)ky/95.0f;
    float xxf = (float)kx/48.0f;
    float rr = sqrtf(yy*yy+xxf*xxf);
    int k = (rr<=0.25f)?0:((rr<=0.6f)?1:2);
    unsigned m = 1u<<k;
#pragma unroll
    for(int s=1;s<64;s<<=1) m |= __shfl_xor(m,s);
    bmask = m;
  }
  // per-lane band/gate for my 4 C-columns (f2local = w*16 + kq*4 + reg)
  int kb[4]; float gv[4];
#pragma unroll
  for(int reg=0;reg<4;reg++){
    int col = f2base + w*16 + kq*4 + reg;
    int ky = col/98, n = col%98, kx = n>>1;
    float yy = -1.0f + 2.0f*(float)ky/95.0f;
    float xxf = (float)kx/48.0f;
    float rr = sqrtf(yy*yy+xxf*xxf);
    kb[reg] = (rr<=0.25f)?0:((rr<=0.6f)?1:2);
    gv[reg] = gates[b*3+kb[reg]];
  }
  __syncthreads();
  s8v af[6];
#pragma unroll
  for(int k6=0;k6<6;k6++) af[k6] = *(const s8v*)&Bs[(w*16+lr)*200 + kq*8 + k6*32];
  float res[12][4];
  for(int k=0;k<3;k++){
    if(!(bmask&(1u<<k))) continue;
    for(int ts=0;ts<12;ts++){
      f4v acc={};
#pragma unroll
      for(int k6=0;k6<6;k6++){
        s8v wf = *(const s8v*)&Wbk[((size_t)(k*192 + ts*16+lr))*192 + kq*8 + k6*32];
        acc = __builtin_amdgcn_mfma_f32_16x16x32_bf16(af[k6],wf,acc,0,0,0);
      }
#pragma unroll
      for(int reg=0;reg<4;reg++) if(kb[reg]==k) res[ts][reg]=gv[reg]*acc[reg];
    }
  }
  // write back: each lane stores float4 (4 consecutive f2) per d-row
#pragma unroll
  for(int ts=0;ts<12;ts++){
    int d = ts*16+lr;
    if(d<Cc){
      float4 o; o.x=res[ts][0]; o.y=res[ts][1]; o.z=res[ts][2]; o.w=res[ts][3];
      *(float4*)(S + (size_t)(b*Cc+d)*SPL + f2base + w*16 + kq*4) = o;
    }
  }
}

// ---------------- CAB 3x3 conv as implicit-GEMM MFMA ----------------
template<typename TIN, int CIN, int KPAD, int NCHUNK, bool ACT, bool OUTBF>
__global__ void __launch_bounds__(256) k_cab(const TIN* __restrict__ xin, const ushort* __restrict__ Wg,
    const float* __restrict__ bias, void* __restrict__ outv, int COUT, int istride){
  __shared__ short As[4*98*36];   // 28224 B; also reused for epilogue transpose
  int y0 = blockIdx.x*2;
  int ct = blockIdx.y;
  int b  = blockIdx.z;
  int t = threadIdx.x;
  int w = t>>6, lane = t&63, kq = lane>>4, lr = lane&15;
  f4v acc[3][4] = {};
  for(int ch=0; ch<NCHUNK; ++ch){
    int ci0 = ch*32;
    __syncthreads();
    for(int i=t;i<4*98*32;i+=256){
      int ci = i/392; int rem = i%392; int row = rem/98; int pxh = rem%98;
      int gy = y0 - 1 + row; int px = pxh - 1;
      int cig = ci0 + ci;
      short sv = 0;
      if((unsigned)gy<96u && (unsigned)px<96u && cig<CIN){
        if constexpr (std::is_same<TIN,float>::value)
          sv = f2bf(xin[(size_t)(b*CIN+cig)*istride + gy*96 + px]);
        else
          sv = (short)xin[(size_t)(b*CIN+cig)*istride + gy*96 + px];
      }
      As[(row*98+pxh)*36 + ci] = sv;
    }
    __syncthreads();
#pragma unroll
    for(int tap=0; tap<9; ++tap){
      int ky = tap/3, kx = tap%3;
      s8v bfr[4];
#pragma unroll
      for(int ts=0;ts<4;ts++)
        bfr[ts] = *(const s8v*)&Wg[((size_t)(ct*64 + ts*16 + lr)*9 + tap)*KPAD + ci0 + kq*8];
#pragma unroll
      for(int s=0;s<3;s++){
        int mt = w + 4*s;
        int orow = mt/6, px = (mt%6)*16 + lr;
        s8v af = *(const s8v*)&As[((orow+ky)*98 + px + kx)*36 + kq*8];
#pragma unroll
        for(int ts=0;ts<4;ts++)
          acc[s][ts] = __builtin_amdgcn_mfma_f32_16x16x32_bf16(af, bfr[ts], acc[s][ts], 0,0,0);
      }
    }
  }
  // epilogue
  if(OUTBF){
    __syncthreads();
    short* cT = As;   // [64 co][200] bf16
#pragma unroll
    for(int ts=0;ts<4;ts++){
      int cog = ct*64 + ts*16 + lr;
      float bb = (cog<COUT)? bias[cog] : 0.f;
#pragma unroll
      for(int s=0;s<3;s++){
#pragma unroll
        for(int reg=0;reg<4;reg++){
          int px = (w+4*s)*16 + kq*4 + reg;
          float v = acc[s][ts][reg] + bb;
          if(ACT) v = geluf(v);
          cT[(ts*16+lr)*200 + px] = f2bf(v);
        }
      }
    }
    __syncthreads();
    ushort* out = (ushort*)outv;
    for(int i=t;i<64*192;i+=256){
      int co=i/192, px=i%192;
      int cog = ct*64+co;
      if(cog<COUT) out[(size_t)(b*COUT+cog)*HWn + y0*96 + px] = (ushort)cT[co*200+px];
    }
  } else {
    float* cF = (float*)As;  // [32 co][200] fp32 per half
    float* out = (float*)outv;
    for(int h=0;h<2;h++){
      __syncthreads();
#pragma unroll
      for(int tt=0;tt<2;tt++){
        int ts = 2*h+tt;
        int cog = ct*64 + ts*16 + lr;
        float bb = (cog<COUT)? bias[cog] : 0.f;
#pragma unroll
        for(int s=0;s<3;s++){
#pragma unroll
          for(int reg=0;reg<4;reg++){
            int px = (w+4*s)*16 + kq*4 + reg;
            cF[(tt*16+lr)*200 + px] = acc[s][ts][reg] + bb;
          }
        }
      }
      __syncthreads();
      for(int i=t;i<32*192;i+=256){
        int co=i/192, px=i%192;
        int cog = ct*64 + h*32 + co;
        if(cog<COUT) out[(size_t)(b*COUT+cog)*HWn + y0*96 + px] = cF[co*200+px];
      }
    }
  }
}

// ---------------- ECA ----------------
__global__ void k_eca(const float* __restrict__ gap, const float* __restrict__ ew, float* __restrict__ s){
  int i = blockIdx.x*blockDim.x + threadIdx.x;
  if(i>=Bb*Cc) return;
  int b=i/Cc, c=i%Cc;
  float z=0.f;
  for(int j=0;j<5;j++){ int cc=c-2+j; if(cc>=0&&cc<Cc) z+=gap[b*Cc+cc]*ew[j]; }
  s[i]=sigm(z);
}

// ------- plk 13x13 + fused dynamic dw3x3 as implicit-GEMM MFMA (tap-pair K=32) -------
__global__ void __launch_bounds__(256) k_plkm(const float* __restrict__ ximg,
    const ushort* __restrict__ Wdk, float* __restrict__ attn){
  __shared__ short As[15*109*20];   // 65,400 B; pxh stride 20 shorts (40B) -> conflict-free
  int y0 = blockIdx.x*3;
  int b  = blockIdx.y;
  int t = threadIdx.x;
  int w = t>>6, lane = t&63, kq = lane>>4, lr = lane&15;
  // stage: As[row][pxh][ci] ; row = y0-6 .. y0+8 ; pxh-6 = px -6..102 (col 108 zero)
  for(int i=t;i<PD*15*109;i+=256){
    int ci = i/(15*109); int rem = i%(15*109);
    int row = rem/109, pxh = rem%109;
    int gy = y0 + row - 6, gx = pxh - 6;
    short sv = 0;
    if((unsigned)gy<96u && (unsigned)gx<96u)
      sv = f2bf(ximg[(size_t)(b*Cc+ci)*HWn + gy*96 + gx]);
    As[(row*109+pxh)*20 + ci] = sv;
  }
  __syncthreads();
  f4v acc[5] = {};
  const ushort* wb = Wdk + ((size_t)(b*PD+lr)*13)*7*32 + kq*8;
  for(int ky=0;ky<13;ky++){
#pragma unroll
    for(int kxp=0;kxp<7;kxp++){
      s8v bfr = *(const s8v*)(wb + (ky*7+kxp)*32);
      int ti=0;
      for(int mt=w; mt<18; mt+=4, ti++){
        int yo = mt/6, o = (mt%6)*16;
        s8v af = *(const s8v*)&As[((yo+ky)*109 + o + lr + 2*kxp + (kq>>1))*20 + (kq&1)*8];
        acc[ti] = __builtin_amdgcn_mfma_f32_16x16x32_bf16(af, bfr, acc[ti], 0,0,0);
      }
    }
  }
  // epilogue: C col = lr = co ; rows = px (4 consecutive) -> float4 stores
  int ti=0;
  for(int mt=w; mt<18; mt+=4, ti++){
    int yo = mt/6, o = (mt%6)*16 + kq*4;
    float4 ov; ov.x=acc[ti][0]; ov.y=acc[ti][1]; ov.z=acc[ti][2]; ov.w=acc[ti][3];
    *(float4*)&attn[(size_t)(b*PD+lr)*HWn + (y0+yo)*96 + o] = ov;
  }
}

// ---------------- aggr as MFMA GEMM + residual + conv_x scale -> xm (B,N,C) ----------------
__global__ void __launch_bounds__(256) k_aggrm(const float* __restrict__ x, const float* __restrict__ attn,
   const float* __restrict__ ximg, const float* __restrict__ ycab, const ushort* __restrict__ Wpa,
   const float* __restrict__ aggb, const float* __restrict__ svec, float* __restrict__ xm){
  __shared__ short smem[64*200];   // As ; reused as cF (fp32 64x68) in epilogue
  short* As = smem;
  int rt = blockIdx.x, ct = blockIdx.y;
  int t = threadIdx.x;
  int w = t>>6, lane = t&63, kq = lane>>4, lr = lane&15;
  int grow0 = rt*64; int b = grow0/HWn; int n0 = grow0%HWn;
  for(int i=t;i<8*192;i+=256){
    int rblk=i&7, kk=i>>3;
    int r0=rblk*8;
    if(kk<Cc){
      const float* src = (kk<PD)? attn + (size_t)(b*PD+kk)*HWn + n0 + r0
                                : ximg + (size_t)(b*Cc+kk)*HWn + n0 + r0;
      float4 v0 = *(const float4*)src;
      float4 v1 = *(const float4*)(src+4);
      As[(r0+0)*200+kk]=f2bf(v0.x); As[(r0+1)*200+kk]=f2bf(v0.y);
      As[(r0+2)*200+kk]=f2bf(v0.z); As[(r0+3)*200+kk]=f2bf(v0.w);
      As[(r0+4)*200+kk]=f2bf(v1.x); As[(r0+5)*200+kk]=f2bf(v1.y);
      As[(r0+6)*200+kk]=f2bf(v1.z); As[(r0+7)*200+kk]=f2bf(v1.w);
    } else {
#pragma unroll
      for(int q=0;q<8;q++) As[(r0+q)*200+kk]=0;
    }
  }
  __syncthreads();
  f4v acc[4]={};
  int arow=(w*16+lr)*200 + kq*8;
#pragma unroll
  for(int k0=0;k0<192;k0+=32){
    s8v af = *(const s8v*)&As[arow+k0];
#pragma unroll
    for(int ts=0;ts<4;ts++){
      s8v wf = *(const s8v*)&Wpa[(size_t)(ct*64+ts*16+lr)*192 + kq*8 + k0];
      acc[ts]=__builtin_amdgcn_mfma_f32_16x16x32_bf16(af,wf,acc[ts],0,0,0);
    }
  }
  __syncthreads();
  float* cF = (float*)smem;
#pragma unroll
  for(int ts=0;ts<4;ts++){
    int j = ts*16+lr;
    int jc = ct*64 + j;
    float bb=0.f, sv=0.f;
    if(jc<Cc){ bb=aggb[jc]; sv=CONV_SCALE*svec[b*Cc+jc]; }
    const float* yrow = ycab + ((jc<Cc)? (size_t)(b*Cc+jc)*HWn + n0 : 0);
#pragma unroll
    for(int reg=0;reg<4;reg++){
      int m = w*16 + kq*4 + reg;
      float v = 0.f;
      if(jc<Cc) v = acc[ts][reg] + bb + sv*yrow[m];
      cF[m*68+j] = v;
    }
  }
  __syncthreads();
  for(int i=t;i<64*64;i+=256){
    int m=i>>6, j=i&63;
    int jc=ct*64+j;
    if(jc<Cc){
      size_t o = (size_t)(grow0+m)*Cc + jc;
      xm[o] = x[o] + cF[m*68+j];
    }
  }
}

// ---------------- LN2 fused: stats + normalize + bf16 cast, K padded 180->192 ----------------
__global__ void __launch_bounds__(256) k_ln2(const float* __restrict__ xm, const float* __restrict__ g2,
    const float* __restrict__ b2, ushort* __restrict__ xn2){
  int w = (blockIdx.x*256 + threadIdx.x)>>6;
  int lane = threadIdx.x&63;
  const float* row = xm + (size_t)w*Cc;
  float s=0,sq=0;
  for(int e=lane;e<Cc;e+=64){ float v=row[e]; s+=v; sq+=v*v; }
  s=wredsum(s); sq=wredsum(sq);
  float m=s*(1.0f/180.0f); float v=sq*(1.0f/180.0f)-m*m;
  float rstd=rsqrtf(v+EPSLN);
  ushort* orow = xn2 + (size_t)w*192;
  for(int e=lane;e<192;e+=64){
    float val = (e<Cc)? (row[e]-m)*rstd*g2[e]+b2[e] : 0.f;
    orow[e] = (ushort)f2bf(val);
  }
}

// -------- fc1 MFMA, W direct from packed global, A frags in registers, ct loop,
//          direct ushort4 stores from C-layout (no LDS, no barriers) --------
__global__ void __launch_bounds__(256) k_fc1(const ushort* __restrict__ xn2,
    const ushort* __restrict__ Wp, const float* __restrict__ fb, ushort* __restrict__ t1){
  int rt = blockIdx.x;
  int t = threadIdx.x;
  int w = t>>6, lane = t&63, kq = lane>>4, lr = lane&15;
  int grow0 = rt*64;
  int bb_ = grow0/HWn, n0 = grow0%HWn;
  s8v af[6];
  const ushort* arow = xn2 + (size_t)(grow0 + w*16 + lr)*192 + kq*8;
#pragma unroll
  for(int k6=0;k6<6;k6++) af[k6] = *(const s8v*)(arow + k6*32);
  int mcol = n0 + w*16 + kq*4;
  for(int ct=0; ct<12; ++ct){
    f4v acc[4]={};
#pragma unroll
    for(int k6=0;k6<6;k6++){
#pragma unroll
      for(int ts=0;ts<4;ts++){
        s8v wf = *(const s8v*)&Wp[(size_t)(ct*64+ts*16+lr)*192 + kq*8 + k6*32];
        acc[ts]=__builtin_amdgcn_mfma_f32_16x16x32_bf16(af[k6],wf,acc[ts],0,0,0);
      }
    }
#pragma unroll
    for(int ts=0;ts<4;ts++){
      int jc = ct*64 + ts*16 + lr;
      if(jc<H2){
        float bb = fb[jc];
        us4 pk;
        pk.x=(ushort)f2bf(acc[ts][0]+bb); pk.y=(ushort)f2bf(acc[ts][1]+bb);
        pk.z=(ushort)f2bf(acc[ts][2]+bb); pk.w=(ushort)f2bf(acc[ts][3]+bb);
        *(us4*)&t1[((size_t)(bb_*H2+jc))*HWn + mcol] = pk;
      }
    }
  }
}

// ---------------- depthwise 3x3 on t1 + GLU -> pg (B,360,HW) bf16 ----------------
__global__ void __launch_bounds__(256) k_dwglu(const bf16* __restrict__ t1, const float* __restrict__ dww,
    const float* __restrict__ dwb, bf16* __restrict__ pg){
  __shared__ float ta[34*34];
  __shared__ float tg[34*34];
  int tile_id=blockIdx.x; int c=blockIdx.y; int b=blockIdx.z;
  int ty0=(tile_id/3)*32, tx0=(tile_id%3)*32;
  int t=threadIdx.x;
  int px0=(t%16)*2, py0=(t/16)*2;
  for(int i=t;i<34*34;i+=256){
    int ly=i/34, lx=i%34; int gy=ty0+ly-1, gx=tx0+lx-1;
    bool ok=((unsigned)gy<96u&&(unsigned)gx<96u);
    ta[i]= ok? __bfloat162float(t1[((size_t)(b*H2+c)*96+gy)*96+gx]) :0.f;
    tg[i]= ok? __bfloat162float(t1[((size_t)(b*H2+c+HID)*96+gy)*96+gx]) :0.f;
  }
  __syncthreads();
  float wp[9],wg[9];
#pragma unroll
  for(int i=0;i<9;i++){ wp[i]=dww[c*9+i]; wg[i]=dww[(c+HID)*9+i]; }
  float bp=dwb[c], bg=dwb[c+HID];
#pragma unroll
  for(int oy=0;oy<2;oy++)
#pragma unroll
    for(int ox=0;ox<2;ox++){
      float p=bp,g=bg;
#pragma unroll
      for(int ky=0;ky<3;ky++)
#pragma unroll
        for(int kx=0;kx<3;kx++){
          p+=wp[ky*3+kx]*ta[(py0+oy+ky)*34+px0+ox+kx];
          g+=wg[ky*3+kx]*tg[(py0+oy+ky)*34+px0+ox+kx];
        }
      float val = p * g * sigm(g);
      pg[((size_t)(b*HID+c)*96 + ty0+py0+oy)*96 + tx0+px0+ox] = __float2bfloat16(val);
    }
}

// ---------------- fc2 MFMA + residual -> out (B,N,C); W direct, single K=384 pass ----------------
__global__ void __launch_bounds__(256) k_fc2(const ushort* __restrict__ pg, const float* __restrict__ xm,
    const ushort* __restrict__ Wp, const float* __restrict__ fb, float* __restrict__ out){
  __shared__ short As[64*392];   // 50176 B
  int rt = blockIdx.x, ct = blockIdx.y;
  int t = threadIdx.x;
  int w = t>>6, lane = t&63, kq = lane>>4, lr = lane&15;
  int grow0 = rt*64; int b = grow0/HWn; int n0 = grow0%HWn;
  for(int i=t;i<8*HID;i+=256){
    int rblk=i&7, kc=i>>3;
    int r0=rblk*8;
    s8v v = *(const s8v*)&pg[((size_t)(b*HID+kc))*HWn + n0 + r0];
#pragma unroll
    for(int q=0;q<8;q++) As[(r0+q)*392 + kc] = v[q];
  }
  for(int i=t;i<64*24;i+=256){
    int r=i/24, kk=i%24;
    As[r*392 + HID + kk] = 0;
  }
  __syncthreads();
  f4v acc[4]={};
  int arow=(w*16+lr)*392 + kq*8;
#pragma unroll
  for(int k0=0;k0<384;k0+=32){
    s8v af = *(const s8v*)&As[arow+k0];
#pragma unroll
    for(int ts=0;ts<4;ts++){
      s8v wf = *(const s8v*)&Wp[(size_t)(ct*64+ts*16+lr)*384 + kq*8 + k0];
      acc[ts]=__builtin_amdgcn_mfma_f32_16x16x32_bf16(af,wf,acc[ts],0,0,0);
    }
  }
#pragma unroll
  for(int ts=0;ts<4;ts++){
    int jc = ct*64 + ts*16 + lr;
    if(jc>=Cc) continue;
    float bb = fb[jc];
#pragma unroll
    for(int reg=0;reg<4;reg++){
      int m = w*16 + kq*4 + reg;
      size_t o = (size_t)(grow0+m)*Cc + jc;
      out[o] = xm[o] + acc[ts][reg] + bb;
    }
  }
}

extern "C" void kernel_launch(void* const* d_in, const int* in_sizes, int n_in,
                              void* d_out, int out_size, void* d_ws, size_t ws_size,
                              hipStream_t stream){
  (void)in_sizes; (void)n_in; (void)out_size; (void)ws_size;
  const float* x     = (const float*)d_in[0];
  const float* ln1_g = (const float*)d_in[3];
  const float* ln1_b = (const float*)d_in[4];
  const float* band_w= (const float*)d_in[5];
  const float* band_b= (const float*)d_in[6];
  const float* gate_w= (const float*)d_in[7];
  const float* gate_b= (const float*)d_in[8];
  const float* cab_w1= (const float*)d_in[9];
  const float* cab_b1= (const float*)d_in[10];
  const float* cab_w2= (const float*)d_in[11];
  const float* cab_b2= (const float*)d_in[12];
  const float* eca_w = (const float*)d_in[13];
  const float* plkw  = (const float*)d_in[14];
  const float* dwc_w1= (const float*)d_in[15];
  const float* dwc_b1= (const float*)d_in[16];
  const float* dwc_w2= (const float*)d_in[17];
  const float* dwc_b2= (const float*)d_in[18];
  const float* aggr_w= (const float*)d_in[19];
  const float* aggr_b= (const float*)d_in[20];
  const float* ln2_g = (const float*)d_in[21];
  const float* ln2_b = (const float*)d_in[22];
  const float* fc1_w = (const float*)d_in[23];
  const float* fc1_b = (const float*)d_in[24];
  const float* dw_w  = (const float*)d_in[25];
  const float* dw_b  = (const float*)d_in[26];
  const float* fc2_w = (const float*)d_in[27];
  const float* fc2_b = (const float*)d_in[28];

  float* ws = (float*)d_ws;
  // persistent region
  float* xm   = ws;                      // 13,271,040
  float* m1   = ws + 13271040;           // 1,440
  float* gates= ws + 13272480;           // 32
  float* dkb  = ws + 13272512;           // 1,152
  float* biasb= ws + 13273664;           // 1,440
  float* gapb = ws + 13275104;           // 1,440
  float* svec = ws + 13276544;           // 1,440 -> 13,277,984
  ushort* Wg1 = (ushort*)(ws + 13278000);// 110,592 sh -> 13,333,296
  ushort* Wg2 = (ushort*)(ws + 13333296);// 110,592 sh -> 13,388,592
  ushort* Wp1 = (ushort*)(ws + 13388592);// 147,456 sh -> 13,462,320
  ushort* Wp2 = (ushort*)(ws + 13462320);//  73,728 sh -> 13,499,184
  ushort* Wpa = (ushort*)(ws + 13499184);//  36,864 sh -> 13,517,616
  ushort* Bfx = (ushort*)(ws + 13517616);//  10,752 sh -> 13,522,992
  ushort* Tmw = (ushort*)(ws + 13522992);//  18,432 sh -> 13,532,208
  ushort* Bix = (ushort*)(ws + 13532208);//  12,288 sh -> 13,538,352
  ushort* Wbk = (ushort*)(ws + 13538352);// 110,592 sh -> 13,593,648
  ushort* Wdk = (ushort*)(ws + 13593648);// 372,736 sh -> 13,780,016
  float* big  = ws + 13780096;
  // phase 1 inside big:
  float* ximg = big;                     // 13,271,040
  float* spec = big + 13271040;          // 13,547,520 (xfft in first 9216 of each 9408 plane)
  ushort* mid = (ushort*)(big + 26818560); // 4,423,680 bf16
  float* attn = big + 29030400;          // 1,179,648 -> phase-1 top = 30,210,048
  float* ycab = spec;                    // reuse (stride 9216), spec dead after conv1
  // phase 2 aliases big:
  ushort* t1  = (ushort*)big;                    // 26,542,080 float slots
  float*  reg2= big + 26542080;
  ushort* xn2 = (ushort*)reg2;                   // (ln2->fc1)
  ushort* pgb = (ushort*)reg2;                   // (dwglu->fc2)
  // total ≈ 13,780,096 + 39,813,120 floats ≈ 214 MB

  k_packw<<<576,256,0,stream>>>(cab_w1, cab_w2, fc1_w, fc2_w, aggr_w, band_w,
                                Wg1, Wg2, Wp1, Wp2, Wpa, Wbk, Bfx, Tmw, Bix);
  k_ln1<<<2304,256,0,stream>>>(x, ln1_g, ln1_b, ximg);
  k_plane_mean<<<1440,256,0,stream>>>(ximg, m1);
  k_small<<<1,64,0,stream>>>(m1, gate_w, gate_b, dwc_w1, dwc_b1, dwc_w2, dwc_b2, band_b, gates, dkb, biasb);
  k_packplk<<<1456,256,0,stream>>>(plkw, dkb, Wdk);
  k_fft_fwd<<<1440,256,0,stream>>>(ximg, Bfx, Tmw, spec);
  k_bandmixm<<<dim3(147,Bb),256,0,stream>>>(spec, Wbk, gates);
  k_fft_inv<<<1440,256,0,stream>>>(spec, ximg, biasb, Tmw, Bix);
  k_cab<float, Cc, 192, 6, true,  true ><<<dim3(48,1,Bb),256,0,stream>>>(spec, Wg1, cab_b1, (void*)mid, CRr, SPL);
  k_cab<ushort, CRr, 64, 2, false, false><<<dim3(48,3,Bb),256,0,stream>>>(mid, Wg2, cab_b2, (void*)ycab, Cc, HWn);
  k_plane_mean<<<1440,256,0,stream>>>(ycab, gapb);
  k_eca<<<6,256,0,stream>>>(gapb, eca_w, svec);
  k_plkm<<<dim3(32,Bb),256,0,stream>>>(ximg, Wdk, attn);
  k_aggrm<<<dim3(1152,3),256,0,stream>>>(x, attn, ximg, ycab, Wpa, aggr_b, svec, xm);
  k_ln2<<<18432,256,0,stream>>>(xm, ln2_g, ln2_b, xn2);
  k_fc1<<<1152,256,0,stream>>>(xn2, Wp1, fc1_b, t1);
  k_dwglu<<<dim3(9,HID,Bb),256,0,stream>>>((const bf16*)t1, dw_w, dw_b, (bf16*)pgb);
  k_fc2<<<dim3(1152,3),256,0,stream>>>(pgb, xm, Wp2, fc2_b, (float*)d_out);
}

// Round 11
// 1273.560 us; speedup vs baseline: 2.8522x; 1.0783x over previous
//
#include <hip/hip_runtime.h>
#include <hip/hip_bf16.h>
#include <math.h>
#include <type_traits>

#define Bb 8
#define Cc 180
#define HWn 9216
#define PD 16
#define CRr 60
#define HID 360
#define H2 720
#define NF 49
#define SPL 9408   /* spectral plane stride in floats: 96*49*2 */
#define CONV_SCALE 0.01f
#define FFT_RES 0.15f
#define EPSLN 1e-5f
#define TWOPI_96 0.06544984694978735f

typedef __hip_bfloat16 bf16;
typedef unsigned short ushort;
typedef __attribute__((ext_vector_type(8))) short s8v;   // 8 bf16 (4 VGPRs) MFMA A/B frag
typedef __attribute__((ext_vector_type(4))) float f4v;   // MFMA C/D frag
struct us4 { ushort x,y,z,w; };

__device__ __forceinline__ float geluf(float x){ return 0.5f*x*(1.0f+erff(x*0.7071067811865476f)); }
__device__ __forceinline__ float sigm(float x){ return 1.0f/(1.0f+expf(-x)); }
__device__ __forceinline__ short f2bf(float f){
  unsigned u = __float_as_uint(f);
  u += 0x7fff + ((u>>16)&1);
  return (short)(u>>16);
}
__device__ __forceinline__ float wredsum(float v){
#pragma unroll
  for(int m=1;m<64;m<<=1) v += __shfl_xor(v,m,64);
  return v;
}

// ---------------- LN1 + transpose to (B,C,H,W) ----------------
__global__ void __launch_bounds__(256) k_ln1(const float* __restrict__ x, const float* __restrict__ g,
                      const float* __restrict__ be, float* __restrict__ ximg){
  __shared__ float sb[32*Cc];
  int b = blockIdx.x / 288;
  int n0 = (blockIdx.x % 288) * 32;
  int t = threadIdx.x;
  const float* src = x + (size_t)(b*HWn + n0)*Cc;
  for(int i=t;i<32*Cc;i+=256) sb[i]=src[i];
  __syncthreads();
  int w = t>>6, lane = t&63;
  for(int pi=0; pi<8; ++pi){
    int p = w*8+pi;
    float s=0.f, sq=0.f;
    for(int e=lane;e<Cc;e+=64){ float v=sb[p*Cc+e]; s+=v; sq+=v*v; }
    s = wredsum(s); sq = wredsum(sq);
    float mean = s*(1.0f/180.0f);
    float var = sq*(1.0f/180.0f) - mean*mean;
    float rstd = rsqrtf(var + EPSLN);
    for(int e=lane;e<Cc;e+=64){ float v=sb[p*Cc+e]; sb[p*Cc+e] = (v-mean)*rstd*g[e]+be[e]; }
  }
  __syncthreads();
  for(int i=t;i<32*Cc;i+=256){
    int c = i/32, p = i%32;
    ximg[(size_t)(b*Cc+c)*HWn + n0 + p] = sb[p*Cc+c];
  }
}

// ---------------- plane mean (9216 -> 1) ----------------
__global__ void __launch_bounds__(256) k_plane_mean(const float* __restrict__ in, float* __restrict__ out){
  __shared__ float red[4];
  int pl = blockIdx.x; int t = threadIdx.x;
  const float* p = in + (size_t)pl*HWn;
  float s=0.f;
  for(int i=t;i<HWn;i+=256) s+=p[i];
  s = wredsum(s);
  if((t&63)==0) red[t>>6]=s;
  __syncthreads();
  if(t==0) out[pl] = (red[0]+red[1]+red[2]+red[3]) * (1.0f/9216.0f);
}

// ---------------- small: gates, hdn->dk, fft bias ----------------
__global__ void k_small(const float* __restrict__ m1, const float* __restrict__ gate_w,
   const float* __restrict__ gate_b, const float* __restrict__ dwc_w1, const float* __restrict__ dwc_b1,
   const float* __restrict__ dwc_w2, const float* __restrict__ dwc_b2, const float* __restrict__ band_b,
   float* __restrict__ gates, float* __restrict__ dkb, float* __restrict__ biasb){
  int b = threadIdx.x;
  if(b>=Bb) return;
  const float* m = m1 + b*Cc;
  float gv[3];
  for(int k=0;k<3;k++){ float a=gate_b[k]; for(int c=0;c<Cc;c++) a+=m[c]*gate_w[k*Cc+c]; gv[k]=sigm(a);}
  float e0=expf(gv[0]), e1=expf(gv[1]), e2=expf(gv[2]); float inv=1.0f/(e0+e1+e2);
  float g0=e0*inv,g1=e1*inv,g2=e2*inv;
  gates[b*3+0]=g0; gates[b*3+1]=g1; gates[b*3+2]=g2;
  float hd[8];
  for(int j=0;j<8;j++){ float a=dwc_b1[j]; for(int c=0;c<PD;c++) a+=m[c]*dwc_w1[j*PD+c]; hd[j]=geluf(a);}
  for(int i=0;i<144;i++){ float a=dwc_b2[i]; for(int j=0;j<8;j++) a+=hd[j]*dwc_w2[i*8+j]; dkb[b*144+i]=a; }
  for(int d=0;d<Cc;d++) biasb[b*Cc+d] = g0*band_b[0*Cc+d]+g1*band_b[1*Cc+d]+g2*band_b[2*Cc+d];
}

// ------- pack weights to bf16 + DFT twiddle matrices -------
__global__ void __launch_bounds__(256) k_packw(const float* __restrict__ w1, const float* __restrict__ w2,
    const float* __restrict__ fw1, const float* __restrict__ fw2, const float* __restrict__ aw,
    const float* __restrict__ bw,
    ushort* __restrict__ Wg1, ushort* __restrict__ Wg2, ushort* __restrict__ Wp1,
    ushort* __restrict__ Wp2, ushort* __restrict__ Wpa, ushort* __restrict__ Wbk,
    ushort* __restrict__ Bfx, ushort* __restrict__ Tm, ushort* __restrict__ Bix){
  int t = blockIdx.x*256 + threadIdx.x;
  if(t < 64*9*192){
    int co = t/(9*192); int rem = t%(9*192); int tap = rem/192; int ci = rem%192;
    float v = (co<CRr && ci<Cc) ? w1[((size_t)(co*Cc+ci))*9 + tap] : 0.f;
    Wg1[t] = (ushort)f2bf(v);
  }
  if(t < 192*9*64){
    int co = t/(9*64); int rem = t%(9*64); int tap = rem/64; int ci = rem%64;
    float v = (co<Cc && ci<CRr) ? w2[((size_t)(co*CRr+ci))*9 + tap] : 0.f;
    Wg2[t] = (ushort)f2bf(v);
  }
  if(t < 768*192){
    int j=t/192, k=t%192;
    Wp1[t] = (ushort)f2bf((j<H2 && k<Cc)? fw1[(size_t)j*Cc+k] : 0.f);
  }
  if(t < 192*384){
    int j=t/384, k=t%384;
    Wp2[t] = (ushort)f2bf((j<Cc && k<HID)? fw2[(size_t)j*HID+k] : 0.f);
  }
  if(t < 192*192){
    int j=t/192, k=t%192;
    Wpa[t] = (ushort)f2bf((j<Cc && k<Cc)? aw[(size_t)j*Cc+k] : 0.f);
  }
  // Wbk[3][192 d][192 c] : band channel-mix weights
  if(t < 3*192*192){
    int k=t/(192*192); int rem=t%(192*192); int j=rem/192, c=rem%192;
    Wbk[t] = (ushort)f2bf((j<Cc && c<Cc)? bw[((size_t)k*Cc + j)*Cc + c] : 0.f);
  }
  // Bfx[112 n][96 k] : fwd-x twiddle (ortho 1/96 folded)
  if(t < 112*96){
    int n=t/96, k=t%96;
    float v=0.f;
    if(n<98){
      int kx=n>>1; int m=(k*kx)%96; float th=(float)m*TWOPI_96;
      v = ((n&1)? -sinf(th) : cosf(th)) * (1.0f/96.0f);
    }
    Bfx[t] = (ushort)f2bf(v);
  }
  // Tm[96 r][192 k] : y-transform twiddle (shared fwd/inv)
  if(t < 96*192){
    int r=t/192, k=t%192;
    int c=k>>1; int m=(r*c)%96; float th=(float)m*TWOPI_96;
    float v = (k&1)? sinf(th) : cosf(th);
    Tm[t] = (ushort)f2bf(v);
  }
  // Bix[96 n][128 k] : inv-x twiddle (wgt and 1/96 folded)
  if(t < 96*128){
    int n=t/128, k=t%128;
    float v=0.f;
    if(k<98){
      int kx=k>>1; float wgt=(kx==0||kx==48)?1.0f:2.0f;
      int m=(n*kx)%96; float th=(float)m*TWOPI_96;
      v = ((k&1)? -wgt*sinf(th) : wgt*cosf(th)) * (1.0f/96.0f);
    }
    Bix[t] = (ushort)f2bf(v);
  }
}

// ------- pack plk + per-batch dynamic depthwise into Wdk[b][co][13ky][7kxp][2tl*16ci] bf16 -------
__global__ void __launch_bounds__(256) k_packplk(const float* __restrict__ plk,
    const float* __restrict__ dkb, ushort* __restrict__ Wdk){
  int t = blockIdx.x*256 + threadIdx.x;
  if(t >= Bb*PD*13*7*32) return;
  int k = t & 31; int rest = t >> 5;
  int kxp = rest % 7; rest /= 7;
  int ky = rest % 13; rest /= 13;
  int co = rest % PD; int b = rest / PD;
  int tl = k >> 4, ci = k & 15;
  int kx = kxp*2 + tl;
  float v = 0.f;
  if(kx < 13){
    v = plk[((size_t)(co*PD+ci)*13 + ky)*13 + kx];
    if(ci==co && ky>=5 && ky<8 && kx>=5 && kx<8)
      v += dkb[b*144 + co*9 + (ky-5)*3 + (kx-5)];
  }
  Wdk[t] = (ushort)f2bf(v);
}

// ---------------- fused forward 2D rDFT (per plane), MFMA ----------------
__global__ void __launch_bounds__(256) k_fft_fwd(const float* __restrict__ ximg,
    const ushort* __restrict__ Bfx, const ushort* __restrict__ Tm, float* __restrict__ S){
  __shared__ __align__(16) short Asi[96*104];
  __shared__ __align__(16) short Bv[112*200];
  int bc = blockIdx.x; int t = threadIdx.x;
  int w=t>>6, lane=t&63, kq=lane>>4, lr=lane&15;
  const float* src = ximg + (size_t)bc*HWn;
  for(int i=t;i<1152;i+=256){
    int y=i/12, seg=i%12;
    float4 v0 = *(const float4*)(src + y*96 + seg*8);
    float4 v1 = *(const float4*)(src + y*96 + seg*8 + 4);
    s8v pk;
    pk[0]=f2bf(v0.x); pk[1]=f2bf(v0.y); pk[2]=f2bf(v0.z); pk[3]=f2bf(v0.w);
    pk[4]=f2bf(v1.x); pk[5]=f2bf(v1.y); pk[6]=f2bf(v1.z); pk[7]=f2bf(v1.w);
    *(s8v*)&Asi[y*104+seg*8] = pk;
  }
  __syncthreads();
  // stage1: V[y][n] = img @ Bfx^T ; write (V, -i*V) into Bv[n][2y,2y+1]
  for(int tile=w; tile<42; tile+=4){
    int mt=tile/7, nt=tile%7;
    f4v acc={};
#pragma unroll
    for(int ks=0;ks<3;ks++){
      s8v af = *(const s8v*)&Asi[(mt*16+lr)*104 + kq*8 + ks*32];
      s8v bf = *(const s8v*)&Bfx[(size_t)(nt*16+lr)*96 + kq*8 + ks*32];
      acc = __builtin_amdgcn_mfma_f32_16x16x32_bf16(af,bf,acc,0,0,0);
    }
    int n = nt*16+lr;
    float sgn = (n&1)? -1.f : 1.f;
#pragma unroll
    for(int reg=0;reg<4;reg++){
      int y = mt*16+kq*4+reg;
      float v = acc[reg];
      float p = __shfl_xor(v,1);
      unsigned pack = ((unsigned)(ushort)f2bf(sgn*p)<<16) | (ushort)(unsigned short)f2bf(v);
      *(unsigned*)&Bv[n*200 + 2*y] = pack;
    }
  }
  __syncthreads();
  // stage2: X[ky][n] = Tm @ Bv^T -> global fp32 spec plane
  float* dst = S + (size_t)bc*SPL;
  for(int tile=w; tile<42; tile+=4){
    int mt=tile/7, nt=tile%7;
    f4v acc={};
#pragma unroll
    for(int ks=0;ks<6;ks++){
      s8v af = *(const s8v*)&Tm[(size_t)(mt*16+lr)*192 + kq*8 + ks*32];
      s8v bf = *(const s8v*)&Bv[(nt*16+lr)*200 + kq*8 + ks*32];
      acc = __builtin_amdgcn_mfma_f32_16x16x32_bf16(af,bf,acc,0,0,0);
    }
    int n = nt*16+lr;
    if(n<98){
#pragma unroll
      for(int reg=0;reg<4;reg++){
        int ky = mt*16+kq*4+reg;
        dst[ky*98 + n] = acc[reg];
      }
    }
  }
}

// ---------------- fused inverse 2D rDFT + combine (per plane), MFMA, in-place ----------------
__global__ void __launch_bounds__(256) k_fft_inv(float* __restrict__ S, const float* __restrict__ ximg,
    const float* __restrict__ biasb, const ushort* __restrict__ Tm, const ushort* __restrict__ Bix){
  __shared__ __align__(16) short Bv[112*200];
  __shared__ __align__(16) short T2s[96*136];
  int bd = blockIdx.x; int t=threadIdx.x;
  int w=t>>6, lane=t&63, kq=lane>>4, lr=lane&15;
  int b = bd/Cc, d = bd%Cc;
  float* pl = S + (size_t)bd*SPL;
  // zero Bv rows n=98..111 and T2s cols 112..135
  for(int i=t;i<1400;i+=256) ((unsigned*)&Bv[98*200])[i] = 0u;
  for(int i=t;i<1152;i+=256){ int y=i/12, c=i%12; *(unsigned*)&T2s[y*136+112+c*2] = 0u; }
  // build Bv from Yhat with +i twist (partner via shfl)
  for(int i=t;i<9408;i+=256){
    float v = pl[i];
    float p = __shfl_xor(v,1);
    int ky = i/98, n = i%98;
    float tw = (n&1)? p : -p;
    unsigned pack = ((unsigned)(ushort)f2bf(tw)<<16) | (ushort)(unsigned short)f2bf(v);
    *(unsigned*)&Bv[n*200 + 2*ky] = pack;
  }
  __syncthreads();
  // stage1: T2[y][n] = Tm @ Bv^T -> LDS
  for(int tile=w; tile<42; tile+=4){
    int mt=tile/7, nt=tile%7;
    f4v acc={};
#pragma unroll
    for(int ks=0;ks<6;ks++){
      s8v af = *(const s8v*)&Tm[(size_t)(mt*16+lr)*192 + kq*8 + ks*32];
      s8v bf = *(const s8v*)&Bv[(nt*16+lr)*200 + kq*8 + ks*32];
      acc = __builtin_amdgcn_mfma_f32_16x16x32_bf16(af,bf,acc,0,0,0);
    }
    int n = nt*16+lr;
#pragma unroll
    for(int reg=0;reg<4;reg++){
      int y = mt*16+kq*4+reg;
      T2s[y*136 + n] = f2bf(acc[reg]);
    }
  }
  __syncthreads();
  // stage2: out[y][xx] = T2 @ Bix^T ; combine with ximg + bias, in-place
  float bias = biasb[b*Cc+d];
  const float* xs = ximg + (size_t)bd*HWn;
  for(int tile=w; tile<36; tile+=4){
    int mt=tile/6, nt=tile%6;
    f4v acc={};
#pragma unroll
    for(int ks=0;ks<4;ks++){
      s8v af = *(const s8v*)&T2s[(mt*16+lr)*136 + kq*8 + ks*32];
      s8v bf = *(const s8v*)&Bix[(size_t)(nt*16+lr)*128 + kq*8 + ks*32];
      acc = __builtin_amdgcn_mfma_f32_16x16x32_bf16(af,bf,acc,0,0,0);
    }
    int xx = nt*16+lr;
#pragma unroll
    for(int reg=0;reg<4;reg++){
      int y = mt*16+kq*4+reg;
      int o = y*96+xx;
      pl[o] = xs[o] + FFT_RES*(acc[reg] + bias);
    }
  }
}

// ---------------- band channel mix as MFMA GEMM, IN-PLACE, per-column band select ----------------
__global__ void __launch_bounds__(256) k_bandmixm(float* __restrict__ S, const ushort* __restrict__ Wbk,
                          const float* __restrict__ gates){
  __shared__ __align__(16) short Bs[64*200];
  int f2base = blockIdx.x*64;
  int b = blockIdx.y;
  int t = threadIdx.x;
  int w=t>>6, lane=t&63, kq=lane>>4, lr=lane&15;
  // stage X-tile transposed: Bs[r=f2local][c], bf16, K padded to 192
  for(int i=t;i<8*192;i+=256){
    int rblk=i&7, kk=i>>3;
    int r0=rblk*8;
    if(kk<Cc){
      const float* src = S + (size_t)(b*Cc+kk)*SPL + f2base + r0;
      float4 v0 = *(const float4*)src;
      float4 v1 = *(const float4*)(src+4);
      Bs[(r0+0)*200+kk]=f2bf(v0.x); Bs[(r0+1)*200+kk]=f2bf(v0.y);
      Bs[(r0+2)*200+kk]=f2bf(v0.z); Bs[(r0+3)*200+kk]=f2bf(v0.w);
      Bs[(r0+4)*200+kk]=f2bf(v1.x); Bs[(r0+5)*200+kk]=f2bf(v1.y);
      Bs[(r0+6)*200+kk]=f2bf(v1.z); Bs[(r0+7)*200+kk]=f2bf(v1.w);
    } else {
#pragma unroll
      for(int q=0;q<8;q++) Bs[(r0+q)*200+kk]=0;
    }
  }
  // block-wide band mask (64 cols, one per lane; all waves compute same)
  unsigned bmask;
  {
    int col = f2base + lane;
    int ky = col/98, n = col%98, kx = n>>1;
    float yy = -1.0f + 2.0f*(float)ky/95.0f;
    float xxf = (float)kx/48.0f;
    float rr = sqrtf(yy*yy+xxf*xxf);
    int k = (rr<=0.25f)?0:((rr<=0.6f)?1:2);
    unsigned m = 1u<<k;
#pragma unroll
    for(int s=1;s<64;s<<=1) m |= __shfl_xor(m,s);
    bmask = m;
  }
  // per-lane band/gate for my 4 C-columns (f2local = w*16 + kq*4 + reg)
  int kb[4]; float gv[4];
#pragma unroll
  for(int reg=0;reg<4;reg++){
    int col = f2base + w*16 + kq*4 + reg;
    int ky = col/98, n = col%98, kx = n>>1;
    float yy = -1.0f + 2.0f*(float)ky/95.0f;
    float xxf = (float)kx/48.0f;
    float rr = sqrtf(yy*yy+xxf*xxf);
    kb[reg] = (rr<=0.25f)?0:((rr<=0.6f)?1:2);
    gv[reg] = gates[b*3+kb[reg]];
  }
  __syncthreads();
  s8v af[6];
#pragma unroll
  for(int k6=0;k6<6;k6++) af[k6] = *(const s8v*)&Bs[(w*16+lr)*200 + kq*8 + k6*32];
  float res[12][4];
  for(int k=0;k<3;k++){
    if(!(bmask&(1u<<k))) continue;
    for(int ts=0;ts<12;ts++){
      f4v acc={};
#pragma unroll
      for(int k6=0;k6<6;k6++){
        s8v wf = *(const s8v*)&Wbk[((size_t)(k*192 + ts*16+lr))*192 + kq*8 + k6*32];
        acc = __builtin_amdgcn_mfma_f32_16x16x32_bf16(af[k6],wf,acc,0,0,0);
      }
#pragma unroll
      for(int reg=0;reg<4;reg++) if(kb[reg]==k) res[ts][reg]=gv[reg]*acc[reg];
    }
  }
  // write back: each lane stores float4 (4 consecutive f2) per d-row
#pragma unroll
  for(int ts=0;ts<12;ts++){
    int d = ts*16+lr;
    if(d<Cc){
      float4 o; o.x=res[ts][0]; o.y=res[ts][1]; o.z=res[ts][2]; o.w=res[ts][3];
      *(float4*)(S + (size_t)(b*Cc+d)*SPL + f2base + w*16 + kq*4) = o;
    }
  }
}

// ---------------- CAB 3x3 conv as implicit-GEMM MFMA ----------------
template<typename TIN, int CIN, int KPAD, int NCHUNK, bool ACT, bool OUTBF>
__global__ void __launch_bounds__(256) k_cab(const TIN* __restrict__ xin, const ushort* __restrict__ Wg,
    const float* __restrict__ bias, void* __restrict__ outv, int COUT, int istride){
  __shared__ short As[4*98*36];   // 28224 B; also reused for epilogue transpose
  int y0 = blockIdx.x*2;
  int ct = blockIdx.y;
  int b  = blockIdx.z;
  int t = threadIdx.x;
  int w = t>>6, lane = t&63, kq = lane>>4, lr = lane&15;
  f4v acc[3][4] = {};
  for(int ch=0; ch<NCHUNK; ++ch){
    int ci0 = ch*32;
    __syncthreads();
    for(int i=t;i<4*98*32;i+=256){
      int ci = i/392; int rem = i%392; int row = rem/98; int pxh = rem%98;
      int gy = y0 - 1 + row; int px = pxh - 1;
      int cig = ci0 + ci;
      short sv = 0;
      if((unsigned)gy<96u && (unsigned)px<96u && cig<CIN){
        if constexpr (std::is_same<TIN,float>::value)
          sv = f2bf(xin[(size_t)(b*CIN+cig)*istride + gy*96 + px]);
        else
          sv = (short)xin[(size_t)(b*CIN+cig)*istride + gy*96 + px];
      }
      As[(row*98+pxh)*36 + ci] = sv;
    }
    __syncthreads();
#pragma unroll
    for(int tap=0; tap<9; ++tap){
      int ky = tap/3, kx = tap%3;
      s8v bfr[4];
#pragma unroll
      for(int ts=0;ts<4;ts++)
        bfr[ts] = *(const s8v*)&Wg[((size_t)(ct*64 + ts*16 + lr)*9 + tap)*KPAD + ci0 + kq*8];
#pragma unroll
      for(int s=0;s<3;s++){
        int mt = w + 4*s;
        int orow = mt/6, px = (mt%6)*16 + lr;
        s8v af = *(const s8v*)&As[((orow+ky)*98 + px + kx)*36 + kq*8];
#pragma unroll
        for(int ts=0;ts<4;ts++)
          acc[s][ts] = __builtin_amdgcn_mfma_f32_16x16x32_bf16(af, bfr[ts], acc[s][ts], 0,0,0);
      }
    }
  }
  // epilogue
  if(OUTBF){
    __syncthreads();
    short* cT = As;   // [64 co][200] bf16
#pragma unroll
    for(int ts=0;ts<4;ts++){
      int cog = ct*64 + ts*16 + lr;
      float bb = (cog<COUT)? bias[cog] : 0.f;
#pragma unroll
      for(int s=0;s<3;s++){
#pragma unroll
        for(int reg=0;reg<4;reg++){
          int px = (w+4*s)*16 + kq*4 + reg;
          float v = acc[s][ts][reg] + bb;
          if(ACT) v = geluf(v);
          cT[(ts*16+lr)*200 + px] = f2bf(v);
        }
      }
    }
    __syncthreads();
    ushort* out = (ushort*)outv;
    for(int i=t;i<64*192;i+=256){
      int co=i/192, px=i%192;
      int cog = ct*64+co;
      if(cog<COUT) out[(size_t)(b*COUT+cog)*HWn + y0*96 + px] = (ushort)cT[co*200+px];
    }
  } else {
    float* cF = (float*)As;  // [32 co][200] fp32 per half
    float* out = (float*)outv;
    for(int h=0;h<2;h++){
      __syncthreads();
#pragma unroll
      for(int tt=0;tt<2;tt++){
        int ts = 2*h+tt;
        int cog = ct*64 + ts*16 + lr;
        float bb = (cog<COUT)? bias[cog] : 0.f;
#pragma unroll
        for(int s=0;s<3;s++){
#pragma unroll
          for(int reg=0;reg<4;reg++){
            int px = (w+4*s)*16 + kq*4 + reg;
            cF[(tt*16+lr)*200 + px] = acc[s][ts][reg] + bb;
          }
        }
      }
      __syncthreads();
      for(int i=t;i<32*192;i+=256){
        int co=i/192, px=i%192;
        int cog = ct*64 + h*32 + co;
        if(cog<COUT) out[(size_t)(b*COUT+cog)*HWn + y0*96 + px] = cF[co*200+px];
      }
    }
  }
}

// ---------------- ECA ----------------
__global__ void k_eca(const float* __restrict__ gap, const float* __restrict__ ew, float* __restrict__ s){
  int i = blockIdx.x*blockDim.x + threadIdx.x;
  if(i>=Bb*Cc) return;
  int b=i/Cc, c=i%Cc;
  float z=0.f;
  for(int j=0;j<5;j++){ int cc=c-2+j; if(cc>=0&&cc<Cc) z+=gap[b*Cc+cc]*ew[j]; }
  s[i]=sigm(z);
}

// ------- plk 13x13 + fused dynamic dw3x3 as implicit-GEMM MFMA (tap-pair K=32) -------
__global__ void __launch_bounds__(256) k_plkm(const float* __restrict__ ximg,
    const ushort* __restrict__ Wdk, float* __restrict__ attn){
  __shared__ short As[15*109*20];   // 65,400 B; pxh stride 20 shorts (40B) -> conflict-free
  int y0 = blockIdx.x*3;
  int b  = blockIdx.y;
  int t = threadIdx.x;
  int w = t>>6, lane = t&63, kq = lane>>4, lr = lane&15;
  // stage: As[row][pxh][ci] ; row = y0-6 .. y0+8 ; pxh-6 = px -6..102 (col 108 zero)
  for(int i=t;i<PD*15*109;i+=256){
    int ci = i/(15*109); int rem = i%(15*109);
    int row = rem/109, pxh = rem%109;
    int gy = y0 + row - 6, gx = pxh - 6;
    short sv = 0;
    if((unsigned)gy<96u && (unsigned)gx<96u)
      sv = f2bf(ximg[(size_t)(b*Cc+ci)*HWn + gy*96 + gx]);
    As[(row*109+pxh)*20 + ci] = sv;
  }
  __syncthreads();
  f4v acc[5] = {};
  const ushort* wb = Wdk + ((size_t)(b*PD+lr)*13)*7*32 + kq*8;
  for(int ky=0;ky<13;ky++){
#pragma unroll
    for(int kxp=0;kxp<7;kxp++){
      s8v bfr = *(const s8v*)(wb + (ky*7+kxp)*32);
      int ti=0;
      for(int mt=w; mt<18; mt+=4, ti++){
        int yo = mt/6, o = (mt%6)*16;
        s8v af = *(const s8v*)&As[((yo+ky)*109 + o + lr + 2*kxp + (kq>>1))*20 + (kq&1)*8];
        acc[ti] = __builtin_amdgcn_mfma_f32_16x16x32_bf16(af, bfr, acc[ti], 0,0,0);
      }
    }
  }
  // epilogue: C col = lr = co ; rows = px (4 consecutive) -> float4 stores
  int ti=0;
  for(int mt=w; mt<18; mt+=4, ti++){
    int yo = mt/6, o = (mt%6)*16 + kq*4;
    float4 ov; ov.x=acc[ti][0]; ov.y=acc[ti][1]; ov.z=acc[ti][2]; ov.w=acc[ti][3];
    *(float4*)&attn[(size_t)(b*PD+lr)*HWn + (y0+yo)*96 + o] = ov;
  }
}

// ---------------- aggr as MFMA GEMM + residual + conv_x scale -> xm (B,N,C) ----------------
__global__ void __launch_bounds__(256) k_aggrm(const float* __restrict__ x, const float* __restrict__ attn,
   const float* __restrict__ ximg, const float* __restrict__ ycab, const ushort* __restrict__ Wpa,
   const float* __restrict__ aggb, const float* __restrict__ svec, float* __restrict__ xm){
  __shared__ short smem[64*200];   // As ; reused as cF (fp32 64x68) in epilogue
  short* As = smem;
  int rt = blockIdx.x, ct = blockIdx.y;
  int t = threadIdx.x;
  int w = t>>6, lane = t&63, kq = lane>>4, lr = lane&15;
  int grow0 = rt*64; int b = grow0/HWn; int n0 = grow0%HWn;
  for(int i=t;i<8*192;i+=256){
    int rblk=i&7, kk=i>>3;
    int r0=rblk*8;
    if(kk<Cc){
      const float* src = (kk<PD)? attn + (size_t)(b*PD+kk)*HWn + n0 + r0
                                : ximg + (size_t)(b*Cc+kk)*HWn + n0 + r0;
      float4 v0 = *(const float4*)src;
      float4 v1 = *(const float4*)(src+4);
      As[(r0+0)*200+kk]=f2bf(v0.x); As[(r0+1)*200+kk]=f2bf(v0.y);
      As[(r0+2)*200+kk]=f2bf(v0.z); As[(r0+3)*200+kk]=f2bf(v0.w);
      As[(r0+4)*200+kk]=f2bf(v1.x); As[(r0+5)*200+kk]=f2bf(v1.y);
      As[(r0+6)*200+kk]=f2bf(v1.z); As[(r0+7)*200+kk]=f2bf(v1.w);
    } else {
#pragma unroll
      for(int q=0;q<8;q++) As[(r0+q)*200+kk]=0;
    }
  }
  __syncthreads();
  f4v acc[4]={};
  int arow=(w*16+lr)*200 + kq*8;
#pragma unroll
  for(int k0=0;k0<192;k0+=32){
    s8v af = *(const s8v*)&As[arow+k0];
#pragma unroll
    for(int ts=0;ts<4;ts++){
      s8v wf = *(const s8v*)&Wpa[(size_t)(ct*64+ts*16+lr)*192 + kq*8 + k0];
      acc[ts]=__builtin_amdgcn_mfma_f32_16x16x32_bf16(af,wf,acc[ts],0,0,0);
    }
  }
  __syncthreads();
  float* cF = (float*)smem;
#pragma unroll
  for(int ts=0;ts<4;ts++){
    int j = ts*16+lr;
    int jc = ct*64 + j;
    float bb=0.f, sv=0.f;
    if(jc<Cc){ bb=aggb[jc]; sv=CONV_SCALE*svec[b*Cc+jc]; }
    const float* yrow = ycab + ((jc<Cc)? (size_t)(b*Cc+jc)*HWn + n0 : 0);
#pragma unroll
    for(int reg=0;reg<4;reg++){
      int m = w*16 + kq*4 + reg;
      float v = 0.f;
      if(jc<Cc) v = acc[ts][reg] + bb + sv*yrow[m];
      cF[m*68+j] = v;
    }
  }
  __syncthreads();
  for(int i=t;i<64*64;i+=256){
    int m=i>>6, j=i&63;
    int jc=ct*64+j;
    if(jc<Cc){
      size_t o = (size_t)(grow0+m)*Cc + jc;
      xm[o] = x[o] + cF[m*68+j];
    }
  }
}

// ---------------- LN2 fused: stats + normalize + bf16 cast, K padded 180->192 ----------------
__global__ void __launch_bounds__(256) k_ln2(const float* __restrict__ xm, const float* __restrict__ g2,
    const float* __restrict__ b2, ushort* __restrict__ xn2){
  int w = (blockIdx.x*256 + threadIdx.x)>>6;
  int lane = threadIdx.x&63;
  const float* row = xm + (size_t)w*Cc;
  float s=0,sq=0;
  for(int e=lane;e<Cc;e+=64){ float v=row[e]; s+=v; sq+=v*v; }
  s=wredsum(s); sq=wredsum(sq);
  float m=s*(1.0f/180.0f); float v=sq*(1.0f/180.0f)-m*m;
  float rstd=rsqrtf(v+EPSLN);
  ushort* orow = xn2 + (size_t)w*192;
  for(int e=lane;e<192;e+=64){
    float val = (e<Cc)? (row[e]-m)*rstd*g2[e]+b2[e] : 0.f;
    orow[e] = (ushort)f2bf(val);
  }
}

// -------- fc1 MFMA: W-tile staged to LDS via coalesced s8v copies (kills 16-line
//          address divergence), A frags in registers, direct us4 stores --------
__global__ void __launch_bounds__(256) k_fc1(const ushort* __restrict__ xn2,
    const ushort* __restrict__ Wp, const float* __restrict__ fb, ushort* __restrict__ t1){
  __shared__ __align__(16) short Ws[64*200];   // 25.6 KB
  int rt = blockIdx.x;
  int t = threadIdx.x;
  int w = t>>6, lane = t&63, kq = lane>>4, lr = lane&15;
  int grow0 = rt*64;
  int bb_ = grow0/HWn, n0 = grow0%HWn;
  s8v af[6];
  const ushort* arow = xn2 + (size_t)(grow0 + w*16 + lr)*192 + kq*8;
#pragma unroll
  for(int k6=0;k6<6;k6++) af[k6] = *(const s8v*)(arow + k6*32);
  int mcol = n0 + w*16 + kq*4;
  for(int ct=0; ct<12; ++ct){
    __syncthreads();
    // stage W tile (64 rows x 192) with contiguous 16B copies: 1536 chunks, 6/thread
    const s8v* src = (const s8v*)(Wp + (size_t)ct*64*192);
#pragma unroll
    for(int q=0;q<6;q++){
      int i = t + q*256;
      int j = i/24, seg = i%24;
      *(s8v*)&Ws[j*200 + seg*8] = src[i];
    }
    __syncthreads();
    f4v acc[4]={};
#pragma unroll
    for(int k6=0;k6<6;k6++){
#pragma unroll
      for(int ts=0;ts<4;ts++){
        s8v wf = *(const s8v*)&Ws[(ts*16+lr)*200 + kq*8 + k6*32];
        acc[ts]=__builtin_amdgcn_mfma_f32_16x16x32_bf16(af[k6],wf,acc[ts],0,0,0);
      }
    }
#pragma unroll
    for(int ts=0;ts<4;ts++){
      int jc = ct*64 + ts*16 + lr;
      if(jc<H2){
        float bb = fb[jc];
        us4 pk;
        pk.x=(ushort)f2bf(acc[ts][0]+bb); pk.y=(ushort)f2bf(acc[ts][1]+bb);
        pk.z=(ushort)f2bf(acc[ts][2]+bb); pk.w=(ushort)f2bf(acc[ts][3]+bb);
        *(us4*)&t1[((size_t)(bb_*H2+jc))*HWn + mcol] = pk;
      }
    }
  }
}

// ---------------- depthwise 3x3 on t1 + GLU -> pg (B,360,HW) bf16 ----------------
__global__ void __launch_bounds__(256) k_dwglu(const bf16* __restrict__ t1, const float* __restrict__ dww,
    const float* __restrict__ dwb, bf16* __restrict__ pg){
  __shared__ float ta[34*34];
  __shared__ float tg[34*34];
  int tile_id=blockIdx.x; int c=blockIdx.y; int b=blockIdx.z;
  int ty0=(tile_id/3)*32, tx0=(tile_id%3)*32;
  int t=threadIdx.x;
  int px0=(t%16)*2, py0=(t/16)*2;
  for(int i=t;i<34*34;i+=256){
    int ly=i/34, lx=i%34; int gy=ty0+ly-1, gx=tx0+lx-1;
    bool ok=((unsigned)gy<96u&&(unsigned)gx<96u);
    ta[i]= ok? __bfloat162float(t1[((size_t)(b*H2+c)*96+gy)*96+gx]) :0.f;
    tg[i]= ok? __bfloat162float(t1[((size_t)(b*H2+c+HID)*96+gy)*96+gx]) :0.f;
  }
  __syncthreads();
  float wp[9],wg[9];
#pragma unroll
  for(int i=0;i<9;i++){ wp[i]=dww[c*9+i]; wg[i]=dww[(c+HID)*9+i]; }
  float bp=dwb[c], bg=dwb[c+HID];
#pragma unroll
  for(int oy=0;oy<2;oy++)
#pragma unroll
    for(int ox=0;ox<2;ox++){
      float p=bp,g=bg;
#pragma unroll
      for(int ky=0;ky<3;ky++)
#pragma unroll
        for(int kx=0;kx<3;kx++){
          p+=wp[ky*3+kx]*ta[(py0+oy+ky)*34+px0+ox+kx];
          g+=wg[ky*3+kx]*tg[(py0+oy+ky)*34+px0+ox+kx];
        }
      float val = p * g * sigm(g);
      pg[((size_t)(b*HID+c)*96 + ty0+py0+oy)*96 + tx0+px0+ox] = __float2bfloat16(val);
    }
}

// ---------------- fc2 MFMA + residual -> out (B,N,C); W direct, single K=384 pass ----------------
__global__ void __launch_bounds__(256) k_fc2(const ushort* __restrict__ pg, const float* __restrict__ xm,
    const ushort* __restrict__ Wp, const float* __restrict__ fb, float* __restrict__ out){
  __shared__ short As[64*392];   // 50176 B
  int rt = blockIdx.x, ct = blockIdx.y;
  int t = threadIdx.x;
  int w = t>>6, lane = t&63, kq = lane>>4, lr = lane&15;
  int grow0 = rt*64; int b = grow0/HWn; int n0 = grow0%HWn;
  for(int i=t;i<8*HID;i+=256){
    int rblk=i&7, kc=i>>3;
    int r0=rblk*8;
    s8v v = *(const s8v*)&pg[((size_t)(b*HID+kc))*HWn + n0 + r0];
#pragma unroll
    for(int q=0;q<8;q++) As[(r0+q)*392 + kc] = v[q];
  }
  for(int i=t;i<64*24;i+=256){
    int r=i/24, kk=i%24;
    As[r*392 + HID + kk] = 0;
  }
  __syncthreads();
  f4v acc[4]={};
  int arow=(w*16+lr)*392 + kq*8;
#pragma unroll
  for(int k0=0;k0<384;k0+=32){
    s8v af = *(const s8v*)&As[arow+k0];
#pragma unroll
    for(int ts=0;ts<4;ts++){
      s8v wf = *(const s8v*)&Wp[(size_t)(ct*64+ts*16+lr)*384 + kq*8 + k0];
      acc[ts]=__builtin_amdgcn_mfma_f32_16x16x32_bf16(af,wf,acc[ts],0,0,0);
    }
  }
#pragma unroll
  for(int ts=0;ts<4;ts++){
    int jc = ct*64 + ts*16 + lr;
    if(jc>=Cc) continue;
    float bb = fb[jc];
#pragma unroll
    for(int reg=0;reg<4;reg++){
      int m = w*16 + kq*4 + reg;
      size_t o = (size_t)(grow0+m)*Cc + jc;
      out[o] = xm[o] + acc[ts][reg] + bb;
    }
  }
}

extern "C" void kernel_launch(void* const* d_in, const int* in_sizes, int n_in,
                              void* d_out, int out_size, void* d_ws, size_t ws_size,
                              hipStream_t stream){
  (void)in_sizes; (void)n_in; (void)out_size; (void)ws_size;
  const float* x     = (const float*)d_in[0];
  const float* ln1_g = (const float*)d_in[3];
  const float* ln1_b = (const float*)d_in[4];
  const float* band_w= (const float*)d_in[5];
  const float* band_b= (const float*)d_in[6];
  const float* gate_w= (const float*)d_in[7];
  const float* gate_b= (const float*)d_in[8];
  const float* cab_w1= (const float*)d_in[9];
  const float* cab_b1= (const float*)d_in[10];
  const float* cab_w2= (const float*)d_in[11];
  const float* cab_b2= (const float*)d_in[12];
  const float* eca_w = (const float*)d_in[13];
  const float* plkw  = (const float*)d_in[14];
  const float* dwc_w1= (const float*)d_in[15];
  const float* dwc_b1= (const float*)d_in[16];
  const float* dwc_w2= (const float*)d_in[17];
  const float* dwc_b2= (const float*)d_in[18];
  const float* aggr_w= (const float*)d_in[19];
  const float* aggr_b= (const float*)d_in[20];
  const float* ln2_g = (const float*)d_in[21];
  const float* ln2_b = (const float*)d_in[22];
  const float* fc1_w = (const float*)d_in[23];
  const float* fc1_b = (const float*)d_in[24];
  const float* dw_w  = (const float*)d_in[25];
  const float* dw_b  = (const float*)d_in[26];
  const float* fc2_w = (const float*)d_in[27];
  const float* fc2_b = (const float*)d_in[28];

  float* ws = (float*)d_ws;
  // persistent region
  float* xm   = ws;                      // 13,271,040
  float* m1   = ws + 13271040;           // 1,440
  float* gates= ws + 13272480;           // 32
  float* dkb  = ws + 13272512;           // 1,152
  float* biasb= ws + 13273664;           // 1,440
  float* gapb = ws + 13275104;           // 1,440
  float* svec = ws + 13276544;           // 1,440 -> 13,277,984
  ushort* Wg1 = (ushort*)(ws + 13278000);// 110,592 sh -> 13,333,296
  ushort* Wg2 = (ushort*)(ws + 13333296);// 110,592 sh -> 13,388,592
  ushort* Wp1 = (ushort*)(ws + 13388592);// 147,456 sh -> 13,462,320
  ushort* Wp2 = (ushort*)(ws + 13462320);//  73,728 sh -> 13,499,184
  ushort* Wpa = (ushort*)(ws + 13499184);//  36,864 sh -> 13,517,616
  ushort* Bfx = (ushort*)(ws + 13517616);//  10,752 sh -> 13,522,992
  ushort* Tmw = (ushort*)(ws + 13522992);//  18,432 sh -> 13,532,208
  ushort* Bix = (ushort*)(ws + 13532208);//  12,288 sh -> 13,538,352
  ushort* Wbk = (ushort*)(ws + 13538352);// 110,592 sh -> 13,593,648
  ushort* Wdk = (ushort*)(ws + 13593648);// 372,736 sh -> 13,780,016
  float* big  = ws + 13780096;
  // phase 1 inside big:
  float* ximg = big;                     // 13,271,040
  float* spec = big + 13271040;          // 13,547,520 (xfft in first 9216 of each 9408 plane)
  ushort* mid = (ushort*)(big + 26818560); // 4,423,680 bf16
  float* attn = big + 29030400;          // 1,179,648 -> phase-1 top = 30,210,048
  float* ycab = spec;                    // reuse (stride 9216), spec dead after conv1
  // phase 2 aliases big:
  ushort* t1  = (ushort*)big;                    // 26,542,080 float slots
  float*  reg2= big + 26542080;
  ushort* xn2 = (ushort*)reg2;                   // (ln2->fc1)
  ushort* pgb = (ushort*)reg2;                   // (dwglu->fc2)
  // total ≈ 13,780,096 + 39,813,120 floats ≈ 214 MB

  k_packw<<<576,256,0,stream>>>(cab_w1, cab_w2, fc1_w, fc2_w, aggr_w, band_w,
                                Wg1, Wg2, Wp1, Wp2, Wpa, Wbk, Bfx, Tmw, Bix);
  k_ln1<<<2304,256,0,stream>>>(x, ln1_g, ln1_b, ximg);
  k_plane_mean<<<1440,256,0,stream>>>(ximg, m1);
  k_small<<<1,64,0,stream>>>(m1, gate_w, gate_b, dwc_w1, dwc_b1, dwc_w2, dwc_b2, band_b, gates, dkb, biasb);
  k_packplk<<<1456,256,0,stream>>>(plkw, dkb, Wdk);
  k_fft_fwd<<<1440,256,0,stream>>>(ximg, Bfx, Tmw, spec);
  k_bandmixm<<<dim3(147,Bb),256,0,stream>>>(spec, Wbk, gates);
  k_fft_inv<<<1440,256,0,stream>>>(spec, ximg, biasb, Tmw, Bix);
  k_cab<float, Cc, 192, 6, true,  true ><<<dim3(48,1,Bb),256,0,stream>>>(spec, Wg1, cab_b1, (void*)mid, CRr, SPL);
  k_cab<ushort, CRr, 64, 2, false, false><<<dim3(48,3,Bb),256,0,stream>>>(mid, Wg2, cab_b2, (void*)ycab, Cc, HWn);
  k_plane_mean<<<1440,256,0,stream>>>(ycab, gapb);
  k_eca<<<6,256,0,stream>>>(gapb, eca_w, svec);
  k_plkm<<<dim3(32,Bb),256,0,stream>>>(ximg, Wdk, attn);
  k_aggrm<<<dim3(1152,3),256,0,stream>>>(x, attn, ximg, ycab, Wpa, aggr_b, svec, xm);
  k_ln2<<<18432,256,0,stream>>>(xm, ln2_g, ln2_b, xn2);
  k_fc1<<<1152,256,0,stream>>>(xn2, Wp1, fc1_b, t1);
  k_dwglu<<<dim3(9,HID,Bb),256,0,stream>>>((const bf16*)t1, dw_w, dw_b, (bf16*)pgb);
  k_fc2<<<dim3(1152,3),256,0,stream>>>(pgb, xm, Wp2, fc2_b, (float*)d_out);
}